// Round 7
// baseline (785.694 us; speedup 1.0000x reference)
//
#include <hip/hip_runtime.h>

typedef _Float16 f16;
typedef _Float16 f16x8 __attribute__((ext_vector_type(8)));
typedef float f32x4 __attribute__((ext_vector_type(4)));

constexpr int Bn = 2, Cn = 128, FH = 96, FW = 160, Hh = 384, Wh = 640;
constexpr int HWl = FH * FW;   // 15360
constexpr int NHd = 4, NPt = 9;

#define DEVINL __device__ __forceinline__

DEVINL f32x4 zero4() { f32x4 z; z[0] = 0.f; z[1] = 0.f; z[2] = 0.f; z[3] = 0.f; return z; }
DEVINL f16x8 zero8() {
  f16x8 z;
#pragma unroll
  for (int j = 0; j < 8; ++j) z[j] = (f16)0.f;
  return z;
}

template<int ACT> DEVINL float activ(float v) {
  if (ACT == 1) return v >= 0.f ? v : 0.1f * v;                           // leaky relu
  if (ACT == 2) return 0.5f * v * (1.f + erff(v * 0.70710678118654752f)); // exact gelu
  if (ACT == 3) return 1.f / (1.f + expf(-v));                            // sigmoid
  return v;
}

// ---------------------------------------------------------------------------
// Merged weight prep (12 jobs, one launch). 3x3 jobs produce
// [tap][ks][CoFt: cf0+cf][lane][8]; 1x1 jobs [ks][cf][lane][8].
// k = (lane>>4)*8+j (A-frag convention). Grouped convs zero-padded to full K.
// cf0/CoFt pack two convs (off0+aw0) into one B tensor.
// ---------------------------------------------------------------------------
struct PrepJob { const float* w; f16* wf; int Cout, cin_g, cout_g, KS, CoF, taps, CoFt, cf0, blk0; };
struct PrepArgs { PrepJob j[12]; };

__global__ __launch_bounds__(256) void k_wprep_all(PrepArgs a)
{
  int jb = 0;
#pragma unroll
  for (int t = 1; t < 12; ++t) if ((int)blockIdx.x >= a.j[t].blk0) jb = t;
  PrepJob J = a.j[jb];
  int idx = (blockIdx.x - J.blk0) * 256 + threadIdx.x;
  int total = J.taps * J.KS * J.CoF * 64;
  if (idx >= total) return;
  int lane = idx & 63;
  int rest = idx >> 6;
  int cf = rest % J.CoF;
  int rest2 = rest / J.CoF;
  int ks = rest2 % J.KS;
  int tap = rest2 / J.KS;
  int co = cf * 16 + (lane & 15);
  f16x8 v = zero8();
#pragma unroll
  for (int j = 0; j < 8; ++j) {
    int cip = ks * 32 + (lane >> 4) * 8 + j;
    int cil = cip - (co / J.cout_g) * J.cin_g;
    float x = 0.f;
    if (co < J.Cout && cil >= 0 && cil < J.cin_g)
      x = J.w[((size_t)co * J.cin_g + cil) * J.taps + tap];
    v[j] = (f16)x;
  }
  size_t oidx = (((size_t)tap * J.KS + ks) * J.CoFt + J.cf0 + cf) * 64 + lane;
  *(f16x8*)&J.wf[oidx * 8] = v;
}

// ---------------------------------------------------------------------------
// NCHW f32 -> NHWC f16 transpose for feat1+feat2.
// ---------------------------------------------------------------------------
__global__ __launch_bounds__(256) void k_tr_h(
    const float* __restrict__ feat1, const float* __restrict__ feat2,
    f16* __restrict__ t1, f16* __restrict__ t2)
{
  int idx = blockIdx.x * blockDim.x + threadIdx.x;
  if (idx >= 2 * Bn * HWl * 8) return;
  int cq = idx & 7;
  int pix = (idx >> 3) % HWl;
  int z = idx / (8 * HWl);
  int b = z & 1;
  const float* src = (z >> 1) ? feat2 : feat1;
  f16* dst = (z >> 1) ? t2 : t1;
  int c0 = cq * 16;
  f16x8 v0, v1;
#pragma unroll
  for (int j = 0; j < 8; ++j) {
    v0[j] = (f16)src[(size_t)(b * Cn + c0 + j) * HWl + pix];
    v1[j] = (f16)src[(size_t)(b * Cn + c0 + 8 + j) * HWl + pix];
  }
  f16* dp = dst + ((size_t)b * HWl + pix) * 128 + c0;
  *(f16x8*)dp = v0;
  *(f16x8*)(dp + 8) = v1;
}

// ---------------------------------------------------------------------------
// Warp + concat + source, NHWC f16, cq-fastest lanes (coalesced).
// ---------------------------------------------------------------------------
__global__ __launch_bounds__(256) void k_warp_fuse_h(
    const f16* __restrict__ t1, const f16* __restrict__ t2,
    const float* __restrict__ flowf, const float* __restrict__ flowb,
    const float* __restrict__ edge1, const float* __restrict__ edge2,
    f16* __restrict__ fused, f16* __restrict__ src)
{
  int idx = blockIdx.x * blockDim.x + threadIdx.x;
  if (idx >= Bn * HWl * 8) return;
  int cq = idx & 7;
  int pix = (idx >> 3) % HWl;
  int b = idx / (8 * HWl);
  int j = pix % FW;
  int i = pix / FW;

  const int y4 = 4 * i + 1, x4 = 4 * j + 1;
  const float* p;
  p = flowf + (size_t)((b * 2 + 0) * Hh + y4) * Wh + x4;
  float fx1 = 0.03125f * (p[0] + p[1] + p[Wh] + p[Wh + 1]);
  p = flowf + (size_t)((b * 2 + 1) * Hh + y4) * Wh + x4;
  float fy1 = 0.03125f * (p[0] + p[1] + p[Wh] + p[Wh + 1]);
  p = flowb + (size_t)((b * 2 + 0) * Hh + y4) * Wh + x4;
  float fx2 = 0.03125f * (p[0] + p[1] + p[Wh] + p[Wh + 1]);
  p = flowb + (size_t)((b * 2 + 1) * Hh + y4) * Wh + x4;
  float fy2 = 0.03125f * (p[0] + p[1] + p[Wh] + p[Wh + 1]);

  float sx1 = fminf(fmaxf((float)j + fx1, 0.f), (float)(FW - 1));
  float sy1 = fminf(fmaxf((float)i + fy1, 0.f), (float)(FH - 1));
  float sx2 = fminf(fmaxf((float)j + fx2, 0.f), (float)(FW - 1));
  float sy2 = fminf(fmaxf((float)i + fy2, 0.f), (float)(FH - 1));

  int x10 = (int)floorf(sx1), y10 = (int)floorf(sy1);
  int x11 = min(x10 + 1, FW - 1), y11 = min(y10 + 1, FH - 1);
  float wx1 = sx1 - (float)x10, wy1 = sy1 - (float)y10;
  int x20 = (int)floorf(sx2), y20 = (int)floorf(sy2);
  int x21 = min(x20 + 1, FW - 1), y21 = min(y20 + 1, FH - 1);
  float wx2 = sx2 - (float)x20, wy2 = sy2 - (float)y20;

  float a00 = (1.f - wx1) * (1.f - wy1), a01 = wx1 * (1.f - wy1);
  float a10 = (1.f - wx1) * wy1,         a11 = wx1 * wy1;
  float c00 = (1.f - wx2) * (1.f - wy2), c01 = wx2 * (1.f - wy2);
  float c10 = (1.f - wx2) * wy2,         c11 = wx2 * wy2;

  int c0 = cq * 16;
  const f16* b1 = t1 + (size_t)b * HWl * 128 + c0;
  const f16* b2 = t2 + (size_t)b * HWl * 128 + c0;
  const f16x8* p100 = (const f16x8*)&b1[(size_t)(y10 * FW + x10) * 128];
  const f16x8* p101 = (const f16x8*)&b1[(size_t)(y10 * FW + x11) * 128];
  const f16x8* p110 = (const f16x8*)&b1[(size_t)(y11 * FW + x10) * 128];
  const f16x8* p111 = (const f16x8*)&b1[(size_t)(y11 * FW + x11) * 128];
  const f16x8* p200 = (const f16x8*)&b2[(size_t)(y20 * FW + x20) * 128];
  const f16x8* p201 = (const f16x8*)&b2[(size_t)(y20 * FW + x21) * 128];
  const f16x8* p210 = (const f16x8*)&b2[(size_t)(y21 * FW + x20) * 128];
  const f16x8* p211 = (const f16x8*)&b2[(size_t)(y21 * FW + x21) * 128];

  f16* fp = fused + ((size_t)b * HWl + pix) * 288;
  f16* sp = src + ((size_t)b * HWl + pix) * 128;

#pragma unroll
  for (int h = 0; h < 2; ++h) {
    f16x8 u00 = p100[h], u01 = p101[h], u10 = p110[h], u11 = p111[h];
    f16x8 w00 = p200[h], w01 = p201[h], w10 = p210[h], w11 = p211[h];
    f16x8 r1, r2, rs;
#pragma unroll
    for (int k = 0; k < 8; ++k) {
      float v1 = (float)u00[k] * a00 + (float)u01[k] * a01
               + (float)u10[k] * a10 + (float)u11[k] * a11;
      float v2 = (float)w00[k] * c00 + (float)w01[k] * c01
               + (float)w10[k] * c10 + (float)w11[k] * c11;
      r1[k] = (f16)v1; r2[k] = (f16)v2; rs[k] = (f16)(0.5f * (v1 + v2));
    }
    *(f16x8*)(fp + c0 + h * 8) = r1;
    *(f16x8*)(fp + 128 + c0 + h * 8) = r2;
    *(f16x8*)(sp + c0 + h * 8) = rs;
  }

  if (cq == 0) {
    p = edge1 + (size_t)(b * Hh + y4) * Wh + x4;
    float e1v = 0.25f * (p[0] + p[1] + p[Wh] + p[Wh + 1]);
    p = edge2 + (size_t)(b * Hh + y4) * Wh + x4;
    float e2v = 0.25f * (p[0] + p[1] + p[Wh] + p[Wh + 1]);
    fp[256] = (f16)e1v;
    fp[257] = (f16)e2v;
    fp[258] = (f16)0.5f;
#pragma unroll
    for (int c = 259; c < 288; ++c) fp[c] = (f16)0.f;
  }
}

// ---------------------------------------------------------------------------
// Barrier-free LDS-free MFMA 3x3 conv, NHWC f16.
// Wave tile: M*16 consecutive pixels (one row; requires 16M | W) x NF*16 co.
// Per (slice, tap): A frags straight from global (tap-shifted, col-predicated),
// B frags from prepped weights (L2-hot). No __syncthreads.
// Dual bias (bias2/bsplit) supports the merged off0+aw0 dispatch.
// Input X holds rows [in_r0, +in_rows); zero-pad outside [0,Htot).
// Output rows [ogr0, +nrows) into window [out_r0, +out_rows).
// ---------------------------------------------------------------------------
template<int ACT, int M, int NF, int W>
__global__ __launch_bounds__(256) void k_conv3g(
    const f16* __restrict__ X, const f16* __restrict__ Wf,
    const float* __restrict__ bias, const float* __restrict__ bias2, int bsplit,
    f16* __restrict__ Out,
    int KS, int CoF, int Cs_in, int Cs_out, int Htot,
    int in_r0, int in_rows, int out_r0, int out_rows,
    int ogr0, int nrows, int coTiles)
{
  int wid = blockIdx.x * 4 + (threadIdx.x >> 6);
  int lane = threadIdx.x & 63;
  int l15 = lane & 15, l4 = lane >> 4;
  int pixTiles = nrows * W / (M * 16);
  if (wid >= pixTiles * coTiles) return;
  int coT = wid % coTiles;
  int pixT = wid / coTiles;
  int b = blockIdx.z;
  int base = pixT * (M * 16);
  int row = ogr0 + base / W;       // wave-uniform (16M | W)
  int colB = base % W;

  f32x4 acc[M][NF];
#pragma unroll
  for (int mf = 0; mf < M; ++mf)
#pragma unroll
    for (int nf = 0; nf < NF; ++nf) acc[mf][nf] = zero4();

  for (int cs = 0; cs < KS; ++cs) {
#pragma unroll
    for (int ky = 0; ky < 3; ++ky) {
      int srow = row + ky - 1;
      bool rv = (srow >= 0 && srow < Htot);
      int crow = min(max(srow, in_r0), in_r0 + in_rows - 1);
      const f16* rp = X + (((size_t)b * in_rows + (crow - in_r0)) * W) * (size_t)Cs_in
                      + cs * 32 + l4 * 8;
#pragma unroll
      for (int kx = 0; kx < 3; ++kx) {
        int tap = ky * 3 + kx;
        f16x8 Bf[NF];
#pragma unroll
        for (int nf = 0; nf < NF; ++nf)
          Bf[nf] = *(const f16x8*)&Wf[((((size_t)tap * KS + cs) * CoF + coT * NF + nf) * 64 + lane) * 8];
        f16x8 Af[M];
#pragma unroll
        for (int mf = 0; mf < M; ++mf) {
          int scol = colB + mf * 16 + l15 + kx - 1;
          f16x8 a = zero8();
          if (rv && (unsigned)scol < (unsigned)W)
            a = *(const f16x8*)&rp[(size_t)scol * Cs_in];
          Af[mf] = a;
        }
#pragma unroll
        for (int mf = 0; mf < M; ++mf)
#pragma unroll
          for (int nf = 0; nf < NF; ++nf)
            acc[mf][nf] = __builtin_amdgcn_mfma_f32_16x16x32_f16(Af[mf], Bf[nf], acc[mf][nf], 0, 0, 0);
      }
    }
  }

  size_t rowoff = ((size_t)b * out_rows + (row - out_r0)) * W;
#pragma unroll
  for (int nf = 0; nf < NF; ++nf) {
    int co = coT * (NF * 16) + nf * 16 + l15;
    float bv = (co < bsplit) ? bias[co] : bias2[co - bsplit];
#pragma unroll
    for (int mf = 0; mf < M; ++mf) {
      int xo = colB + mf * 16 + l4 * 4;
#pragma unroll
      for (int rg = 0; rg < 4; ++rg) {
        float v = activ<ACT>(acc[mf][nf][rg] + bv);
        Out[(rowoff + xo + rg) * (size_t)Cs_out + co] = (f16)v;
      }
    }
  }
}

// ---------------------------------------------------------------------------
// 4x bilinear upsample NHWC f16: xbuf (B,96,160,128) -> U rows [u0, +urows).
// ---------------------------------------------------------------------------
__global__ __launch_bounds__(256) void k_up4_h(
    const f16* __restrict__ Xl, f16* __restrict__ U, int u0, int urows)
{
  int idx = blockIdx.x * blockDim.x + threadIdx.x;
  if (idx >= Bn * urows * Wh * 8) return;
  int cq = idx & 7;
  int x = (idx >> 3) % Wh;
  int r = ((idx >> 3) / Wh) % urows;
  int b = idx / (8 * Wh * urows);
  int R = u0 + r;

  float uy = ((float)R + 0.5f) * 0.25f - 0.5f;
  uy = fminf(fmaxf(uy, 0.f), (float)(FH - 1));
  int y0 = (int)floorf(uy);
  int y1 = min(y0 + 1, FH - 1);
  float fy = uy - (float)y0;
  float ux = ((float)x + 0.5f) * 0.25f - 0.5f;
  ux = fminf(fmaxf(ux, 0.f), (float)(FW - 1));
  int x0 = (int)floorf(ux);
  int x1 = min(x0 + 1, FW - 1);
  float fx = ux - (float)x0;

  const f16* xb = Xl + (size_t)b * HWl * 128 + cq * 16;
  const f16x8* c00 = (const f16x8*)&xb[(size_t)(y0 * FW + x0) * 128];
  const f16x8* c01 = (const f16x8*)&xb[(size_t)(y0 * FW + x1) * 128];
  const f16x8* c10 = (const f16x8*)&xb[(size_t)(y1 * FW + x0) * 128];
  const f16x8* c11 = (const f16x8*)&xb[(size_t)(y1 * FW + x1) * 128];
  f16* up = U + (((size_t)b * urows + r) * Wh + x) * 128 + cq * 16;
#pragma unroll
  for (int h = 0; h < 2; ++h) {
    f16x8 a = c00[h], bb = c01[h], cc = c10[h], dd = c11[h];
    f16x8 o;
#pragma unroll
    for (int jj = 0; jj < 8; ++jj) {
      float t0 = (float)a[jj] * (1.f - fx) + (float)bb[jj] * fx;
      float t1 = (float)cc[jj] * (1.f - fx) + (float)dd[jj] * fx;
      o[jj] = (f16)(t0 * (1.f - fy) + t1 * fy);
    }
    *(f16x8*)(up + h * 8) = o;
  }
}

// ---------------------------------------------------------------------------
// MFMA 1x1 conv (pure GEMM). Wave = 32px x up-to-64co.
// ---------------------------------------------------------------------------
template<int ACT, int RES>
__global__ __launch_bounds__(256) void k_gemm1x1(
    const f16* __restrict__ X, const f16* __restrict__ Wf,
    const float* __restrict__ bias, f16* __restrict__ Out,
    int KS, int CoF, int Cs_in, int Cs_out, int Cr, int coTiles, int pixTiles)
{
  int wid = blockIdx.x * 4 + (threadIdx.x >> 6);
  int lane = threadIdx.x & 63;
  int total = pixTiles * coTiles;
  if (wid >= total) return;
  int coT = wid % coTiles;
  int pixT = wid / coTiles;
  int nfc = min(4, CoF - coT * 4);
  int l15 = lane & 15, l4 = lane >> 4;

  f32x4 acc[2][4];
#pragma unroll
  for (int mf = 0; mf < 2; ++mf)
#pragma unroll
    for (int nf = 0; nf < 4; ++nf) acc[mf][nf] = zero4();

  int pA0 = pixT * 32 + l15;
  for (int ks = 0; ks < KS; ++ks) {
    f16x8 a0 = *(const f16x8*)&X[(size_t)pA0 * Cs_in + ks * 32 + l4 * 8];
    f16x8 a1 = *(const f16x8*)&X[(size_t)(pA0 + 16) * Cs_in + ks * 32 + l4 * 8];
#pragma unroll
    for (int nf = 0; nf < 4; ++nf) {
      if (nf < nfc) {
        f16x8 bf = *(const f16x8*)&Wf[(((size_t)ks * CoF + coT * 4 + nf) * 64 + lane) * 8];
        acc[0][nf] = __builtin_amdgcn_mfma_f32_16x16x32_f16(a0, bf, acc[0][nf], 0, 0, 0);
        acc[1][nf] = __builtin_amdgcn_mfma_f32_16x16x32_f16(a1, bf, acc[1][nf], 0, 0, 0);
      }
    }
  }
#pragma unroll
  for (int nf = 0; nf < 4; ++nf) {
    if (nf < nfc) {
      int co = coT * 64 + nf * 16 + l15;
      if (co < Cr) {
        float bv = bias[co];
#pragma unroll
        for (int mf = 0; mf < 2; ++mf) {
          int p0 = pixT * 32 + mf * 16 + l4 * 4;
#pragma unroll
          for (int rg = 0; rg < 4; ++rg) {
            float v = activ<ACT>(acc[mf][nf][rg] + bv);
            size_t o = (size_t)(p0 + rg) * Cs_out + co;
            if (RES) v += (float)Out[o];
            Out[o] = (f16)v;
          }
        }
      }
    }
  }
}

// ---------------------------------------------------------------------------
// GroupNorm on NHWC f16, two stage.
// ---------------------------------------------------------------------------
__global__ __launch_bounds__(256) void k_gn_part_h(
    const f16* __restrict__ X, float* __restrict__ part)
{
  int s = blockIdx.x & 7;
  int g = (blockIdx.x >> 3) & 7;
  int b = blockIdx.x >> 6;
  int tid = threadIdx.x;
  const f16* Xp = X + (size_t)b * HWl * 128 + g * 16 + (tid & 1) * 8;
  float sum = 0.f, ss = 0.f;
  for (int p = s * 1920 + (tid >> 1); p < (s + 1) * 1920; p += 128) {
    f16x8 v = *(const f16x8*)&Xp[(size_t)p * 128];
#pragma unroll
    for (int jj = 0; jj < 8; ++jj) { float f = (float)v[jj]; sum += f; ss += f * f; }
  }
  __shared__ float sh1[256], sh2[256];
  sh1[tid] = sum; sh2[tid] = ss;
  __syncthreads();
  for (int st = 128; st > 0; st >>= 1) {
    if (tid < st) { sh1[tid] += sh1[tid + st]; sh2[tid] += sh2[tid + st]; }
    __syncthreads();
  }
  if (tid == 0) {
    part[((b * 8 + g) * 8 + s) * 2] = sh1[0];
    part[((b * 8 + g) * 8 + s) * 2 + 1] = sh2[0];
  }
}

__global__ __launch_bounds__(256) void k_gn_apply_h(
    const f16* __restrict__ X, const float* __restrict__ gw,
    const float* __restrict__ gb, const float* __restrict__ part,
    f16* __restrict__ Q)
{
  int idx = blockIdx.x * blockDim.x + threadIdx.x;
  int total = Bn * HWl * 16;
  if (idx >= total) return;
  int u = idx & 15;
  int pix = (idx >> 4) % HWl;
  int b = idx / (16 * HWl);
  int c0 = u * 8;
  int g = c0 >> 4;
  const float* pp = part + ((b * 8 + g) * 8) * 2;
  float sum = 0.f, ss = 0.f;
#pragma unroll
  for (int s = 0; s < 8; ++s) { sum += pp[s * 2]; ss += pp[s * 2 + 1]; }
  const float n = 16.f * HWl;
  float mean = sum / n;
  float var = ss / n - mean * mean;
  float inv = rsqrtf(var + 1e-5f);
  f16x8 v = *(const f16x8*)&X[((size_t)b * HWl + pix) * 128 + c0];
  f16x8 r;
#pragma unroll
  for (int jj = 0; jj < 8; ++jj) {
    int c = c0 + jj;
    r[jj] = (f16)(((float)v[jj] - mean) * (gw[c] * inv) + gb[c]);
  }
  *(f16x8*)&Q[((size_t)b * HWl + pix) * 128 + c0] = r;
}

// softmax over the 9 points; attn NHWC [b][pix][48]
__global__ __launch_bounds__(256) void k_softmax9_h(f16* __restrict__ a)
{
  int idx = blockIdx.x * blockDim.x + threadIdx.x;
  if (idx >= Bn * NHd * HWl) return;
  int pix = idx % HWl;
  int head = (idx / HWl) & 3;
  int b = idx / (HWl * NHd);
  f16* base = a + ((size_t)b * HWl + pix) * 48 + head * 9;
  float v[9];
  float m = -1e30f;
#pragma unroll
  for (int p0 = 0; p0 < 9; ++p0) { v[p0] = (float)base[p0]; m = fmaxf(m, v[p0]); }
  float s = 0.f;
#pragma unroll
  for (int p0 = 0; p0 < 9; ++p0) { v[p0] = expf(v[p0] - m); s += v[p0]; }
  float inv = 1.f / s;
#pragma unroll
  for (int p0 = 0; p0 < 9; ++p0) base[p0] = (f16)(v[p0] * inv);
}

// ---------------------------------------------------------------------------
// Deformable sampling, NHWC. Thread per (b, head, pix), 32 head-channels.
// ---------------------------------------------------------------------------
__global__ __launch_bounds__(256) void k_deform_h(
    const f16* __restrict__ vals, const f16* __restrict__ off,
    const f16* __restrict__ attn, f16* __restrict__ outa)
{
  int idx = blockIdx.x * blockDim.x + threadIdx.x;
  if (idx >= Bn * NHd * HWl) return;
  int pix = idx % HWl;
  int head = (idx / HWl) & 3;
  int b = idx / (HWl * NHd);
  int j = pix % FW, i = pix / FW;

  const float kx = (float)FW / (float)(FW - 1);
  const float ky = (float)FH / (float)(FH - 1);
  const f16* vb = vals + (size_t)b * HWl * 128 + head * 32;
  const f16* ab = attn + ((size_t)b * HWl + pix) * 48 + head * 9;
  const f16* ob = off + ((size_t)b * HWl + pix) * 80 + head * 18;

  float acc[32];
#pragma unroll
  for (int k = 0; k < 32; ++k) acc[k] = 0.f;

#pragma unroll
  for (int p0 = 0; p0 < 9; ++p0) {
    float ox = (float)ob[p0 * 2];
    float oy = (float)ob[p0 * 2 + 1];
    float aw = (float)ab[p0];
    float xf = ((float)j + ox) * kx - 0.5f;
    float yf = ((float)i + oy) * ky - 0.5f;
    xf = fminf(fmaxf(xf, 0.f), (float)(FW - 1));
    yf = fminf(fmaxf(yf, 0.f), (float)(FH - 1));
    int x0 = (int)floorf(xf), y0 = (int)floorf(yf);
    int x1 = min(x0 + 1, FW - 1), y1 = min(y0 + 1, FH - 1);
    float fx = xf - (float)x0, fy = yf - (float)y0;
    float w00 = aw * (1.f - fx) * (1.f - fy);
    float w01 = aw * fx * (1.f - fy);
    float w10 = aw * (1.f - fx) * fy;
    float w11 = aw * fx * fy;
    const f16x8* c00 = (const f16x8*)&vb[(size_t)(y0 * FW + x0) * 128];
    const f16x8* c01 = (const f16x8*)&vb[(size_t)(y0 * FW + x1) * 128];
    const f16x8* c10 = (const f16x8*)&vb[(size_t)(y1 * FW + x0) * 128];
    const f16x8* c11 = (const f16x8*)&vb[(size_t)(y1 * FW + x1) * 128];
#pragma unroll
    for (int k8 = 0; k8 < 4; ++k8) {
      f16x8 a = c00[k8], bb = c01[k8], cc = c10[k8], dd = c11[k8];
#pragma unroll
      for (int jj = 0; jj < 8; ++jj)
        acc[k8 * 8 + jj] += w00 * (float)a[jj] + w01 * (float)bb[jj]
                          + w10 * (float)cc[jj] + w11 * (float)dd[jj];
    }
  }
  f16* op = outa + ((size_t)b * HWl + pix) * 128 + head * 32;
#pragma unroll
  for (int k = 0; k < 32; ++k) op[k] = (f16)acc[k];
}

// ---------------------------------------------------------------------------
// dec2: 32->3 conv from NHWC f16 window + sigmoid, NCHW f32 out rows [c0,+R).
// ---------------------------------------------------------------------------
__global__ __launch_bounds__(256) void k_dec2_h(
    const f16* __restrict__ Xb, const float* __restrict__ w,
    const float* __restrict__ bias, float* __restrict__ out,
    int c0, int b0, int brows, int R)
{
  int idx = blockIdx.x * blockDim.x + threadIdx.x;
  if (idx >= Bn * R * Wh) return;
  int x = idx % Wh;
  int y = c0 + (idx / Wh) % R;
  int b = idx / (Wh * R);
  float a0 = bias[0], a1 = bias[1], a2 = bias[2];
#pragma unroll
  for (int ky = 0; ky < 3; ++ky) {
    int gy = y + ky - 1;
    if (gy < 0 || gy >= Hh) continue;
#pragma unroll
    for (int kxx = 0; kxx < 3; ++kxx) {
      int gx = x + kxx - 1;
      if (gx < 0 || gx >= Wh) continue;
      int tap = ky * 3 + kxx;
      const f16* px = Xb + ((size_t)(b * brows + (gy - b0)) * Wh + gx) * 32;
#pragma unroll
      for (int k8 = 0; k8 < 4; ++k8) {
        f16x8 v = *(const f16x8*)&px[k8 * 8];
#pragma unroll
        for (int jj = 0; jj < 8; ++jj) {
          int ci = k8 * 8 + jj;
          float f = (float)v[jj];
          a0 += f * w[(0 * 32 + ci) * 9 + tap];
          a1 += f * w[(1 * 32 + ci) * 9 + tap];
          a2 += f * w[(2 * 32 + ci) * 9 + tap];
        }
      }
    }
  }
  size_t o = ((size_t)(b * 3 + 0) * Hh + y) * Wh + x;
  out[o] = 1.f / (1.f + expf(-a0));
  out[o + (size_t)Hh * Wh] = 1.f / (1.f + expf(-a1));
  out[o + (size_t)2 * Hh * Wh] = 1.f / (1.f + expf(-a2));
}

// ---------------------------------------------------------------------------
extern "C" void kernel_launch(void* const* d_in, const int* in_sizes, int n_in,
                              void* d_out, int out_size, void* d_ws, size_t ws_size,
                              hipStream_t stream) {
  (void)in_sizes; (void)n_in; (void)out_size; (void)ws_size;
  const float* feat1  = (const float*)d_in[0];
  const float* feat2  = (const float*)d_in[1];
  const float* flowf  = (const float*)d_in[2];
  const float* flowb  = (const float*)d_in[3];
  const float* edge1  = (const float*)d_in[4];
  const float* edge2  = (const float*)d_in[5];
  const float* fuse_w0 = (const float*)d_in[6];
  const float* fuse_b0 = (const float*)d_in[7];
  const float* fuse_w1 = (const float*)d_in[8];
  const float* fuse_b1 = (const float*)d_in[9];
  const float* gn_g   = (const float*)d_in[10];
  const float* gn_b   = (const float*)d_in[11];
  const float* off_w0 = (const float*)d_in[12];
  const float* off_b0 = (const float*)d_in[13];
  const float* off_w1 = (const float*)d_in[14];
  const float* off_b1 = (const float*)d_in[15];
  const float* aw_w0  = (const float*)d_in[16];
  const float* aw_b0  = (const float*)d_in[17];
  const float* aw_w1  = (const float*)d_in[18];
  const float* aw_b1  = (const float*)d_in[19];
  const float* val_w  = (const float*)d_in[20];
  const float* val_b  = (const float*)d_in[21];
  const float* out_w  = (const float*)d_in[22];
  const float* out_b  = (const float*)d_in[23];
  const float* ffn_w0 = (const float*)d_in[24];
  const float* ffn_b0 = (const float*)d_in[25];
  const float* ffn_w1 = (const float*)d_in[26];
  const float* ffn_b1 = (const float*)d_in[27];
  const float* dec_w0 = (const float*)d_in[28];
  const float* dec_b0 = (const float*)d_in[29];
  const float* dec_w1 = (const float*)d_in[30];
  const float* dec_b1 = (const float*)d_in[31];
  const float* dec_w2 = (const float*)d_in[32];
  const float* dec_b2 = (const float*)d_in[33];
  float* out = (float*)d_out;

  // ---- workspace layout (f16 units). Weights FIRST so the decoder overlay
  // (which reuses the activation pool) can never clobber them. Total ~75 MB.
  f16* ws16 = (f16*)d_ws;
  size_t o = 0;
  auto alloc = [&](size_t n) { f16* p = ws16 + o; o += (n + 7) & ~(size_t)7; return p; };
  f16* xbuf  = alloc((size_t)2 * HWl * 128);
  f16* wfF0 = alloc(9 * 9 * 8 * 512);
  f16* wfF1 = alloc(9 * 4 * 8 * 512);
  f16* wfOA = alloc(9 * 4 * 16 * 512);          // off0 (cf 0..7) + aw0 (cf 8..15)
  f16* wfD0 = alloc(9 * 4 * 4 * 512);
  f16* wfD1 = alloc(9 * 2 * 2 * 512);
  f16* w1O  = alloc(4 * 5 * 512);
  f16* w1A  = alloc(4 * 3 * 512);
  f16* w1V  = alloc(4 * 8 * 512);
  f16* w1U  = alloc(4 * 8 * 512);
  f16* w1G0 = alloc(4 * 16 * 512);
  f16* w1G1 = alloc(8 * 8 * 512);
  float* gnp = (float*)alloc(512);
  f16* pool  = ws16 + o;                        // decoder overlay starts here
  f16* regA  = alloc((size_t)2 * HWl * 288);    // fused / t_oa / ffn_t
  f16* regB  = alloc((size_t)2 * HWl * 128);    // source / out_attn
  f16* regC  = alloc((size_t)2 * HWl * 128);    // fuse0-out / qb
  f16* offb  = alloc((size_t)2 * HWl * 80);
  f16* attnb = alloc((size_t)2 * HWl * 48);
  f16* regF  = alloc((size_t)2 * HWl * 131);    // valsb
  f16* featT1 = alloc((size_t)2 * HWl * 128);
  f16* featT2 = alloc((size_t)2 * HWl * 128);

  f16* fused = regA;
  f16* t_oa  = regA;        // merged off/aw 3x3 out, 256 ch
  f16* ffn_t = regA;
  f16* src_h = regB;
  f16* out_attn = regB;
  f16* tmp_h = regC;
  f16* qb    = regC;
  f16* valsb = regF;
  // Decoder overlay over pool (dead after FFN). 96-row chunks:
  // bufU 2*103*640*128 = 16.88M ; bufA 2*100*640*64 = 8.19M ;
  // bufB 2*99*640*32 = 4.06M ; total 29.12M <= pool 32.53M f16.
  f16* bufU = pool;
  f16* bufA = bufU + (size_t)2 * 103 * 640 * 128;
  f16* bufB = bufA + (size_t)2 * 100 * 640 * 64;

  dim3 blk(256);
  auto pg = [](long n) { return dim3((unsigned)((n + 255) / 256)); };
  auto cg = [](int pixTiles, int coTiles) {
    return dim3((unsigned)((pixTiles * coTiles + 3) / 4), 1, 2);
  };
  const int BIG = 1 << 30;

  // ---- merged weight prep ----
  PrepArgs pa;
  int pb = 0;
  auto addj = [&](int k, const float* w, f16* wf, int Cout, int cing, int coutg,
                  int KS, int CoF, int taps, int CoFt, int cf0) {
    pa.j[k] = PrepJob{w, wf, Cout, cing, coutg, KS, CoF, taps, CoFt, cf0, pb};
    pb += (taps * KS * CoF * 64 + 255) / 256;
  };
  addj(0, fuse_w0, wfF0, 128, 259, 128, 9, 8, 9, 8, 0);
  addj(1, fuse_w1, wfF1, 128, 128, 128, 4, 8, 9, 8, 0);
  addj(2, off_w0, wfOA, 128, 32, 32, 4, 8, 9, 16, 0);
  addj(3, aw_w0,  wfOA, 128, 32, 32, 4, 8, 9, 16, 8);
  addj(4, dec_w0, wfD0, 64, 128, 64, 4, 4, 9, 4, 0);
  addj(5, dec_w1, wfD1, 32, 64, 32, 2, 2, 9, 2, 0);
  addj(6, off_w1, w1O, 72, 128, 72, 4, 5, 1, 5, 0);
  addj(7, aw_w1,  w1A, 36, 128, 36, 4, 3, 1, 3, 0);
  addj(8, val_w,  w1V, 128, 128, 128, 4, 8, 1, 8, 0);
  addj(9, out_w,  w1U, 128, 128, 128, 4, 8, 1, 8, 0);
  addj(10, ffn_w0, w1G0, 256, 128, 256, 4, 16, 1, 16, 0);
  addj(11, ffn_w1, w1G1, 128, 256, 128, 8, 8, 1, 8, 0);
  k_wprep_all<<<dim3((unsigned)pb), blk, 0, stream>>>(pa);

  // ---- 0. feats -> NHWC f16 ----
  k_tr_h<<<pg(2L * Bn * HWl * 8), blk, 0, stream>>>(feat1, feat2, featT1, featT2);
  // ---- 1. warp + concat + source ----
  k_warp_fuse_h<<<pg((long)Bn * HWl * 8), blk, 0, stream>>>(featT1, featT2, flowf, flowb,
                                                            edge1, edge2, fused, src_h);
  // ---- 2-3. fuse convs (barrier-free M=2 NF=2) ----
  k_conv3g<1, 2, 2, 160><<<cg(480, 4), blk, 0, stream>>>(fused, wfF0, fuse_b0, fuse_b0, BIG,
      tmp_h, 9, 8, 288, 128, FH, 0, FH, 0, FH, 0, FH, 4);
  k_conv3g<1, 2, 2, 160><<<cg(480, 4), blk, 0, stream>>>(tmp_h, wfF1, fuse_b1, fuse_b1, BIG,
      xbuf, 4, 8, 128, 128, FH, 0, FH, 0, FH, 0, FH, 4);
  // ---- 4. group norm ----
  k_gn_part_h<<<dim3(128), blk, 0, stream>>>(xbuf, gnp);
  k_gn_apply_h<<<pg(2L * HWl * 16), blk, 0, stream>>>(xbuf, gn_g, gn_b, gnp, qb);
  // ---- 5. merged off0+aw0 grouped 3x3 (256 out ch, dual bias) ----
  k_conv3g<1, 2, 2, 160><<<cg(480, 8), blk, 0, stream>>>(qb, wfOA, off_b0, aw_b0, 128,
      t_oa, 4, 16, 128, 256, FH, 0, FH, 0, FH, 0, FH, 8);
  // ---- 6-8. 1x1 heads + softmax ----
  k_gemm1x1<0, 0><<<dim3(480), blk, 0, stream>>>(t_oa, w1O, off_b1, offb,
      4, 5, 256, 80, 72, 2, 960);
  k_gemm1x1<0, 0><<<dim3(240), blk, 0, stream>>>(t_oa + 128, w1A, aw_b1, attnb,
      4, 3, 256, 48, 36, 1, 960);
  k_softmax9_h<<<pg(2L * NHd * HWl), blk, 0, stream>>>(attnb);
  // ---- 9. vals ----
  k_gemm1x1<0, 0><<<dim3(480), blk, 0, stream>>>(src_h, w1V, val_b, valsb,
      4, 8, 128, 128, 128, 2, 960);
  // ---- 10. deform ----
  k_deform_h<<<pg(2L * NHd * HWl), blk, 0, stream>>>(valsb, offb, attnb, out_attn);
  // ---- 11. out-proj (residual into xbuf) ----
  k_gemm1x1<0, 1><<<dim3(480), blk, 0, stream>>>(out_attn, w1U, out_b, xbuf,
      4, 8, 128, 128, 128, 2, 960);
  // ---- 12-13. FFN ----
  k_gemm1x1<2, 0><<<dim3(960), blk, 0, stream>>>(xbuf, w1G0, ffn_b0, ffn_t,
      4, 16, 128, 256, 256, 4, 960);
  k_gemm1x1<0, 1><<<dim3(480), blk, 0, stream>>>(ffn_t, w1G1, ffn_b1, xbuf,
      8, 8, 256, 128, 128, 2, 960);

  // ---- 14. decoder, 4 chunks of 96 rows: up4 -> dec0 -> dec1 -> dec2 ----
  for (int c0 = 0; c0 < Hh; c0 += 96) {
    int c1 = c0 + 96;
    int a0 = c0 - 2 > 0 ? c0 - 2 : 0;
    int a1 = c1 + 2 < Hh ? c1 + 2 : Hh;
    int b0 = c0 - 1 > 0 ? c0 - 1 : 0;
    int b1 = c1 + 1 < Hh ? c1 + 1 : Hh;
    int u0 = a0 - 1 > 0 ? a0 - 1 : 0;
    int u1 = a1 + 1 < Hh ? a1 + 1 : Hh;
    int ar = a1 - a0, br = b1 - b0, ur = u1 - u0;
    // upsample rows [u0,u1) -> bufU
    k_up4_h<<<pg(2L * ur * Wh * 8), blk, 0, stream>>>(xbuf, bufU, u0, ur);
    // dec0: 128->64, rows [a0,a1) -> bufA  (M=4, NF=4)
    k_conv3g<1, 4, 4, 640><<<cg(ar * 10, 1), blk, 0, stream>>>(bufU, wfD0, dec_b0, dec_b0, BIG,
        bufA, 4, 4, 128, 64, Hh, u0, ur, a0, ar, a0, ar, 1);
    // dec1: 64->32, rows [b0,b1) -> bufB  (M=4, NF=2)
    k_conv3g<1, 4, 2, 640><<<cg(br * 10, 1), blk, 0, stream>>>(bufA, wfD1, dec_b1, dec_b1, BIG,
        bufB, 2, 2, 64, 32, Hh, a0, ar, b0, br, b0, br, 1);
    // dec2: 32->3 + sigmoid -> out rows [c0,c1)
    k_dec2_h<<<pg(2L * 96 * Wh), blk, 0, stream>>>(bufB, dec_w2, dec_b2, out,
                                                   c0, b0, br, 96);
  }
}

// Round 8
// 741.050 us; speedup vs baseline: 1.0602x; 1.0602x over previous
//
#include <hip/hip_runtime.h>

typedef _Float16 f16;
typedef _Float16 f16x8 __attribute__((ext_vector_type(8)));
typedef float f32x4 __attribute__((ext_vector_type(4)));

constexpr int Bn = 2, Cn = 128, FH = 96, FW = 160, Hh = 384, Wh = 640;
constexpr int HWl = FH * FW;   // 15360
constexpr int NHd = 4, NPt = 9;

#define DEVINL __device__ __forceinline__

DEVINL f32x4 zero4() { f32x4 z; z[0] = 0.f; z[1] = 0.f; z[2] = 0.f; z[3] = 0.f; return z; }
DEVINL f16x8 zero8() {
  f16x8 z;
#pragma unroll
  for (int j = 0; j < 8; ++j) z[j] = (f16)0.f;
  return z;
}

template<int ACT> DEVINL float activ(float v) {
  if (ACT == 1) return v >= 0.f ? v : 0.1f * v;                           // leaky relu
  if (ACT == 2) return 0.5f * v * (1.f + erff(v * 0.70710678118654752f)); // exact gelu
  if (ACT == 3) return 1.f / (1.f + expf(-v));                            // sigmoid
  return v;
}

// ---------------------------------------------------------------------------
// Merged weight prep (12 jobs, one launch). 3x3 jobs produce
// [tap][ks][CoFt: cf0+cf][lane][8]; 1x1 jobs [ks][cf][lane][8].
// k = (lane>>4)*8+j (A-frag convention). Grouped convs zero-padded to full K.
// ---------------------------------------------------------------------------
struct PrepJob { const float* w; f16* wf; int Cout, cin_g, cout_g, KS, CoF, taps, CoFt, cf0, blk0; };
struct PrepArgs { PrepJob j[12]; };

__global__ __launch_bounds__(256) void k_wprep_all(PrepArgs a)
{
  int jb = 0;
#pragma unroll
  for (int t = 1; t < 12; ++t) if ((int)blockIdx.x >= a.j[t].blk0) jb = t;
  PrepJob J = a.j[jb];
  int idx = (blockIdx.x - J.blk0) * 256 + threadIdx.x;
  int total = J.taps * J.KS * J.CoF * 64;
  if (idx >= total) return;
  int lane = idx & 63;
  int rest = idx >> 6;
  int cf = rest % J.CoF;
  int rest2 = rest / J.CoF;
  int ks = rest2 % J.KS;
  int tap = rest2 / J.KS;
  int co = cf * 16 + (lane & 15);
  f16x8 v = zero8();
#pragma unroll
  for (int j = 0; j < 8; ++j) {
    int cip = ks * 32 + (lane >> 4) * 8 + j;
    int cil = cip - (co / J.cout_g) * J.cin_g;
    float x = 0.f;
    if (co < J.Cout && cil >= 0 && cil < J.cin_g)
      x = J.w[((size_t)co * J.cin_g + cil) * J.taps + tap];
    v[j] = (f16)x;
  }
  size_t oidx = (((size_t)tap * J.KS + ks) * J.CoFt + J.cf0 + cf) * 64 + lane;
  *(f16x8*)&J.wf[oidx * 8] = v;
}

// ---------------------------------------------------------------------------
// NCHW f32 -> NHWC f16 transpose for feat1+feat2.
// ---------------------------------------------------------------------------
__global__ __launch_bounds__(256) void k_tr_h(
    const float* __restrict__ feat1, const float* __restrict__ feat2,
    f16* __restrict__ t1, f16* __restrict__ t2)
{
  int idx = blockIdx.x * blockDim.x + threadIdx.x;
  if (idx >= 2 * Bn * HWl * 8) return;
  int cq = idx & 7;
  int pix = (idx >> 3) % HWl;
  int z = idx / (8 * HWl);
  int b = z & 1;
  const float* src = (z >> 1) ? feat2 : feat1;
  f16* dst = (z >> 1) ? t2 : t1;
  int c0 = cq * 16;
  f16x8 v0, v1;
#pragma unroll
  for (int j = 0; j < 8; ++j) {
    v0[j] = (f16)src[(size_t)(b * Cn + c0 + j) * HWl + pix];
    v1[j] = (f16)src[(size_t)(b * Cn + c0 + 8 + j) * HWl + pix];
  }
  f16* dp = dst + ((size_t)b * HWl + pix) * 128 + c0;
  *(f16x8*)dp = v0;
  *(f16x8*)(dp + 8) = v1;
}

// ---------------------------------------------------------------------------
// Warp + concat + source, NHWC f16, cq-fastest lanes (coalesced).
// ---------------------------------------------------------------------------
__global__ __launch_bounds__(256) void k_warp_fuse_h(
    const f16* __restrict__ t1, const f16* __restrict__ t2,
    const float* __restrict__ flowf, const float* __restrict__ flowb,
    const float* __restrict__ edge1, const float* __restrict__ edge2,
    f16* __restrict__ fused, f16* __restrict__ src)
{
  int idx = blockIdx.x * blockDim.x + threadIdx.x;
  if (idx >= Bn * HWl * 8) return;
  int cq = idx & 7;
  int pix = (idx >> 3) % HWl;
  int b = idx / (8 * HWl);
  int j = pix % FW;
  int i = pix / FW;

  const int y4 = 4 * i + 1, x4 = 4 * j + 1;
  const float* p;
  p = flowf + (size_t)((b * 2 + 0) * Hh + y4) * Wh + x4;
  float fx1 = 0.03125f * (p[0] + p[1] + p[Wh] + p[Wh + 1]);
  p = flowf + (size_t)((b * 2 + 1) * Hh + y4) * Wh + x4;
  float fy1 = 0.03125f * (p[0] + p[1] + p[Wh] + p[Wh + 1]);
  p = flowb + (size_t)((b * 2 + 0) * Hh + y4) * Wh + x4;
  float fx2 = 0.03125f * (p[0] + p[1] + p[Wh] + p[Wh + 1]);
  p = flowb + (size_t)((b * 2 + 1) * Hh + y4) * Wh + x4;
  float fy2 = 0.03125f * (p[0] + p[1] + p[Wh] + p[Wh + 1]);

  float sx1 = fminf(fmaxf((float)j + fx1, 0.f), (float)(FW - 1));
  float sy1 = fminf(fmaxf((float)i + fy1, 0.f), (float)(FH - 1));
  float sx2 = fminf(fmaxf((float)j + fx2, 0.f), (float)(FW - 1));
  float sy2 = fminf(fmaxf((float)i + fy2, 0.f), (float)(FH - 1));

  int x10 = (int)floorf(sx1), y10 = (int)floorf(sy1);
  int x11 = min(x10 + 1, FW - 1), y11 = min(y10 + 1, FH - 1);
  float wx1 = sx1 - (float)x10, wy1 = sy1 - (float)y10;
  int x20 = (int)floorf(sx2), y20 = (int)floorf(sy2);
  int x21 = min(x20 + 1, FW - 1), y21 = min(y20 + 1, FH - 1);
  float wx2 = sx2 - (float)x20, wy2 = sy2 - (float)y20;

  float a00 = (1.f - wx1) * (1.f - wy1), a01 = wx1 * (1.f - wy1);
  float a10 = (1.f - wx1) * wy1,         a11 = wx1 * wy1;
  float c00 = (1.f - wx2) * (1.f - wy2), c01 = wx2 * (1.f - wy2);
  float c10 = (1.f - wx2) * wy2,         c11 = wx2 * wy2;

  int c0 = cq * 16;
  const f16* b1 = t1 + (size_t)b * HWl * 128 + c0;
  const f16* b2 = t2 + (size_t)b * HWl * 128 + c0;
  const f16x8* p100 = (const f16x8*)&b1[(size_t)(y10 * FW + x10) * 128];
  const f16x8* p101 = (const f16x8*)&b1[(size_t)(y10 * FW + x11) * 128];
  const f16x8* p110 = (const f16x8*)&b1[(size_t)(y11 * FW + x10) * 128];
  const f16x8* p111 = (const f16x8*)&b1[(size_t)(y11 * FW + x11) * 128];
  const f16x8* p200 = (const f16x8*)&b2[(size_t)(y20 * FW + x20) * 128];
  const f16x8* p201 = (const f16x8*)&b2[(size_t)(y20 * FW + x21) * 128];
  const f16x8* p210 = (const f16x8*)&b2[(size_t)(y21 * FW + x20) * 128];
  const f16x8* p211 = (const f16x8*)&b2[(size_t)(y21 * FW + x21) * 128];

  f16* fp = fused + ((size_t)b * HWl + pix) * 288;
  f16* sp = src + ((size_t)b * HWl + pix) * 128;

#pragma unroll
  for (int h = 0; h < 2; ++h) {
    f16x8 u00 = p100[h], u01 = p101[h], u10 = p110[h], u11 = p111[h];
    f16x8 w00 = p200[h], w01 = p201[h], w10 = p210[h], w11 = p211[h];
    f16x8 r1, r2, rs;
#pragma unroll
    for (int k = 0; k < 8; ++k) {
      float v1 = (float)u00[k] * a00 + (float)u01[k] * a01
               + (float)u10[k] * a10 + (float)u11[k] * a11;
      float v2 = (float)w00[k] * c00 + (float)w01[k] * c01
               + (float)w10[k] * c10 + (float)w11[k] * c11;
      r1[k] = (f16)v1; r2[k] = (f16)v2; rs[k] = (f16)(0.5f * (v1 + v2));
    }
    *(f16x8*)(fp + c0 + h * 8) = r1;
    *(f16x8*)(fp + 128 + c0 + h * 8) = r2;
    *(f16x8*)(sp + c0 + h * 8) = rs;
  }

  if (cq == 0) {
    p = edge1 + (size_t)(b * Hh + y4) * Wh + x4;
    float e1v = 0.25f * (p[0] + p[1] + p[Wh] + p[Wh + 1]);
    p = edge2 + (size_t)(b * Hh + y4) * Wh + x4;
    float e2v = 0.25f * (p[0] + p[1] + p[Wh] + p[Wh + 1]);
    fp[256] = (f16)e1v;
    fp[257] = (f16)e2v;
    fp[258] = (f16)0.5f;
#pragma unroll
    for (int c = 259; c < 288; ++c) fp[c] = (f16)0.f;
  }
}

// ---------------------------------------------------------------------------
// Barrier-free LDS-free MFMA 3x3 conv, NHWC f16 — straight-line version.
// KS is a template param -> full K unroll; all loads are UNCONDITIONAL
// (clamped addresses) with cndmask zeroing -> compiler can batch loads
// far ahead of the MFMAs (deep ILP pipelining). Wave tile: M*16 px x NF*16 co.
// ---------------------------------------------------------------------------
template<int ACT, int M, int NF, int W, int KS>
__global__ __launch_bounds__(256) void k_conv3g(
    const f16* __restrict__ X, const f16* __restrict__ Wf,
    const float* __restrict__ bias, const float* __restrict__ bias2, int bsplit,
    f16* __restrict__ Out,
    int CoF, int Cs_in, int Cs_out, int Htot,
    int in_r0, int in_rows, int out_r0, int out_rows,
    int ogr0, int nrows, int coTiles)
{
  int wid = blockIdx.x * 4 + (threadIdx.x >> 6);
  int lane = threadIdx.x & 63;
  int l15 = lane & 15, l4 = lane >> 4;
  int pixTiles = nrows * W / (M * 16);
  if (wid >= pixTiles * coTiles) return;
  int coT = wid % coTiles;
  int pixT = wid / coTiles;
  int b = blockIdx.z;
  int base = pixT * (M * 16);
  int row = ogr0 + base / W;       // wave-uniform (16M | W)
  int colB = base % W;

  f32x4 acc[M][NF];
#pragma unroll
  for (int mf = 0; mf < M; ++mf)
#pragma unroll
    for (int nf = 0; nf < NF; ++nf) acc[mf][nf] = zero4();

  // Precompute clamped row pointers + validity (static-indexed, unrolled).
  const f16* rp[3]; bool rvv[3];
#pragma unroll
  for (int ky = 0; ky < 3; ++ky) {
    int srow = row + ky - 1;
    rvv[ky] = (srow >= 0 && srow < Htot);
    int crow = min(max(srow, in_r0), in_r0 + in_rows - 1);
    rp[ky] = X + ((size_t)(b * in_rows + (crow - in_r0)) * W) * Cs_in + l4 * 8;
  }
  // Precompute clamped column offsets + validity.
  int sc[3][M]; bool okc[3][M];
#pragma unroll
  for (int kx = 0; kx < 3; ++kx)
#pragma unroll
    for (int mf = 0; mf < M; ++mf) {
      int scol = colB + mf * 16 + l15 + kx - 1;
      okc[kx][mf] = (unsigned)scol < (unsigned)W;
      sc[kx][mf] = min(max(scol, 0), W - 1);
    }

  const f16* wb = Wf + (size_t)coT * NF * 512;

#pragma unroll
  for (int cs = 0; cs < KS; ++cs) {
#pragma unroll
    for (int ky = 0; ky < 3; ++ky) {
#pragma unroll
      for (int kx = 0; kx < 3; ++kx) {
        f16x8 Bf[NF];
#pragma unroll
        for (int nf = 0; nf < NF; ++nf)
          Bf[nf] = *(const f16x8*)&wb[((((size_t)(ky * 3 + kx) * KS + cs) * CoF + nf) * 64 + lane) * 8];
        f16x8 Af[M];
#pragma unroll
        for (int mf = 0; mf < M; ++mf) {
          f16x8 t = *(const f16x8*)&rp[ky][(size_t)sc[kx][mf] * Cs_in + cs * 32];
          Af[mf] = (rvv[ky] && okc[kx][mf]) ? t : zero8();
        }
#pragma unroll
        for (int mf = 0; mf < M; ++mf)
#pragma unroll
          for (int nf = 0; nf < NF; ++nf)
            acc[mf][nf] = __builtin_amdgcn_mfma_f32_16x16x32_f16(Af[mf], Bf[nf], acc[mf][nf], 0, 0, 0);
      }
    }
  }

  size_t rowoff = ((size_t)b * out_rows + (row - out_r0)) * W;
#pragma unroll
  for (int nf = 0; nf < NF; ++nf) {
    int co = coT * (NF * 16) + nf * 16 + l15;
    float bv = (co < bsplit) ? bias[co] : bias2[co - bsplit];
#pragma unroll
    for (int mf = 0; mf < M; ++mf) {
      int xo = colB + mf * 16 + l4 * 4;
#pragma unroll
      for (int rg = 0; rg < 4; ++rg) {
        float v = activ<ACT>(acc[mf][nf][rg] + bv);
        Out[(rowoff + xo + rg) * (size_t)Cs_out + co] = (f16)v;
      }
    }
  }
}

// ---------------------------------------------------------------------------
// 4x bilinear upsample NHWC f16: xbuf (B,96,160,128) -> U rows [u0, +urows).
// ---------------------------------------------------------------------------
__global__ __launch_bounds__(256) void k_up4_h(
    const f16* __restrict__ Xl, f16* __restrict__ U, int u0, int urows)
{
  int idx = blockIdx.x * blockDim.x + threadIdx.x;
  if (idx >= Bn * urows * Wh * 8) return;
  int cq = idx & 7;
  int x = (idx >> 3) % Wh;
  int r = ((idx >> 3) / Wh) % urows;
  int b = idx / (8 * Wh * urows);
  int R = u0 + r;

  float uy = ((float)R + 0.5f) * 0.25f - 0.5f;
  uy = fminf(fmaxf(uy, 0.f), (float)(FH - 1));
  int y0 = (int)floorf(uy);
  int y1 = min(y0 + 1, FH - 1);
  float fy = uy - (float)y0;
  float ux = ((float)x + 0.5f) * 0.25f - 0.5f;
  ux = fminf(fmaxf(ux, 0.f), (float)(FW - 1));
  int x0 = (int)floorf(ux);
  int x1 = min(x0 + 1, FW - 1);
  float fx = ux - (float)x0;

  const f16* xb = Xl + (size_t)b * HWl * 128 + cq * 16;
  const f16x8* c00 = (const f16x8*)&xb[(size_t)(y0 * FW + x0) * 128];
  const f16x8* c01 = (const f16x8*)&xb[(size_t)(y0 * FW + x1) * 128];
  const f16x8* c10 = (const f16x8*)&xb[(size_t)(y1 * FW + x0) * 128];
  const f16x8* c11 = (const f16x8*)&xb[(size_t)(y1 * FW + x1) * 128];
  f16* up = U + (((size_t)b * urows + r) * Wh + x) * 128 + cq * 16;
#pragma unroll
  for (int h = 0; h < 2; ++h) {
    f16x8 a = c00[h], bb = c01[h], cc = c10[h], dd = c11[h];
    f16x8 o;
#pragma unroll
    for (int jj = 0; jj < 8; ++jj) {
      float t0 = (float)a[jj] * (1.f - fx) + (float)bb[jj] * fx;
      float t1 = (float)cc[jj] * (1.f - fx) + (float)dd[jj] * fx;
      o[jj] = (f16)(t0 * (1.f - fy) + t1 * fy);
    }
    *(f16x8*)(up + h * 8) = o;
  }
}

// ---------------------------------------------------------------------------
// MFMA 1x1 conv (pure GEMM), KS-templated straight-line.
// ---------------------------------------------------------------------------
template<int ACT, int RES, int KS>
__global__ __launch_bounds__(256) void k_gemm1x1(
    const f16* __restrict__ X, const f16* __restrict__ Wf,
    const float* __restrict__ bias, f16* __restrict__ Out,
    int CoF, int Cs_in, int Cs_out, int Cr, int coTiles, int pixTiles)
{
  int wid = blockIdx.x * 4 + (threadIdx.x >> 6);
  int lane = threadIdx.x & 63;
  int total = pixTiles * coTiles;
  if (wid >= total) return;
  int coT = wid % coTiles;
  int pixT = wid / coTiles;
  int nfc = min(4, CoF - coT * 4);
  int l15 = lane & 15, l4 = lane >> 4;

  f32x4 acc[2][4];
#pragma unroll
  for (int mf = 0; mf < 2; ++mf)
#pragma unroll
    for (int nf = 0; nf < 4; ++nf) acc[mf][nf] = zero4();

  int pA0 = pixT * 32 + l15;
#pragma unroll
  for (int ks = 0; ks < KS; ++ks) {
    f16x8 a0 = *(const f16x8*)&X[(size_t)pA0 * Cs_in + ks * 32 + l4 * 8];
    f16x8 a1 = *(const f16x8*)&X[(size_t)(pA0 + 16) * Cs_in + ks * 32 + l4 * 8];
#pragma unroll
    for (int nf = 0; nf < 4; ++nf) {
      if (nf < nfc) {
        f16x8 bf = *(const f16x8*)&Wf[(((size_t)ks * CoF + coT * 4 + nf) * 64 + lane) * 8];
        acc[0][nf] = __builtin_amdgcn_mfma_f32_16x16x32_f16(a0, bf, acc[0][nf], 0, 0, 0);
        acc[1][nf] = __builtin_amdgcn_mfma_f32_16x16x32_f16(a1, bf, acc[1][nf], 0, 0, 0);
      }
    }
  }
#pragma unroll
  for (int nf = 0; nf < 4; ++nf) {
    if (nf < nfc) {
      int co = coT * 64 + nf * 16 + l15;
      if (co < Cr) {
        float bv = bias[co];
#pragma unroll
        for (int mf = 0; mf < 2; ++mf) {
          int p0 = pixT * 32 + mf * 16 + l4 * 4;
#pragma unroll
          for (int rg = 0; rg < 4; ++rg) {
            float v = activ<ACT>(acc[mf][nf][rg] + bv);
            size_t o = (size_t)(p0 + rg) * Cs_out + co;
            if (RES) v += (float)Out[o];
            Out[o] = (f16)v;
          }
        }
      }
    }
  }
}

// ---------------------------------------------------------------------------
// GroupNorm on NHWC f16, two stage.
// ---------------------------------------------------------------------------
__global__ __launch_bounds__(256) void k_gn_part_h(
    const f16* __restrict__ X, float* __restrict__ part)
{
  int s = blockIdx.x & 7;
  int g = (blockIdx.x >> 3) & 7;
  int b = blockIdx.x >> 6;
  int tid = threadIdx.x;
  const f16* Xp = X + (size_t)b * HWl * 128 + g * 16 + (tid & 1) * 8;
  float sum = 0.f, ss = 0.f;
  for (int p = s * 1920 + (tid >> 1); p < (s + 1) * 1920; p += 128) {
    f16x8 v = *(const f16x8*)&Xp[(size_t)p * 128];
#pragma unroll
    for (int jj = 0; jj < 8; ++jj) { float f = (float)v[jj]; sum += f; ss += f * f; }
  }
  __shared__ float sh1[256], sh2[256];
  sh1[tid] = sum; sh2[tid] = ss;
  __syncthreads();
  for (int st = 128; st > 0; st >>= 1) {
    if (tid < st) { sh1[tid] += sh1[tid + st]; sh2[tid] += sh2[tid + st]; }
    __syncthreads();
  }
  if (tid == 0) {
    part[((b * 8 + g) * 8 + s) * 2] = sh1[0];
    part[((b * 8 + g) * 8 + s) * 2 + 1] = sh2[0];
  }
}

__global__ __launch_bounds__(256) void k_gn_apply_h(
    const f16* __restrict__ X, const float* __restrict__ gw,
    const float* __restrict__ gb, const float* __restrict__ part,
    f16* __restrict__ Q)
{
  int idx = blockIdx.x * blockDim.x + threadIdx.x;
  int total = Bn * HWl * 16;
  if (idx >= total) return;
  int u = idx & 15;
  int pix = (idx >> 4) % HWl;
  int b = idx / (16 * HWl);
  int c0 = u * 8;
  int g = c0 >> 4;
  const float* pp = part + ((b * 8 + g) * 8) * 2;
  float sum = 0.f, ss = 0.f;
#pragma unroll
  for (int s = 0; s < 8; ++s) { sum += pp[s * 2]; ss += pp[s * 2 + 1]; }
  const float n = 16.f * HWl;
  float mean = sum / n;
  float var = ss / n - mean * mean;
  float inv = rsqrtf(var + 1e-5f);
  f16x8 v = *(const f16x8*)&X[((size_t)b * HWl + pix) * 128 + c0];
  f16x8 r;
#pragma unroll
  for (int jj = 0; jj < 8; ++jj) {
    int c = c0 + jj;
    r[jj] = (f16)(((float)v[jj] - mean) * (gw[c] * inv) + gb[c]);
  }
  *(f16x8*)&Q[((size_t)b * HWl + pix) * 128 + c0] = r;
}

// softmax over the 9 points; attn NHWC [b][pix][48]
__global__ __launch_bounds__(256) void k_softmax9_h(f16* __restrict__ a)
{
  int idx = blockIdx.x * blockDim.x + threadIdx.x;
  if (idx >= Bn * NHd * HWl) return;
  int pix = idx % HWl;
  int head = (idx / HWl) & 3;
  int b = idx / (HWl * NHd);
  f16* base = a + ((size_t)b * HWl + pix) * 48 + head * 9;
  float v[9];
  float m = -1e30f;
#pragma unroll
  for (int p0 = 0; p0 < 9; ++p0) { v[p0] = (float)base[p0]; m = fmaxf(m, v[p0]); }
  float s = 0.f;
#pragma unroll
  for (int p0 = 0; p0 < 9; ++p0) { v[p0] = expf(v[p0] - m); s += v[p0]; }
  float inv = 1.f / s;
#pragma unroll
  for (int p0 = 0; p0 < 9; ++p0) base[p0] = (f16)(v[p0] * inv);
}

// ---------------------------------------------------------------------------
// Deformable sampling, NHWC. Thread per (b, head, pix), 32 head-channels.
// ---------------------------------------------------------------------------
__global__ __launch_bounds__(256) void k_deform_h(
    const f16* __restrict__ vals, const f16* __restrict__ off,
    const f16* __restrict__ attn, f16* __restrict__ outa)
{
  int idx = blockIdx.x * blockDim.x + threadIdx.x;
  if (idx >= Bn * NHd * HWl) return;
  int pix = idx % HWl;
  int head = (idx / HWl) & 3;
  int b = idx / (HWl * NHd);
  int j = pix % FW, i = pix / FW;

  const float kx = (float)FW / (float)(FW - 1);
  const float ky = (float)FH / (float)(FH - 1);
  const f16* vb = vals + (size_t)b * HWl * 128 + head * 32;
  const f16* ab = attn + ((size_t)b * HWl + pix) * 48 + head * 9;
  const f16* ob = off + ((size_t)b * HWl + pix) * 80 + head * 18;

  float acc[32];
#pragma unroll
  for (int k = 0; k < 32; ++k) acc[k] = 0.f;

#pragma unroll
  for (int p0 = 0; p0 < 9; ++p0) {
    float ox = (float)ob[p0 * 2];
    float oy = (float)ob[p0 * 2 + 1];
    float aw = (float)ab[p0];
    float xf = ((float)j + ox) * kx - 0.5f;
    float yf = ((float)i + oy) * ky - 0.5f;
    xf = fminf(fmaxf(xf, 0.f), (float)(FW - 1));
    yf = fminf(fmaxf(yf, 0.f), (float)(FH - 1));
    int x0 = (int)floorf(xf), y0 = (int)floorf(yf);
    int x1 = min(x0 + 1, FW - 1), y1 = min(y0 + 1, FH - 1);
    float fx = xf - (float)x0, fy = yf - (float)y0;
    float w00 = aw * (1.f - fx) * (1.f - fy);
    float w01 = aw * fx * (1.f - fy);
    float w10 = aw * (1.f - fx) * fy;
    float w11 = aw * fx * fy;
    const f16x8* c00 = (const f16x8*)&vb[(size_t)(y0 * FW + x0) * 128];
    const f16x8* c01 = (const f16x8*)&vb[(size_t)(y0 * FW + x1) * 128];
    const f16x8* c10 = (const f16x8*)&vb[(size_t)(y1 * FW + x0) * 128];
    const f16x8* c11 = (const f16x8*)&vb[(size_t)(y1 * FW + x1) * 128];
#pragma unroll
    for (int k8 = 0; k8 < 4; ++k8) {
      f16x8 a = c00[k8], bb = c01[k8], cc = c10[k8], dd = c11[k8];
#pragma unroll
      for (int jj = 0; jj < 8; ++jj)
        acc[k8 * 8 + jj] += w00 * (float)a[jj] + w01 * (float)bb[jj]
                          + w10 * (float)cc[jj] + w11 * (float)dd[jj];
    }
  }
  f16* op = outa + ((size_t)b * HWl + pix) * 128 + head * 32;
#pragma unroll
  for (int k = 0; k < 32; ++k) op[k] = (f16)acc[k];
}

// ---------------------------------------------------------------------------
// dec2: 32->3 conv from NHWC f16 window + sigmoid, NCHW f32 out rows [c0,+R).
// ---------------------------------------------------------------------------
__global__ __launch_bounds__(256) void k_dec2_h(
    const f16* __restrict__ Xb, const float* __restrict__ w,
    const float* __restrict__ bias, float* __restrict__ out,
    int c0, int b0, int brows, int R)
{
  int idx = blockIdx.x * blockDim.x + threadIdx.x;
  if (idx >= Bn * R * Wh) return;
  int x = idx % Wh;
  int y = c0 + (idx / Wh) % R;
  int b = idx / (Wh * R);
  float a0 = bias[0], a1 = bias[1], a2 = bias[2];
#pragma unroll
  for (int ky = 0; ky < 3; ++ky) {
    int gy = y + ky - 1;
    if (gy < 0 || gy >= Hh) continue;
#pragma unroll
    for (int kxx = 0; kxx < 3; ++kxx) {
      int gx = x + kxx - 1;
      if (gx < 0 || gx >= Wh) continue;
      int tap = ky * 3 + kxx;
      const f16* px = Xb + ((size_t)(b * brows + (gy - b0)) * Wh + gx) * 32;
#pragma unroll
      for (int k8 = 0; k8 < 4; ++k8) {
        f16x8 v = *(const f16x8*)&px[k8 * 8];
#pragma unroll
        for (int jj = 0; jj < 8; ++jj) {
          int ci = k8 * 8 + jj;
          float f = (float)v[jj];
          a0 += f * w[(0 * 32 + ci) * 9 + tap];
          a1 += f * w[(1 * 32 + ci) * 9 + tap];
          a2 += f * w[(2 * 32 + ci) * 9 + tap];
        }
      }
    }
  }
  size_t o = ((size_t)(b * 3 + 0) * Hh + y) * Wh + x;
  out[o] = 1.f / (1.f + expf(-a0));
  out[o + (size_t)Hh * Wh] = 1.f / (1.f + expf(-a1));
  out[o + (size_t)2 * Hh * Wh] = 1.f / (1.f + expf(-a2));
}

// ---------------------------------------------------------------------------
extern "C" void kernel_launch(void* const* d_in, const int* in_sizes, int n_in,
                              void* d_out, int out_size, void* d_ws, size_t ws_size,
                              hipStream_t stream) {
  (void)in_sizes; (void)n_in; (void)out_size; (void)ws_size;
  const float* feat1  = (const float*)d_in[0];
  const float* feat2  = (const float*)d_in[1];
  const float* flowf  = (const float*)d_in[2];
  const float* flowb  = (const float*)d_in[3];
  const float* edge1  = (const float*)d_in[4];
  const float* edge2  = (const float*)d_in[5];
  const float* fuse_w0 = (const float*)d_in[6];
  const float* fuse_b0 = (const float*)d_in[7];
  const float* fuse_w1 = (const float*)d_in[8];
  const float* fuse_b1 = (const float*)d_in[9];
  const float* gn_g   = (const float*)d_in[10];
  const float* gn_b   = (const float*)d_in[11];
  const float* off_w0 = (const float*)d_in[12];
  const float* off_b0 = (const float*)d_in[13];
  const float* off_w1 = (const float*)d_in[14];
  const float* off_b1 = (const float*)d_in[15];
  const float* aw_w0  = (const float*)d_in[16];
  const float* aw_b0  = (const float*)d_in[17];
  const float* aw_w1  = (const float*)d_in[18];
  const float* aw_b1  = (const float*)d_in[19];
  const float* val_w  = (const float*)d_in[20];
  const float* val_b  = (const float*)d_in[21];
  const float* out_w  = (const float*)d_in[22];
  const float* out_b  = (const float*)d_in[23];
  const float* ffn_w0 = (const float*)d_in[24];
  const float* ffn_b0 = (const float*)d_in[25];
  const float* ffn_w1 = (const float*)d_in[26];
  const float* ffn_b1 = (const float*)d_in[27];
  const float* dec_w0 = (const float*)d_in[28];
  const float* dec_b0 = (const float*)d_in[29];
  const float* dec_w1 = (const float*)d_in[30];
  const float* dec_b1 = (const float*)d_in[31];
  const float* dec_w2 = (const float*)d_in[32];
  const float* dec_b2 = (const float*)d_in[33];
  float* out = (float*)d_out;

  // ---- workspace layout (f16 units). Weights FIRST (decoder overlay can
  // never clobber them). Total ~75 MB.
  f16* ws16 = (f16*)d_ws;
  size_t o = 0;
  auto alloc = [&](size_t n) { f16* p = ws16 + o; o += (n + 7) & ~(size_t)7; return p; };
  f16* xbuf  = alloc((size_t)2 * HWl * 128);
  f16* wfF0 = alloc(9 * 9 * 8 * 512);
  f16* wfF1 = alloc(9 * 4 * 8 * 512);
  f16* wfOA = alloc(9 * 4 * 16 * 512);          // off0 (cf 0..7) + aw0 (cf 8..15)
  f16* wfD0 = alloc(9 * 4 * 4 * 512);
  f16* wfD1 = alloc(9 * 2 * 2 * 512);
  f16* w1O  = alloc(4 * 5 * 512);
  f16* w1A  = alloc(4 * 3 * 512);
  f16* w1V  = alloc(4 * 8 * 512);
  f16* w1U  = alloc(4 * 8 * 512);
  f16* w1G0 = alloc(4 * 16 * 512);
  f16* w1G1 = alloc(8 * 8 * 512);
  float* gnp = (float*)alloc(512);
  f16* pool  = ws16 + o;                        // decoder overlay starts here
  f16* regA  = alloc((size_t)2 * HWl * 288);    // fused / t_oa / ffn_t
  f16* regB  = alloc((size_t)2 * HWl * 128);    // source / out_attn
  f16* regC  = alloc((size_t)2 * HWl * 128);    // fuse0-out / qb
  f16* offb  = alloc((size_t)2 * HWl * 80);
  f16* attnb = alloc((size_t)2 * HWl * 48);
  f16* regF  = alloc((size_t)2 * HWl * 131);    // valsb
  f16* featT1 = alloc((size_t)2 * HWl * 128);
  f16* featT2 = alloc((size_t)2 * HWl * 128);

  f16* fused = regA;
  f16* t_oa  = regA;        // merged off/aw 3x3 out, 256 ch
  f16* ffn_t = regA;
  f16* src_h = regB;
  f16* out_attn = regB;
  f16* tmp_h = regC;
  f16* qb    = regC;
  f16* valsb = regF;
  // Decoder overlay over pool (dead after FFN). 96-row chunks:
  // bufU 2*103*640*128 = 16.88M ; bufA 2*100*640*64 = 8.19M ;
  // bufB 2*99*640*32 = 4.06M ; total 29.12M <= pool 32.53M f16.
  f16* bufU = pool;
  f16* bufA = bufU + (size_t)2 * 103 * 640 * 128;
  f16* bufB = bufA + (size_t)2 * 100 * 640 * 64;

  dim3 blk(256);
  auto pg = [](long n) { return dim3((unsigned)((n + 255) / 256)); };
  auto cg = [](int pixTiles, int coTiles) {
    return dim3((unsigned)((pixTiles * coTiles + 3) / 4), 1, 2);
  };
  const int BIG = 1 << 30;

  // ---- merged weight prep ----
  PrepArgs pa;
  int pb = 0;
  auto addj = [&](int k, const float* w, f16* wf, int Cout, int cing, int coutg,
                  int KS, int CoF, int taps, int CoFt, int cf0) {
    pa.j[k] = PrepJob{w, wf, Cout, cing, coutg, KS, CoF, taps, CoFt, cf0, pb};
    pb += (taps * KS * CoF * 64 + 255) / 256;
  };
  addj(0, fuse_w0, wfF0, 128, 259, 128, 9, 8, 9, 8, 0);
  addj(1, fuse_w1, wfF1, 128, 128, 128, 4, 8, 9, 8, 0);
  addj(2, off_w0, wfOA, 128, 32, 32, 4, 8, 9, 16, 0);
  addj(3, aw_w0,  wfOA, 128, 32, 32, 4, 8, 9, 16, 8);
  addj(4, dec_w0, wfD0, 64, 128, 64, 4, 4, 9, 4, 0);
  addj(5, dec_w1, wfD1, 32, 64, 32, 2, 2, 9, 2, 0);
  addj(6, off_w1, w1O, 72, 128, 72, 4, 5, 1, 5, 0);
  addj(7, aw_w1,  w1A, 36, 128, 36, 4, 3, 1, 3, 0);
  addj(8, val_w,  w1V, 128, 128, 128, 4, 8, 1, 8, 0);
  addj(9, out_w,  w1U, 128, 128, 128, 4, 8, 1, 8, 0);
  addj(10, ffn_w0, w1G0, 256, 128, 256, 4, 16, 1, 16, 0);
  addj(11, ffn_w1, w1G1, 128, 256, 128, 8, 8, 1, 8, 0);
  k_wprep_all<<<dim3((unsigned)pb), blk, 0, stream>>>(pa);

  // ---- 0. feats -> NHWC f16 ----
  k_tr_h<<<pg(2L * Bn * HWl * 8), blk, 0, stream>>>(feat1, feat2, featT1, featT2);
  // ---- 1. warp + concat + source ----
  k_warp_fuse_h<<<pg((long)Bn * HWl * 8), blk, 0, stream>>>(featT1, featT2, flowf, flowb,
                                                            edge1, edge2, fused, src_h);
  // ---- 2-3. fuse convs (straight-line, clamp+select loads) ----
  k_conv3g<1, 2, 2, 160, 9><<<cg(480, 4), blk, 0, stream>>>(fused, wfF0, fuse_b0, fuse_b0, BIG,
      tmp_h, 8, 288, 128, FH, 0, FH, 0, FH, 0, FH, 4);
  k_conv3g<1, 2, 2, 160, 4><<<cg(480, 4), blk, 0, stream>>>(tmp_h, wfF1, fuse_b1, fuse_b1, BIG,
      xbuf, 8, 128, 128, FH, 0, FH, 0, FH, 0, FH, 4);
  // ---- 4. group norm ----
  k_gn_part_h<<<dim3(128), blk, 0, stream>>>(xbuf, gnp);
  k_gn_apply_h<<<pg(2L * HWl * 16), blk, 0, stream>>>(xbuf, gn_g, gn_b, gnp, qb);
  // ---- 5. merged off0+aw0 grouped 3x3 (256 out ch, dual bias, NF=4) ----
  k_conv3g<1, 2, 4, 160, 4><<<cg(480, 4), blk, 0, stream>>>(qb, wfOA, off_b0, aw_b0, 128,
      t_oa, 16, 128, 256, FH, 0, FH, 0, FH, 0, FH, 4);
  // ---- 6-8. 1x1 heads + softmax ----
  k_gemm1x1<0, 0, 4><<<dim3(480), blk, 0, stream>>>(t_oa, w1O, off_b1, offb,
      5, 256, 80, 72, 2, 960);
  k_gemm1x1<0, 0, 4><<<dim3(240), blk, 0, stream>>>(t_oa + 128, w1A, aw_b1, attnb,
      3, 256, 48, 36, 1, 960);
  k_softmax9_h<<<pg(2L * NHd * HWl), blk, 0, stream>>>(attnb);
  // ---- 9. vals ----
  k_gemm1x1<0, 0, 4><<<dim3(480), blk, 0, stream>>>(src_h, w1V, val_b, valsb,
      8, 128, 128, 128, 2, 960);
  // ---- 10. deform ----
  k_deform_h<<<pg(2L * NHd * HWl), blk, 0, stream>>>(valsb, offb, attnb, out_attn);
  // ---- 11. out-proj (residual into xbuf) ----
  k_gemm1x1<0, 1, 4><<<dim3(480), blk, 0, stream>>>(out_attn, w1U, out_b, xbuf,
      8, 128, 128, 128, 2, 960);
  // ---- 12-13. FFN ----
  k_gemm1x1<2, 0, 4><<<dim3(960), blk, 0, stream>>>(xbuf, w1G0, ffn_b0, ffn_t,
      16, 128, 256, 256, 4, 960);
  k_gemm1x1<0, 1, 8><<<dim3(480), blk, 0, stream>>>(ffn_t, w1G1, ffn_b1, xbuf,
      8, 256, 128, 128, 2, 960);

  // ---- 14. decoder, 4 chunks of 96 rows: up4 -> dec0 -> dec1 -> dec2 ----
  for (int c0 = 0; c0 < Hh; c0 += 96) {
    int c1 = c0 + 96;
    int a0 = c0 - 2 > 0 ? c0 - 2 : 0;
    int a1 = c1 + 2 < Hh ? c1 + 2 : Hh;
    int b0 = c0 - 1 > 0 ? c0 - 1 : 0;
    int b1 = c1 + 1 < Hh ? c1 + 1 : Hh;
    int u0 = a0 - 1 > 0 ? a0 - 1 : 0;
    int u1 = a1 + 1 < Hh ? a1 + 1 : Hh;
    int ar = a1 - a0, br = b1 - b0, ur = u1 - u0;
    // upsample rows [u0,u1) -> bufU
    k_up4_h<<<pg(2L * ur * Wh * 8), blk, 0, stream>>>(xbuf, bufU, u0, ur);
    // dec0: 128->64, rows [a0,a1) -> bufA  (M=4, NF=4, KS=4)
    k_conv3g<1, 4, 4, 640, 4><<<cg(ar * 10, 1), blk, 0, stream>>>(bufU, wfD0, dec_b0, dec_b0, BIG,
        bufA, 4, 128, 64, Hh, u0, ur, a0, ar, a0, ar, 1);
    // dec1: 64->32, rows [b0,b1) -> bufB  (M=4, NF=2, KS=2)
    k_conv3g<1, 4, 2, 640, 2><<<cg(br * 10, 1), blk, 0, stream>>>(bufA, wfD1, dec_b1, dec_b1, BIG,
        bufB, 2, 64, 32, Hh, a0, ar, b0, br, b0, br, 1);
    // dec2: 32->3 + sigmoid -> out rows [c0,c1)
    k_dec2_h<<<pg(2L * 96 * Wh), blk, 0, stream>>>(bufB, dec_w2, dec_b2, out,
                                                   c0, b0, br, 96);
  }
}

// Round 9
// 698.289 us; speedup vs baseline: 1.1252x; 1.0612x over previous
//
#include <hip/hip_runtime.h>

typedef _Float16 f16;
typedef _Float16 f16x8 __attribute__((ext_vector_type(8)));
typedef float f32x4 __attribute__((ext_vector_type(4)));

constexpr int Bn = 2, Cn = 128, FH = 96, FW = 160, Hh = 384, Wh = 640;
constexpr int HWl = FH * FW;   // 15360
constexpr int NHd = 4, NPt = 9;

#define DEVINL __device__ __forceinline__

DEVINL f32x4 zero4() { f32x4 z; z[0] = 0.f; z[1] = 0.f; z[2] = 0.f; z[3] = 0.f; return z; }
DEVINL f16x8 zero8() {
  f16x8 z;
#pragma unroll
  for (int j = 0; j < 8; ++j) z[j] = (f16)0.f;
  return z;
}

template<int ACT> DEVINL float activ(float v) {
  if (ACT == 1) return v >= 0.f ? v : 0.1f * v;                           // leaky relu
  if (ACT == 2) return 0.5f * v * (1.f + erff(v * 0.70710678118654752f)); // exact gelu
  if (ACT == 3) return 1.f / (1.f + expf(-v));                            // sigmoid
  return v;
}

// ---------------------------------------------------------------------------
// Merged weight prep (12 jobs, one launch). 3x3 jobs produce
// [tap][ks][CoFt: cf0+cf][lane][8]; 1x1 jobs [ks][cf][lane][8].
// k = (lane>>4)*8+j (A-frag convention). Grouped convs zero-padded to full K.
// ---------------------------------------------------------------------------
struct PrepJob { const float* w; f16* wf; int Cout, cin_g, cout_g, KS, CoF, taps, CoFt, cf0, blk0; };
struct PrepArgs { PrepJob j[12]; };

__global__ __launch_bounds__(256) void k_wprep_all(PrepArgs a)
{
  int jb = 0;
#pragma unroll
  for (int t = 1; t < 12; ++t) if ((int)blockIdx.x >= a.j[t].blk0) jb = t;
  PrepJob J = a.j[jb];
  int idx = (blockIdx.x - J.blk0) * 256 + threadIdx.x;
  int total = J.taps * J.KS * J.CoF * 64;
  if (idx >= total) return;
  int lane = idx & 63;
  int rest = idx >> 6;
  int cf = rest % J.CoF;
  int rest2 = rest / J.CoF;
  int ks = rest2 % J.KS;
  int tap = rest2 / J.KS;
  int co = cf * 16 + (lane & 15);
  f16x8 v = zero8();
#pragma unroll
  for (int j = 0; j < 8; ++j) {
    int cip = ks * 32 + (lane >> 4) * 8 + j;
    int cil = cip - (co / J.cout_g) * J.cin_g;
    float x = 0.f;
    if (co < J.Cout && cil >= 0 && cil < J.cin_g)
      x = J.w[((size_t)co * J.cin_g + cil) * J.taps + tap];
    v[j] = (f16)x;
  }
  size_t oidx = (((size_t)tap * J.KS + ks) * J.CoFt + J.cf0 + cf) * 64 + lane;
  *(f16x8*)&J.wf[oidx * 8] = v;
}

// ---------------------------------------------------------------------------
// NCHW f32 -> NHWC f16 transpose for feat1+feat2.
// ---------------------------------------------------------------------------
__global__ __launch_bounds__(256) void k_tr_h(
    const float* __restrict__ feat1, const float* __restrict__ feat2,
    f16* __restrict__ t1, f16* __restrict__ t2)
{
  int idx = blockIdx.x * blockDim.x + threadIdx.x;
  if (idx >= 2 * Bn * HWl * 8) return;
  int cq = idx & 7;
  int pix = (idx >> 3) % HWl;
  int z = idx / (8 * HWl);
  int b = z & 1;
  const float* src = (z >> 1) ? feat2 : feat1;
  f16* dst = (z >> 1) ? t2 : t1;
  int c0 = cq * 16;
  f16x8 v0, v1;
#pragma unroll
  for (int j = 0; j < 8; ++j) {
    v0[j] = (f16)src[(size_t)(b * Cn + c0 + j) * HWl + pix];
    v1[j] = (f16)src[(size_t)(b * Cn + c0 + 8 + j) * HWl + pix];
  }
  f16* dp = dst + ((size_t)b * HWl + pix) * 128 + c0;
  *(f16x8*)dp = v0;
  *(f16x8*)(dp + 8) = v1;
}

// ---------------------------------------------------------------------------
// Warp + concat + source, NHWC f16, cq-fastest lanes (coalesced).
// ---------------------------------------------------------------------------
__global__ __launch_bounds__(256) void k_warp_fuse_h(
    const f16* __restrict__ t1, const f16* __restrict__ t2,
    const float* __restrict__ flowf, const float* __restrict__ flowb,
    const float* __restrict__ edge1, const float* __restrict__ edge2,
    f16* __restrict__ fused, f16* __restrict__ src)
{
  int idx = blockIdx.x * blockDim.x + threadIdx.x;
  if (idx >= Bn * HWl * 8) return;
  int cq = idx & 7;
  int pix = (idx >> 3) % HWl;
  int b = idx / (8 * HWl);
  int j = pix % FW;
  int i = pix / FW;

  const int y4 = 4 * i + 1, x4 = 4 * j + 1;
  const float* p;
  p = flowf + (size_t)((b * 2 + 0) * Hh + y4) * Wh + x4;
  float fx1 = 0.03125f * (p[0] + p[1] + p[Wh] + p[Wh + 1]);
  p = flowf + (size_t)((b * 2 + 1) * Hh + y4) * Wh + x4;
  float fy1 = 0.03125f * (p[0] + p[1] + p[Wh] + p[Wh + 1]);
  p = flowb + (size_t)((b * 2 + 0) * Hh + y4) * Wh + x4;
  float fx2 = 0.03125f * (p[0] + p[1] + p[Wh] + p[Wh + 1]);
  p = flowb + (size_t)((b * 2 + 1) * Hh + y4) * Wh + x4;
  float fy2 = 0.03125f * (p[0] + p[1] + p[Wh] + p[Wh + 1]);

  float sx1 = fminf(fmaxf((float)j + fx1, 0.f), (float)(FW - 1));
  float sy1 = fminf(fmaxf((float)i + fy1, 0.f), (float)(FH - 1));
  float sx2 = fminf(fmaxf((float)j + fx2, 0.f), (float)(FW - 1));
  float sy2 = fminf(fmaxf((float)i + fy2, 0.f), (float)(FH - 1));

  int x10 = (int)floorf(sx1), y10 = (int)floorf(sy1);
  int x11 = min(x10 + 1, FW - 1), y11 = min(y10 + 1, FH - 1);
  float wx1 = sx1 - (float)x10, wy1 = sy1 - (float)y10;
  int x20 = (int)floorf(sx2), y20 = (int)floorf(sy2);
  int x21 = min(x20 + 1, FW - 1), y21 = min(y20 + 1, FH - 1);
  float wx2 = sx2 - (float)x20, wy2 = sy2 - (float)y20;

  float a00 = (1.f - wx1) * (1.f - wy1), a01 = wx1 * (1.f - wy1);
  float a10 = (1.f - wx1) * wy1,         a11 = wx1 * wy1;
  float c00 = (1.f - wx2) * (1.f - wy2), c01 = wx2 * (1.f - wy2);
  float c10 = (1.f - wx2) * wy2,         c11 = wx2 * wy2;

  int c0 = cq * 16;
  const f16* b1 = t1 + (size_t)b * HWl * 128 + c0;
  const f16* b2 = t2 + (size_t)b * HWl * 128 + c0;
  const f16x8* p100 = (const f16x8*)&b1[(size_t)(y10 * FW + x10) * 128];
  const f16x8* p101 = (const f16x8*)&b1[(size_t)(y10 * FW + x11) * 128];
  const f16x8* p110 = (const f16x8*)&b1[(size_t)(y11 * FW + x10) * 128];
  const f16x8* p111 = (const f16x8*)&b1[(size_t)(y11 * FW + x11) * 128];
  const f16x8* p200 = (const f16x8*)&b2[(size_t)(y20 * FW + x20) * 128];
  const f16x8* p201 = (const f16x8*)&b2[(size_t)(y20 * FW + x21) * 128];
  const f16x8* p210 = (const f16x8*)&b2[(size_t)(y21 * FW + x20) * 128];
  const f16x8* p211 = (const f16x8*)&b2[(size_t)(y21 * FW + x21) * 128];

  f16* fp = fused + ((size_t)b * HWl + pix) * 288;
  f16* sp = src + ((size_t)b * HWl + pix) * 128;

#pragma unroll
  for (int h = 0; h < 2; ++h) {
    f16x8 u00 = p100[h], u01 = p101[h], u10 = p110[h], u11 = p111[h];
    f16x8 w00 = p200[h], w01 = p201[h], w10 = p210[h], w11 = p211[h];
    f16x8 r1, r2, rs;
#pragma unroll
    for (int k = 0; k < 8; ++k) {
      float v1 = (float)u00[k] * a00 + (float)u01[k] * a01
               + (float)u10[k] * a10 + (float)u11[k] * a11;
      float v2 = (float)w00[k] * c00 + (float)w01[k] * c01
               + (float)w10[k] * c10 + (float)w11[k] * c11;
      r1[k] = (f16)v1; r2[k] = (f16)v2; rs[k] = (f16)(0.5f * (v1 + v2));
    }
    *(f16x8*)(fp + c0 + h * 8) = r1;
    *(f16x8*)(fp + 128 + c0 + h * 8) = r2;
    *(f16x8*)(sp + c0 + h * 8) = rs;
  }

  if (cq == 0) {
    p = edge1 + (size_t)(b * Hh + y4) * Wh + x4;
    float e1v = 0.25f * (p[0] + p[1] + p[Wh] + p[Wh + 1]);
    p = edge2 + (size_t)(b * Hh + y4) * Wh + x4;
    float e2v = 0.25f * (p[0] + p[1] + p[Wh] + p[Wh + 1]);
    fp[256] = (f16)e1v;
    fp[257] = (f16)e2v;
    fp[258] = (f16)0.5f;
#pragma unroll
    for (int c = 259; c < 288; ++c) fp[c] = (f16)0.f;
  }
}

// ---------------------------------------------------------------------------
// Barrier-free LDS-free MFMA 3x3 conv, NHWC f16 — batched-load version.
// Per (cs, ky) group: ALL A frags (3kx x M) and ALL B frags (3kx x NF) are
// loaded into statically-indexed register arrays FIRST, then 3*M*NF MFMAs.
// __launch_bounds__(256,2) lets the allocator keep them live (<=256 VGPR).
// Loads unconditional (clamped) + cndmask zero; no barriers, no LDS.
// ---------------------------------------------------------------------------
template<int ACT, int M, int NF, int W, int KS>
__global__ __launch_bounds__(256, 2) void k_conv3g(
    const f16* __restrict__ X, const f16* __restrict__ Wf,
    const float* __restrict__ bias, const float* __restrict__ bias2, int bsplit,
    f16* __restrict__ Out,
    int CoF, int Cs_in, int Cs_out, int Htot,
    int in_r0, int in_rows, int out_r0, int out_rows,
    int ogr0, int nrows, int coTiles)
{
  int wid = blockIdx.x * 4 + (threadIdx.x >> 6);
  int lane = threadIdx.x & 63;
  int l15 = lane & 15, l4 = lane >> 4;
  int pixTiles = nrows * W / (M * 16);
  if (wid >= pixTiles * coTiles) return;
  int coT = wid % coTiles;
  int pixT = wid / coTiles;
  int b = blockIdx.z;
  int base = pixT * (M * 16);
  int row = ogr0 + base / W;       // wave-uniform (16M | W)
  int colB = base % W;

  f32x4 acc[M][NF];
#pragma unroll
  for (int mf = 0; mf < M; ++mf)
#pragma unroll
    for (int nf = 0; nf < NF; ++nf) acc[mf][nf] = zero4();

  // Clamped row pointers + validity.
  const f16* rp[3]; bool rvv[3];
#pragma unroll
  for (int ky = 0; ky < 3; ++ky) {
    int srow = row + ky - 1;
    rvv[ky] = (srow >= 0 && srow < Htot);
    int crow = min(max(srow, in_r0), in_r0 + in_rows - 1);
    rp[ky] = X + ((size_t)(b * in_rows + (crow - in_r0)) * W) * Cs_in + l4 * 8;
  }
  // Clamped column offsets + validity.
  int sc[3][M]; bool okc[3][M];
#pragma unroll
  for (int kx = 0; kx < 3; ++kx)
#pragma unroll
    for (int mf = 0; mf < M; ++mf) {
      int scol = colB + mf * 16 + l15 + kx - 1;
      okc[kx][mf] = (unsigned)scol < (unsigned)W;
      sc[kx][mf] = min(max(scol, 0), W - 1);
    }

  const f16* wb = Wf + (size_t)coT * NF * 512;

#pragma unroll
  for (int cs = 0; cs < KS; ++cs) {
#pragma unroll
    for (int ky = 0; ky < 3; ++ky) {
      // ---- batch-load ALL fragments for this (cs, ky) group ----
      f16x8 Af[3][M];
#pragma unroll
      for (int kx = 0; kx < 3; ++kx)
#pragma unroll
        for (int mf = 0; mf < M; ++mf) {
          f16x8 t = *(const f16x8*)&rp[ky][(size_t)sc[kx][mf] * Cs_in + cs * 32];
          Af[kx][mf] = (rvv[ky] && okc[kx][mf]) ? t : zero8();
        }
      f16x8 Bf[3][NF];
#pragma unroll
      for (int kx = 0; kx < 3; ++kx)
#pragma unroll
        for (int nf = 0; nf < NF; ++nf)
          Bf[kx][nf] = *(const f16x8*)&wb[((((size_t)(ky * 3 + kx) * KS + cs) * CoF + nf) * 64 + lane) * 8];
      // ---- MFMA burst ----
#pragma unroll
      for (int kx = 0; kx < 3; ++kx)
#pragma unroll
        for (int mf = 0; mf < M; ++mf)
#pragma unroll
          for (int nf = 0; nf < NF; ++nf)
            acc[mf][nf] = __builtin_amdgcn_mfma_f32_16x16x32_f16(Af[kx][mf], Bf[kx][nf], acc[mf][nf], 0, 0, 0);
    }
  }

  size_t rowoff = ((size_t)b * out_rows + (row - out_r0)) * W;
#pragma unroll
  for (int nf = 0; nf < NF; ++nf) {
    int co = coT * (NF * 16) + nf * 16 + l15;
    float bv = (co < bsplit) ? bias[co] : bias2[co - bsplit];
#pragma unroll
    for (int mf = 0; mf < M; ++mf) {
      int xo = colB + mf * 16 + l4 * 4;
#pragma unroll
      for (int rg = 0; rg < 4; ++rg) {
        float v = activ<ACT>(acc[mf][nf][rg] + bv);
        Out[(rowoff + xo + rg) * (size_t)Cs_out + co] = (f16)v;
      }
    }
  }
}

// ---------------------------------------------------------------------------
// 4x bilinear upsample NHWC f16: xbuf (B,96,160,128) -> U rows [u0, +urows).
// ---------------------------------------------------------------------------
__global__ __launch_bounds__(256) void k_up4_h(
    const f16* __restrict__ Xl, f16* __restrict__ U, int u0, int urows)
{
  int idx = blockIdx.x * blockDim.x + threadIdx.x;
  if (idx >= Bn * urows * Wh * 8) return;
  int cq = idx & 7;
  int x = (idx >> 3) % Wh;
  int r = ((idx >> 3) / Wh) % urows;
  int b = idx / (8 * Wh * urows);
  int R = u0 + r;

  float uy = ((float)R + 0.5f) * 0.25f - 0.5f;
  uy = fminf(fmaxf(uy, 0.f), (float)(FH - 1));
  int y0 = (int)floorf(uy);
  int y1 = min(y0 + 1, FH - 1);
  float fy = uy - (float)y0;
  float ux = ((float)x + 0.5f) * 0.25f - 0.5f;
  ux = fminf(fmaxf(ux, 0.f), (float)(FW - 1));
  int x0 = (int)floorf(ux);
  int x1 = min(x0 + 1, FW - 1);
  float fx = ux - (float)x0;

  const f16* xb = Xl + (size_t)b * HWl * 128 + cq * 16;
  const f16x8* c00 = (const f16x8*)&xb[(size_t)(y0 * FW + x0) * 128];
  const f16x8* c01 = (const f16x8*)&xb[(size_t)(y0 * FW + x1) * 128];
  const f16x8* c10 = (const f16x8*)&xb[(size_t)(y1 * FW + x0) * 128];
  const f16x8* c11 = (const f16x8*)&xb[(size_t)(y1 * FW + x1) * 128];
  f16* up = U + (((size_t)b * urows + r) * Wh + x) * 128 + cq * 16;
#pragma unroll
  for (int h = 0; h < 2; ++h) {
    f16x8 a = c00[h], bb = c01[h], cc = c10[h], dd = c11[h];
    f16x8 o;
#pragma unroll
    for (int jj = 0; jj < 8; ++jj) {
      float t0 = (float)a[jj] * (1.f - fx) + (float)bb[jj] * fx;
      float t1 = (float)cc[jj] * (1.f - fx) + (float)dd[jj] * fx;
      o[jj] = (f16)(t0 * (1.f - fy) + t1 * fy);
    }
    *(f16x8*)(up + h * 8) = o;
  }
}

// ---------------------------------------------------------------------------
// MFMA 1x1 conv (pure GEMM), KS-templated straight-line.
// ---------------------------------------------------------------------------
template<int ACT, int RES, int KS>
__global__ __launch_bounds__(256, 2) void k_gemm1x1(
    const f16* __restrict__ X, const f16* __restrict__ Wf,
    const float* __restrict__ bias, f16* __restrict__ Out,
    int CoF, int Cs_in, int Cs_out, int Cr, int coTiles, int pixTiles)
{
  int wid = blockIdx.x * 4 + (threadIdx.x >> 6);
  int lane = threadIdx.x & 63;
  int total = pixTiles * coTiles;
  if (wid >= total) return;
  int coT = wid % coTiles;
  int pixT = wid / coTiles;
  int nfc = min(4, CoF - coT * 4);
  int l15 = lane & 15, l4 = lane >> 4;

  f32x4 acc[2][4];
#pragma unroll
  for (int mf = 0; mf < 2; ++mf)
#pragma unroll
    for (int nf = 0; nf < 4; ++nf) acc[mf][nf] = zero4();

  int pA0 = pixT * 32 + l15;
#pragma unroll
  for (int ks = 0; ks < KS; ++ks) {
    f16x8 a0 = *(const f16x8*)&X[(size_t)pA0 * Cs_in + ks * 32 + l4 * 8];
    f16x8 a1 = *(const f16x8*)&X[(size_t)(pA0 + 16) * Cs_in + ks * 32 + l4 * 8];
#pragma unroll
    for (int nf = 0; nf < 4; ++nf) {
      if (nf < nfc) {
        f16x8 bf = *(const f16x8*)&Wf[(((size_t)ks * CoF + coT * 4 + nf) * 64 + lane) * 8];
        acc[0][nf] = __builtin_amdgcn_mfma_f32_16x16x32_f16(a0, bf, acc[0][nf], 0, 0, 0);
        acc[1][nf] = __builtin_amdgcn_mfma_f32_16x16x32_f16(a1, bf, acc[1][nf], 0, 0, 0);
      }
    }
  }
#pragma unroll
  for (int nf = 0; nf < 4; ++nf) {
    if (nf < nfc) {
      int co = coT * 64 + nf * 16 + l15;
      if (co < Cr) {
        float bv = bias[co];
#pragma unroll
        for (int mf = 0; mf < 2; ++mf) {
          int p0 = pixT * 32 + mf * 16 + l4 * 4;
#pragma unroll
          for (int rg = 0; rg < 4; ++rg) {
            float v = activ<ACT>(acc[mf][nf][rg] + bv);
            size_t o = (size_t)(p0 + rg) * Cs_out + co;
            if (RES) v += (float)Out[o];
            Out[o] = (f16)v;
          }
        }
      }
    }
  }
}

// ---------------------------------------------------------------------------
// GroupNorm on NHWC f16, two stage.
// ---------------------------------------------------------------------------
__global__ __launch_bounds__(256) void k_gn_part_h(
    const f16* __restrict__ X, float* __restrict__ part)
{
  int s = blockIdx.x & 7;
  int g = (blockIdx.x >> 3) & 7;
  int b = blockIdx.x >> 6;
  int tid = threadIdx.x;
  const f16* Xp = X + (size_t)b * HWl * 128 + g * 16 + (tid & 1) * 8;
  float sum = 0.f, ss = 0.f;
  for (int p = s * 1920 + (tid >> 1); p < (s + 1) * 1920; p += 128) {
    f16x8 v = *(const f16x8*)&Xp[(size_t)p * 128];
#pragma unroll
    for (int jj = 0; jj < 8; ++jj) { float f = (float)v[jj]; sum += f; ss += f * f; }
  }
  __shared__ float sh1[256], sh2[256];
  sh1[tid] = sum; sh2[tid] = ss;
  __syncthreads();
  for (int st = 128; st > 0; st >>= 1) {
    if (tid < st) { sh1[tid] += sh1[tid + st]; sh2[tid] += sh2[tid + st]; }
    __syncthreads();
  }
  if (tid == 0) {
    part[((b * 8 + g) * 8 + s) * 2] = sh1[0];
    part[((b * 8 + g) * 8 + s) * 2 + 1] = sh2[0];
  }
}

__global__ __launch_bounds__(256) void k_gn_apply_h(
    const f16* __restrict__ X, const float* __restrict__ gw,
    const float* __restrict__ gb, const float* __restrict__ part,
    f16* __restrict__ Q)
{
  int idx = blockIdx.x * blockDim.x + threadIdx.x;
  int total = Bn * HWl * 16;
  if (idx >= total) return;
  int u = idx & 15;
  int pix = (idx >> 4) % HWl;
  int b = idx / (16 * HWl);
  int c0 = u * 8;
  int g = c0 >> 4;
  const float* pp = part + ((b * 8 + g) * 8) * 2;
  float sum = 0.f, ss = 0.f;
#pragma unroll
  for (int s = 0; s < 8; ++s) { sum += pp[s * 2]; ss += pp[s * 2 + 1]; }
  const float n = 16.f * HWl;
  float mean = sum / n;
  float var = ss / n - mean * mean;
  float inv = rsqrtf(var + 1e-5f);
  f16x8 v = *(const f16x8*)&X[((size_t)b * HWl + pix) * 128 + c0];
  f16x8 r;
#pragma unroll
  for (int jj = 0; jj < 8; ++jj) {
    int c = c0 + jj;
    r[jj] = (f16)(((float)v[jj] - mean) * (gw[c] * inv) + gb[c]);
  }
  *(f16x8*)&Q[((size_t)b * HWl + pix) * 128 + c0] = r;
}

// softmax over the 9 points; attn NHWC [b][pix][48]
__global__ __launch_bounds__(256) void k_softmax9_h(f16* __restrict__ a)
{
  int idx = blockIdx.x * blockDim.x + threadIdx.x;
  if (idx >= Bn * NHd * HWl) return;
  int pix = idx % HWl;
  int head = (idx / HWl) & 3;
  int b = idx / (HWl * NHd);
  f16* base = a + ((size_t)b * HWl + pix) * 48 + head * 9;
  float v[9];
  float m = -1e30f;
#pragma unroll
  for (int p0 = 0; p0 < 9; ++p0) { v[p0] = (float)base[p0]; m = fmaxf(m, v[p0]); }
  float s = 0.f;
#pragma unroll
  for (int p0 = 0; p0 < 9; ++p0) { v[p0] = expf(v[p0] - m); s += v[p0]; }
  float inv = 1.f / s;
#pragma unroll
  for (int p0 = 0; p0 < 9; ++p0) base[p0] = (f16)(v[p0] * inv);
}

// ---------------------------------------------------------------------------
// Deformable sampling, NHWC. Thread per (b, head, pix), 32 head-channels.
// ---------------------------------------------------------------------------
__global__ __launch_bounds__(256) void k_deform_h(
    const f16* __restrict__ vals, const f16* __restrict__ off,
    const f16* __restrict__ attn, f16* __restrict__ outa)
{
  int idx = blockIdx.x * blockDim.x + threadIdx.x;
  if (idx >= Bn * NHd * HWl) return;
  int pix = idx % HWl;
  int head = (idx / HWl) & 3;
  int b = idx / (HWl * NHd);
  int j = pix % FW, i = pix / FW;

  const float kx = (float)FW / (float)(FW - 1);
  const float ky = (float)FH / (float)(FH - 1);
  const f16* vb = vals + (size_t)b * HWl * 128 + head * 32;
  const f16* ab = attn + ((size_t)b * HWl + pix) * 48 + head * 9;
  const f16* ob = off + ((size_t)b * HWl + pix) * 80 + head * 18;

  float acc[32];
#pragma unroll
  for (int k = 0; k < 32; ++k) acc[k] = 0.f;

#pragma unroll
  for (int p0 = 0; p0 < 9; ++p0) {
    float ox = (float)ob[p0 * 2];
    float oy = (float)ob[p0 * 2 + 1];
    float aw = (float)ab[p0];
    float xf = ((float)j + ox) * kx - 0.5f;
    float yf = ((float)i + oy) * ky - 0.5f;
    xf = fminf(fmaxf(xf, 0.f), (float)(FW - 1));
    yf = fminf(fmaxf(yf, 0.f), (float)(FH - 1));
    int x0 = (int)floorf(xf), y0 = (int)floorf(yf);
    int x1 = min(x0 + 1, FW - 1), y1 = min(y0 + 1, FH - 1);
    float fx = xf - (float)x0, fy = yf - (float)y0;
    float w00 = aw * (1.f - fx) * (1.f - fy);
    float w01 = aw * fx * (1.f - fy);
    float w10 = aw * (1.f - fx) * fy;
    float w11 = aw * fx * fy;
    const f16x8* c00 = (const f16x8*)&vb[(size_t)(y0 * FW + x0) * 128];
    const f16x8* c01 = (const f16x8*)&vb[(size_t)(y0 * FW + x1) * 128];
    const f16x8* c10 = (const f16x8*)&vb[(size_t)(y1 * FW + x0) * 128];
    const f16x8* c11 = (const f16x8*)&vb[(size_t)(y1 * FW + x1) * 128];
#pragma unroll
    for (int k8 = 0; k8 < 4; ++k8) {
      f16x8 a = c00[k8], bb = c01[k8], cc = c10[k8], dd = c11[k8];
#pragma unroll
      for (int jj = 0; jj < 8; ++jj)
        acc[k8 * 8 + jj] += w00 * (float)a[jj] + w01 * (float)bb[jj]
                          + w10 * (float)cc[jj] + w11 * (float)dd[jj];
    }
  }
  f16* op = outa + ((size_t)b * HWl + pix) * 128 + head * 32;
#pragma unroll
  for (int k = 0; k < 32; ++k) op[k] = (f16)acc[k];
}

// ---------------------------------------------------------------------------
// dec2: 32->3 conv from NHWC f16 window + sigmoid, NCHW f32 out rows [c0,+R).
// ---------------------------------------------------------------------------
__global__ __launch_bounds__(256) void k_dec2_h(
    const f16* __restrict__ Xb, const float* __restrict__ w,
    const float* __restrict__ bias, float* __restrict__ out,
    int c0, int b0, int brows, int R)
{
  int idx = blockIdx.x * blockDim.x + threadIdx.x;
  if (idx >= Bn * R * Wh) return;
  int x = idx % Wh;
  int y = c0 + (idx / Wh) % R;
  int b = idx / (Wh * R);
  float a0 = bias[0], a1 = bias[1], a2 = bias[2];
#pragma unroll
  for (int ky = 0; ky < 3; ++ky) {
    int gy = y + ky - 1;
    if (gy < 0 || gy >= Hh) continue;
#pragma unroll
    for (int kxx = 0; kxx < 3; ++kxx) {
      int gx = x + kxx - 1;
      if (gx < 0 || gx >= Wh) continue;
      int tap = ky * 3 + kxx;
      const f16* px = Xb + ((size_t)(b * brows + (gy - b0)) * Wh + gx) * 32;
#pragma unroll
      for (int k8 = 0; k8 < 4; ++k8) {
        f16x8 v = *(const f16x8*)&px[k8 * 8];
#pragma unroll
        for (int jj = 0; jj < 8; ++jj) {
          int ci = k8 * 8 + jj;
          float f = (float)v[jj];
          a0 += f * w[(0 * 32 + ci) * 9 + tap];
          a1 += f * w[(1 * 32 + ci) * 9 + tap];
          a2 += f * w[(2 * 32 + ci) * 9 + tap];
        }
      }
    }
  }
  size_t o = ((size_t)(b * 3 + 0) * Hh + y) * Wh + x;
  out[o] = 1.f / (1.f + expf(-a0));
  out[o + (size_t)Hh * Wh] = 1.f / (1.f + expf(-a1));
  out[o + (size_t)2 * Hh * Wh] = 1.f / (1.f + expf(-a2));
}

// ---------------------------------------------------------------------------
extern "C" void kernel_launch(void* const* d_in, const int* in_sizes, int n_in,
                              void* d_out, int out_size, void* d_ws, size_t ws_size,
                              hipStream_t stream) {
  (void)in_sizes; (void)n_in; (void)out_size; (void)ws_size;
  const float* feat1  = (const float*)d_in[0];
  const float* feat2  = (const float*)d_in[1];
  const float* flowf  = (const float*)d_in[2];
  const float* flowb  = (const float*)d_in[3];
  const float* edge1  = (const float*)d_in[4];
  const float* edge2  = (const float*)d_in[5];
  const float* fuse_w0 = (const float*)d_in[6];
  const float* fuse_b0 = (const float*)d_in[7];
  const float* fuse_w1 = (const float*)d_in[8];
  const float* fuse_b1 = (const float*)d_in[9];
  const float* gn_g   = (const float*)d_in[10];
  const float* gn_b   = (const float*)d_in[11];
  const float* off_w0 = (const float*)d_in[12];
  const float* off_b0 = (const float*)d_in[13];
  const float* off_w1 = (const float*)d_in[14];
  const float* off_b1 = (const float*)d_in[15];
  const float* aw_w0  = (const float*)d_in[16];
  const float* aw_b0  = (const float*)d_in[17];
  const float* aw_w1  = (const float*)d_in[18];
  const float* aw_b1  = (const float*)d_in[19];
  const float* val_w  = (const float*)d_in[20];
  const float* val_b  = (const float*)d_in[21];
  const float* out_w  = (const float*)d_in[22];
  const float* out_b  = (const float*)d_in[23];
  const float* ffn_w0 = (const float*)d_in[24];
  const float* ffn_b0 = (const float*)d_in[25];
  const float* ffn_w1 = (const float*)d_in[26];
  const float* ffn_b1 = (const float*)d_in[27];
  const float* dec_w0 = (const float*)d_in[28];
  const float* dec_b0 = (const float*)d_in[29];
  const float* dec_w1 = (const float*)d_in[30];
  const float* dec_b1 = (const float*)d_in[31];
  const float* dec_w2 = (const float*)d_in[32];
  const float* dec_b2 = (const float*)d_in[33];
  float* out = (float*)d_out;

  // ---- workspace layout (f16 units). Weights FIRST (decoder overlay can
  // never clobber them). Total ~75 MB.
  f16* ws16 = (f16*)d_ws;
  size_t o = 0;
  auto alloc = [&](size_t n) { f16* p = ws16 + o; o += (n + 7) & ~(size_t)7; return p; };
  f16* xbuf  = alloc((size_t)2 * HWl * 128);
  f16* wfF0 = alloc(9 * 9 * 8 * 512);
  f16* wfF1 = alloc(9 * 4 * 8 * 512);
  f16* wfOA = alloc(9 * 4 * 16 * 512);          // off0 (cf 0..7) + aw0 (cf 8..15)
  f16* wfD0 = alloc(9 * 4 * 4 * 512);
  f16* wfD1 = alloc(9 * 2 * 2 * 512);
  f16* w1O  = alloc(4 * 5 * 512);
  f16* w1A  = alloc(4 * 3 * 512);
  f16* w1V  = alloc(4 * 8 * 512);
  f16* w1U  = alloc(4 * 8 * 512);
  f16* w1G0 = alloc(4 * 16 * 512);
  f16* w1G1 = alloc(8 * 8 * 512);
  float* gnp = (float*)alloc(512);
  f16* pool  = ws16 + o;                        // decoder overlay starts here
  f16* regA  = alloc((size_t)2 * HWl * 288);    // fused / t_oa / ffn_t
  f16* regB  = alloc((size_t)2 * HWl * 128);    // source / out_attn
  f16* regC  = alloc((size_t)2 * HWl * 128);    // fuse0-out / qb
  f16* offb  = alloc((size_t)2 * HWl * 80);
  f16* attnb = alloc((size_t)2 * HWl * 48);
  f16* regF  = alloc((size_t)2 * HWl * 131);    // valsb
  f16* featT1 = alloc((size_t)2 * HWl * 128);
  f16* featT2 = alloc((size_t)2 * HWl * 128);

  f16* fused = regA;
  f16* t_oa  = regA;        // merged off/aw 3x3 out, 256 ch
  f16* ffn_t = regA;
  f16* src_h = regB;
  f16* out_attn = regB;
  f16* tmp_h = regC;
  f16* qb    = regC;
  f16* valsb = regF;
  // Decoder overlay over pool (dead after FFN). 96-row chunks:
  // bufU 2*103*640*128 = 16.88M ; bufA 2*100*640*64 = 8.19M ;
  // bufB 2*99*640*32 = 4.06M ; total 29.12M <= pool 32.53M f16.
  f16* bufU = pool;
  f16* bufA = bufU + (size_t)2 * 103 * 640 * 128;
  f16* bufB = bufA + (size_t)2 * 100 * 640 * 64;

  dim3 blk(256);
  auto pg = [](long n) { return dim3((unsigned)((n + 255) / 256)); };
  auto cg = [](int pixTiles, int coTiles) {
    return dim3((unsigned)((pixTiles * coTiles + 3) / 4), 1, 2);
  };
  const int BIG = 1 << 30;

  // ---- merged weight prep ----
  PrepArgs pa;
  int pb = 0;
  auto addj = [&](int k, const float* w, f16* wf, int Cout, int cing, int coutg,
                  int KS, int CoF, int taps, int CoFt, int cf0) {
    pa.j[k] = PrepJob{w, wf, Cout, cing, coutg, KS, CoF, taps, CoFt, cf0, pb};
    pb += (taps * KS * CoF * 64 + 255) / 256;
  };
  addj(0, fuse_w0, wfF0, 128, 259, 128, 9, 8, 9, 8, 0);
  addj(1, fuse_w1, wfF1, 128, 128, 128, 4, 8, 9, 8, 0);
  addj(2, off_w0, wfOA, 128, 32, 32, 4, 8, 9, 16, 0);
  addj(3, aw_w0,  wfOA, 128, 32, 32, 4, 8, 9, 16, 8);
  addj(4, dec_w0, wfD0, 64, 128, 64, 4, 4, 9, 4, 0);
  addj(5, dec_w1, wfD1, 32, 64, 32, 2, 2, 9, 2, 0);
  addj(6, off_w1, w1O, 72, 128, 72, 4, 5, 1, 5, 0);
  addj(7, aw_w1,  w1A, 36, 128, 36, 4, 3, 1, 3, 0);
  addj(8, val_w,  w1V, 128, 128, 128, 4, 8, 1, 8, 0);
  addj(9, out_w,  w1U, 128, 128, 128, 4, 8, 1, 8, 0);
  addj(10, ffn_w0, w1G0, 256, 128, 256, 4, 16, 1, 16, 0);
  addj(11, ffn_w1, w1G1, 128, 256, 128, 8, 8, 1, 8, 0);
  k_wprep_all<<<dim3((unsigned)pb), blk, 0, stream>>>(pa);

  // ---- 0. feats -> NHWC f16 ----
  k_tr_h<<<pg(2L * Bn * HWl * 8), blk, 0, stream>>>(feat1, feat2, featT1, featT2);
  // ---- 1. warp + concat + source ----
  k_warp_fuse_h<<<pg((long)Bn * HWl * 8), blk, 0, stream>>>(featT1, featT2, flowf, flowb,
                                                            edge1, edge2, fused, src_h);
  // ---- 2-3. fuse convs (batched loads, NF=4) ----
  k_conv3g<1, 2, 4, 160, 9><<<cg(480, 2), blk, 0, stream>>>(fused, wfF0, fuse_b0, fuse_b0, BIG,
      tmp_h, 8, 288, 128, FH, 0, FH, 0, FH, 0, FH, 2);
  k_conv3g<1, 2, 4, 160, 4><<<cg(480, 2), blk, 0, stream>>>(tmp_h, wfF1, fuse_b1, fuse_b1, BIG,
      xbuf, 8, 128, 128, FH, 0, FH, 0, FH, 0, FH, 2);
  // ---- 4. group norm ----
  k_gn_part_h<<<dim3(128), blk, 0, stream>>>(xbuf, gnp);
  k_gn_apply_h<<<pg(2L * HWl * 16), blk, 0, stream>>>(xbuf, gn_g, gn_b, gnp, qb);
  // ---- 5. merged off0+aw0 grouped 3x3 (256 out ch, dual bias, NF=4) ----
  k_conv3g<1, 2, 4, 160, 4><<<cg(480, 4), blk, 0, stream>>>(qb, wfOA, off_b0, aw_b0, 128,
      t_oa, 16, 128, 256, FH, 0, FH, 0, FH, 0, FH, 4);
  // ---- 6-8. 1x1 heads + softmax ----
  k_gemm1x1<0, 0, 4><<<dim3(480), blk, 0, stream>>>(t_oa, w1O, off_b1, offb,
      5, 256, 80, 72, 2, 960);
  k_gemm1x1<0, 0, 4><<<dim3(240), blk, 0, stream>>>(t_oa + 128, w1A, aw_b1, attnb,
      3, 256, 48, 36, 1, 960);
  k_softmax9_h<<<pg(2L * NHd * HWl), blk, 0, stream>>>(attnb);
  // ---- 9. vals ----
  k_gemm1x1<0, 0, 4><<<dim3(480), blk, 0, stream>>>(src_h, w1V, val_b, valsb,
      8, 128, 128, 128, 2, 960);
  // ---- 10. deform ----
  k_deform_h<<<pg(2L * NHd * HWl), blk, 0, stream>>>(valsb, offb, attnb, out_attn);
  // ---- 11. out-proj (residual into xbuf) ----
  k_gemm1x1<0, 1, 4><<<dim3(480), blk, 0, stream>>>(out_attn, w1U, out_b, xbuf,
      8, 128, 128, 128, 2, 960);
  // ---- 12-13. FFN ----
  k_gemm1x1<2, 0, 4><<<dim3(960), blk, 0, stream>>>(xbuf, w1G0, ffn_b0, ffn_t,
      16, 128, 256, 256, 4, 960);
  k_gemm1x1<0, 1, 8><<<dim3(480), blk, 0, stream>>>(ffn_t, w1G1, ffn_b1, xbuf,
      8, 256, 128, 128, 2, 960);

  // ---- 14. decoder, 4 chunks of 96 rows: up4 -> dec0 -> dec1 -> dec2 ----
  for (int c0 = 0; c0 < Hh; c0 += 96) {
    int c1 = c0 + 96;
    int a0 = c0 - 2 > 0 ? c0 - 2 : 0;
    int a1 = c1 + 2 < Hh ? c1 + 2 : Hh;
    int b0 = c0 - 1 > 0 ? c0 - 1 : 0;
    int b1 = c1 + 1 < Hh ? c1 + 1 : Hh;
    int u0 = a0 - 1 > 0 ? a0 - 1 : 0;
    int u1 = a1 + 1 < Hh ? a1 + 1 : Hh;
    int ar = a1 - a0, br = b1 - b0, ur = u1 - u0;
    // upsample rows [u0,u1) -> bufU
    k_up4_h<<<pg(2L * ur * Wh * 8), blk, 0, stream>>>(xbuf, bufU, u0, ur);
    // dec0: 128->64, rows [a0,a1) -> bufA  (M=4, NF=4, KS=4)
    k_conv3g<1, 4, 4, 640, 4><<<cg(ar * 10, 1), blk, 0, stream>>>(bufU, wfD0, dec_b0, dec_b0, BIG,
        bufA, 4, 128, 64, Hh, u0, ur, a0, ar, a0, ar, 1);
    // dec1: 64->32, rows [b0,b1) -> bufB  (M=4, NF=2, KS=2)
    k_conv3g<1, 4, 2, 640, 2><<<cg(br * 10, 1), blk, 0, stream>>>(bufA, wfD1, dec_b1, dec_b1, BIG,
        bufB, 2, 64, 32, Hh, a0, ar, b0, br, b0, br, 1);
    // dec2: 32->3 + sigmoid -> out rows [c0,c1)
    k_dec2_h<<<pg(2L * 96 * Wh), blk, 0, stream>>>(bufB, dec_w2, dec_b2, out,
                                                   c0, b0, br, 96);
  }
}

// Round 14
// 678.125 us; speedup vs baseline: 1.1586x; 1.0297x over previous
//
#include <hip/hip_runtime.h>

typedef _Float16 f16;
typedef _Float16 f16x8 __attribute__((ext_vector_type(8)));
typedef float f32x4 __attribute__((ext_vector_type(4)));

constexpr int Bn = 2, Cn = 128, FH = 96, FW = 160, Hh = 384, Wh = 640;
constexpr int HWl = FH * FW;   // 15360
constexpr int NHd = 4, NPt = 9;

#define DEVINL __device__ __forceinline__

DEVINL f32x4 zero4() { f32x4 z; z[0] = 0.f; z[1] = 0.f; z[2] = 0.f; z[3] = 0.f; return z; }
DEVINL f16x8 zero8() {
  f16x8 z;
#pragma unroll
  for (int j = 0; j < 8; ++j) z[j] = (f16)0.f;
  return z;
}

template<int ACT> DEVINL float activ(float v) {
  if (ACT == 1) return v >= 0.f ? v : 0.1f * v;                           // leaky relu
  if (ACT == 2) return 0.5f * v * (1.f + erff(v * 0.70710678118654752f)); // exact gelu
  if (ACT == 3) return 1.f / (1.f + expf(-v));                            // sigmoid
  return v;
}

// Zero-fill (for the zero page; conv rows outside the image point here).
__global__ __launch_bounds__(256) void k_zero(f16* __restrict__ p, int n8)
{
  int i = blockIdx.x * 256 + threadIdx.x;
  if (i < n8) *(f16x8*)&p[(size_t)i * 8] = zero8();
}

// ---------------------------------------------------------------------------
// Merged weight prep (12 jobs, one launch). 3x3 jobs produce
// [tap][ks][CoFt: cf0+cf][lane][8]; 1x1 jobs [ks][cf][lane][8].
// k = (lane>>4)*8+j (A-frag convention). Grouped convs zero-padded to full K.
// ---------------------------------------------------------------------------
struct PrepJob { const float* w; f16* wf; int Cout, cin_g, cout_g, KS, CoF, taps, CoFt, cf0, blk0; };
struct PrepArgs { PrepJob j[12]; };

__global__ __launch_bounds__(256) void k_wprep_all(PrepArgs a)
{
  int jb = 0;
#pragma unroll
  for (int t = 1; t < 12; ++t) if ((int)blockIdx.x >= a.j[t].blk0) jb = t;
  PrepJob J = a.j[jb];
  int idx = (blockIdx.x - J.blk0) * 256 + threadIdx.x;
  int total = J.taps * J.KS * J.CoF * 64;
  if (idx >= total) return;
  int lane = idx & 63;
  int rest = idx >> 6;
  int cf = rest % J.CoF;
  int rest2 = rest / J.CoF;
  int ks = rest2 % J.KS;
  int tap = rest2 / J.KS;
  int co = cf * 16 + (lane & 15);
  f16x8 v = zero8();
#pragma unroll
  for (int j = 0; j < 8; ++j) {
    int cip = ks * 32 + (lane >> 4) * 8 + j;
    int cil = cip - (co / J.cout_g) * J.cin_g;
    float x = 0.f;
    if (co < J.Cout && cil >= 0 && cil < J.cin_g)
      x = J.w[((size_t)co * J.cin_g + cil) * J.taps + tap];
    v[j] = (f16)x;
  }
  size_t oidx = (((size_t)tap * J.KS + ks) * J.CoFt + J.cf0 + cf) * 64 + lane;
  *(f16x8*)&J.wf[oidx * 8] = v;
}

// ---------------------------------------------------------------------------
// NCHW f32 -> NHWC f16 transpose for feat1+feat2.
// ---------------------------------------------------------------------------
__global__ __launch_bounds__(256) void k_tr_h(
    const float* __restrict__ feat1, const float* __restrict__ feat2,
    f16* __restrict__ t1, f16* __restrict__ t2)
{
  int idx = blockIdx.x * blockDim.x + threadIdx.x;
  if (idx >= 2 * Bn * HWl * 8) return;
  int cq = idx & 7;
  int pix = (idx >> 3) % HWl;
  int z = idx / (8 * HWl);
  int b = z & 1;
  const float* src = (z >> 1) ? feat2 : feat1;
  f16* dst = (z >> 1) ? t2 : t1;
  int c0 = cq * 16;
  f16x8 v0, v1;
#pragma unroll
  for (int j = 0; j < 8; ++j) {
    v0[j] = (f16)src[(size_t)(b * Cn + c0 + j) * HWl + pix];
    v1[j] = (f16)src[(size_t)(b * Cn + c0 + 8 + j) * HWl + pix];
  }
  f16* dp = dst + ((size_t)b * HWl + pix) * 128 + c0;
  *(f16x8*)dp = v0;
  *(f16x8*)(dp + 8) = v1;
}

// ---------------------------------------------------------------------------
// Warp + concat + source, NHWC f16, cq-fastest lanes (coalesced).
// ---------------------------------------------------------------------------
__global__ __launch_bounds__(256) void k_warp_fuse_h(
    const f16* __restrict__ t1, const f16* __restrict__ t2,
    const float* __restrict__ flowf, const float* __restrict__ flowb,
    const float* __restrict__ edge1, const float* __restrict__ edge2,
    f16* __restrict__ fused, f16* __restrict__ src)
{
  int idx = blockIdx.x * blockDim.x + threadIdx.x;
  if (idx >= Bn * HWl * 8) return;
  int cq = idx & 7;
  int pix = (idx >> 3) % HWl;
  int b = idx / (8 * HWl);
  int j = pix % FW;
  int i = pix / FW;

  const int y4 = 4 * i + 1, x4 = 4 * j + 1;
  const float* p;
  p = flowf + (size_t)((b * 2 + 0) * Hh + y4) * Wh + x4;
  float fx1 = 0.03125f * (p[0] + p[1] + p[Wh] + p[Wh + 1]);
  p = flowf + (size_t)((b * 2 + 1) * Hh + y4) * Wh + x4;
  float fy1 = 0.03125f * (p[0] + p[1] + p[Wh] + p[Wh + 1]);
  p = flowb + (size_t)((b * 2 + 0) * Hh + y4) * Wh + x4;
  float fx2 = 0.03125f * (p[0] + p[1] + p[Wh] + p[Wh + 1]);
  p = flowb + (size_t)((b * 2 + 1) * Hh + y4) * Wh + x4;
  float fy2 = 0.03125f * (p[0] + p[1] + p[Wh] + p[Wh + 1]);

  float sx1 = fminf(fmaxf((float)j + fx1, 0.f), (float)(FW - 1));
  float sy1 = fminf(fmaxf((float)i + fy1, 0.f), (float)(FH - 1));
  float sx2 = fminf(fmaxf((float)j + fx2, 0.f), (float)(FW - 1));
  float sy2 = fminf(fmaxf((float)i + fy2, 0.f), (float)(FH - 1));

  int x10 = (int)floorf(sx1), y10 = (int)floorf(sy1);
  int x11 = min(x10 + 1, FW - 1), y11 = min(y10 + 1, FH - 1);
  float wx1 = sx1 - (float)x10, wy1 = sy1 - (float)y10;
  int x20 = (int)floorf(sx2), y20 = (int)floorf(sy2);
  int x21 = min(x20 + 1, FW - 1), y21 = min(y20 + 1, FH - 1);
  float wx2 = sx2 - (float)x20, wy2 = sy2 - (float)y20;

  float a00 = (1.f - wx1) * (1.f - wy1), a01 = wx1 * (1.f - wy1);
  float a10 = (1.f - wx1) * wy1,         a11 = wx1 * wy1;
  float c00 = (1.f - wx2) * (1.f - wy2), c01 = wx2 * (1.f - wy2);
  float c10 = (1.f - wx2) * wy2,         c11 = wx2 * wy2;

  int c0 = cq * 16;
  const f16* b1 = t1 + (size_t)b * HWl * 128 + c0;
  const f16* b2 = t2 + (size_t)b * HWl * 128 + c0;
  const f16x8* p100 = (const f16x8*)&b1[(size_t)(y10 * FW + x10) * 128];
  const f16x8* p101 = (const f16x8*)&b1[(size_t)(y10 * FW + x11) * 128];
  const f16x8* p110 = (const f16x8*)&b1[(size_t)(y11 * FW + x10) * 128];
  const f16x8* p111 = (const f16x8*)&b1[(size_t)(y11 * FW + x11) * 128];
  const f16x8* p200 = (const f16x8*)&b2[(size_t)(y20 * FW + x20) * 128];
  const f16x8* p201 = (const f16x8*)&b2[(size_t)(y20 * FW + x21) * 128];
  const f16x8* p210 = (const f16x8*)&b2[(size_t)(y21 * FW + x20) * 128];
  const f16x8* p211 = (const f16x8*)&b2[(size_t)(y21 * FW + x21) * 128];

  f16* fp = fused + ((size_t)b * HWl + pix) * 288;
  f16* sp = src + ((size_t)b * HWl + pix) * 128;

#pragma unroll
  for (int h = 0; h < 2; ++h) {
    f16x8 u00 = p100[h], u01 = p101[h], u10 = p110[h], u11 = p111[h];
    f16x8 w00 = p200[h], w01 = p201[h], w10 = p210[h], w11 = p211[h];
    f16x8 r1, r2, rs;
#pragma unroll
    for (int k = 0; k < 8; ++k) {
      float v1 = (float)u00[k] * a00 + (float)u01[k] * a01
               + (float)u10[k] * a10 + (float)u11[k] * a11;
      float v2 = (float)w00[k] * c00 + (float)w01[k] * c01
               + (float)w10[k] * c10 + (float)w11[k] * c11;
      r1[k] = (f16)v1; r2[k] = (f16)v2; rs[k] = (f16)(0.5f * (v1 + v2));
    }
    *(f16x8*)(fp + c0 + h * 8) = r1;
    *(f16x8*)(fp + 128 + c0 + h * 8) = r2;
    *(f16x8*)(sp + c0 + h * 8) = rs;
  }

  if (cq == 0) {
    p = edge1 + (size_t)(b * Hh + y4) * Wh + x4;
    float e1v = 0.25f * (p[0] + p[1] + p[Wh] + p[Wh + 1]);
    p = edge2 + (size_t)(b * Hh + y4) * Wh + x4;
    float e2v = 0.25f * (p[0] + p[1] + p[Wh] + p[Wh + 1]);
    fp[256] = (f16)e1v;
    fp[257] = (f16)e2v;
    fp[258] = (f16)0.5f;
#pragma unroll
    for (int c = 259; c < 288; ++c) fp[c] = (f16)0.f;
  }
}

// ---------------------------------------------------------------------------
// Barrier-free MFMA 3x3 conv — explicit 2-stage pipeline + sched_group_barrier.
// Group = (cs, ky): 3*(M+NF) loads, 3*M*NF MFMAs. Iteration g loads group g+1
// (other buffer) then MFMAs group g; SGB pins [VMEM xNLD][MFMA xNMM] so the
// compiler emits counted vmcnt and keeps both buffers live.
// Invalid rows read a ZERO PAGE (pointer select, no per-load cndmask); only
// the two truly-edge (kx,mf) fragments keep a value select.
// ---------------------------------------------------------------------------
template<int ACT, int M, int NF, int W, int KS>
__global__ __launch_bounds__(256, 2) void k_conv3g(
    const f16* __restrict__ X, const f16* __restrict__ Wf,
    const float* __restrict__ bias, const float* __restrict__ bias2, int bsplit,
    f16* __restrict__ Out, const f16* __restrict__ zpage,
    int CoF, int Cs_in, int Cs_out, int Htot,
    int in_r0, int in_rows, int out_r0, int out_rows,
    int ogr0, int nrows, int coTiles)
{
  int wid = blockIdx.x * 4 + (threadIdx.x >> 6);
  int lane = threadIdx.x & 63;
  int l15 = lane & 15, l4 = lane >> 4;
  int pixTiles = nrows * W / (M * 16);
  if (wid >= pixTiles * coTiles) return;
  int coT = wid % coTiles;
  int pixT = wid / coTiles;
  int b = blockIdx.z;
  int base = pixT * (M * 16);
  int row = ogr0 + base / W;       // wave-uniform (16M | W)
  int colB = base % W;

  f32x4 acc[M][NF];
#pragma unroll
  for (int mf = 0; mf < M; ++mf)
#pragma unroll
    for (int nf = 0; nf < NF; ++nf) acc[mf][nf] = zero4();

  // Row pointers: invalid rows -> zero page (no per-load select).
  const f16* rp[3];
#pragma unroll
  for (int ky = 0; ky < 3; ++ky) {
    int srow = row + ky - 1;
    bool rv = (srow >= 0 && srow < Htot);
    int crow = min(max(srow, in_r0), in_r0 + in_rows - 1);
    const f16* real = X + ((size_t)(b * in_rows + (crow - in_r0)) * W) * Cs_in + l4 * 8;
    rp[ky] = rv ? real : (zpage + l4 * 8);
  }
  // Column offsets; only 2 edge fragments can be invalid.
  int sc[3][M]; bool okc[3][M];
#pragma unroll
  for (int kx = 0; kx < 3; ++kx)
#pragma unroll
    for (int mf = 0; mf < M; ++mf) {
      int scol = colB + mf * 16 + l15 + kx - 1;
      okc[kx][mf] = (unsigned)scol < (unsigned)W;
      sc[kx][mf] = min(max(scol, 0), W - 1);
    }

  const f16* wb = Wf + (size_t)coT * NF * 512;
  constexpr int G = KS * 3;
  constexpr int NLD = 3 * (M + NF);
  constexpr int NMM = 3 * M * NF;

  f16x8 Afb[2][3][M];
  f16x8 Bfb[2][3][NF];

  auto loadGroup = [&](int g, int buf) {
    int cs = g / 3, ky = g % 3;
#pragma unroll
    for (int kx = 0; kx < 3; ++kx) {
#pragma unroll
      for (int mf = 0; mf < M; ++mf) {
        f16x8 t = *(const f16x8*)&rp[ky][(size_t)sc[kx][mf] * Cs_in + cs * 32];
        if ((kx == 0 && mf == 0) || (kx == 2 && mf == M - 1))
          t = okc[kx][mf] ? t : zero8();
        Afb[buf][kx][mf] = t;
      }
#pragma unroll
      for (int nf = 0; nf < NF; ++nf)
        Bfb[buf][kx][nf] =
            *(const f16x8*)&wb[((((size_t)(ky * 3 + kx) * KS + cs) * CoF + nf) * 64 + lane) * 8];
    }
  };

  loadGroup(0, 0);
  __builtin_amdgcn_sched_group_barrier(0x20, NLD, 0);   // VMEM_READ
#pragma unroll
  for (int g = 0; g < G; ++g) {
    int cb = g & 1;
    if (g + 1 < G) loadGroup(g + 1, cb ^ 1);
#pragma unroll
    for (int kx = 0; kx < 3; ++kx)
#pragma unroll
      for (int mf = 0; mf < M; ++mf)
#pragma unroll
        for (int nf = 0; nf < NF; ++nf)
          acc[mf][nf] = __builtin_amdgcn_mfma_f32_16x16x32_f16(
              Afb[cb][kx][mf], Bfb[cb][kx][nf], acc[mf][nf], 0, 0, 0);
    if (g + 1 < G) __builtin_amdgcn_sched_group_barrier(0x20, NLD, 0);
    __builtin_amdgcn_sched_group_barrier(0x8, NMM, 0);  // MFMA
  }

  size_t rowoff = ((size_t)b * out_rows + (row - out_r0)) * W;
#pragma unroll
  for (int nf = 0; nf < NF; ++nf) {
    int co = coT * (NF * 16) + nf * 16 + l15;
    float bv = (co < bsplit) ? bias[co] : bias2[co - bsplit];
#pragma unroll
    for (int mf = 0; mf < M; ++mf) {
      int xo = colB + mf * 16 + l4 * 4;
#pragma unroll
      for (int rg = 0; rg < 4; ++rg) {
        float v = activ<ACT>(acc[mf][nf][rg] + bv);
        Out[(rowoff + xo + rg) * (size_t)Cs_out + co] = (f16)v;
      }
    }
  }
}

// ---------------------------------------------------------------------------
// 4x bilinear upsample NHWC f16: xbuf (B,96,160,128) -> U rows [u0, +urows).
// ---------------------------------------------------------------------------
__global__ __launch_bounds__(256) void k_up4_h(
    const f16* __restrict__ Xl, f16* __restrict__ U, int u0, int urows)
{
  int idx = blockIdx.x * blockDim.x + threadIdx.x;
  if (idx >= Bn * urows * Wh * 8) return;
  int cq = idx & 7;
  int x = (idx >> 3) % Wh;
  int r = ((idx >> 3) / Wh) % urows;
  int b = idx / (8 * Wh * urows);
  int R = u0 + r;

  float uy = ((float)R + 0.5f) * 0.25f - 0.5f;
  uy = fminf(fmaxf(uy, 0.f), (float)(FH - 1));
  int y0 = (int)floorf(uy);
  int y1 = min(y0 + 1, FH - 1);
  float fy = uy - (float)y0;
  float ux = ((float)x + 0.5f) * 0.25f - 0.5f;
  ux = fminf(fmaxf(ux, 0.f), (float)(FW - 1));
  int x0 = (int)floorf(ux);
  int x1 = min(x0 + 1, FW - 1);
  float fx = ux - (float)x0;

  const f16* xb = Xl + (size_t)b * HWl * 128 + cq * 16;
  const f16x8* c00 = (const f16x8*)&xb[(size_t)(y0 * FW + x0) * 128];
  const f16x8* c01 = (const f16x8*)&xb[(size_t)(y0 * FW + x1) * 128];
  const f16x8* c10 = (const f16x8*)&xb[(size_t)(y1 * FW + x0) * 128];
  const f16x8* c11 = (const f16x8*)&xb[(size_t)(y1 * FW + x1) * 128];
  f16* up = U + (((size_t)b * urows + r) * Wh + x) * 128 + cq * 16;
#pragma unroll
  for (int h = 0; h < 2; ++h) {
    f16x8 a = c00[h], bb = c01[h], cc = c10[h], dd = c11[h];
    f16x8 o;
#pragma unroll
    for (int jj = 0; jj < 8; ++jj) {
      float t0 = (float)a[jj] * (1.f - fx) + (float)bb[jj] * fx;
      float t1 = (float)cc[jj] * (1.f - fx) + (float)dd[jj] * fx;
      o[jj] = (f16)(t0 * (1.f - fy) + t1 * fy);
    }
    *(f16x8*)(up + h * 8) = o;
  }
}

// ---------------------------------------------------------------------------
// MFMA 1x1 conv (pure GEMM), 2-stage pipeline + SGB. Loads unconditional
// (overreads stay inside workspace; garbage accs discarded by co<Cr guard).
// ---------------------------------------------------------------------------
template<int ACT, int RES, int KS>
__global__ __launch_bounds__(256, 2) void k_gemm1x1(
    const f16* __restrict__ X, const f16* __restrict__ Wf,
    const float* __restrict__ bias, f16* __restrict__ Out,
    int CoF, int Cs_in, int Cs_out, int Cr, int coTiles, int pixTiles)
{
  int wid = blockIdx.x * 4 + (threadIdx.x >> 6);
  int lane = threadIdx.x & 63;
  int total = pixTiles * coTiles;
  if (wid >= total) return;
  int coT = wid % coTiles;
  int pixT = wid / coTiles;
  int l15 = lane & 15, l4 = lane >> 4;

  f32x4 acc[2][4];
#pragma unroll
  for (int mf = 0; mf < 2; ++mf)
#pragma unroll
    for (int nf = 0; nf < 4; ++nf) acc[mf][nf] = zero4();

  int pA0 = pixT * 32 + l15;
  f16x8 Ab[2][2];
  f16x8 Bb[2][4];
  auto load = [&](int ks, int buf) {
    Ab[buf][0] = *(const f16x8*)&X[(size_t)pA0 * Cs_in + ks * 32 + l4 * 8];
    Ab[buf][1] = *(const f16x8*)&X[(size_t)(pA0 + 16) * Cs_in + ks * 32 + l4 * 8];
#pragma unroll
    for (int nf = 0; nf < 4; ++nf)
      Bb[buf][nf] = *(const f16x8*)&Wf[(((size_t)ks * CoF + coT * 4 + nf) * 64 + lane) * 8];
  };

  load(0, 0);
  __builtin_amdgcn_sched_group_barrier(0x20, 6, 0);
#pragma unroll
  for (int ks = 0; ks < KS; ++ks) {
    int cb = ks & 1;
    if (ks + 1 < KS) load(ks + 1, cb ^ 1);
#pragma unroll
    for (int nf = 0; nf < 4; ++nf) {
      acc[0][nf] = __builtin_amdgcn_mfma_f32_16x16x32_f16(Ab[cb][0], Bb[cb][nf], acc[0][nf], 0, 0, 0);
      acc[1][nf] = __builtin_amdgcn_mfma_f32_16x16x32_f16(Ab[cb][1], Bb[cb][nf], acc[1][nf], 0, 0, 0);
    }
    if (ks + 1 < KS) __builtin_amdgcn_sched_group_barrier(0x20, 6, 0);
    __builtin_amdgcn_sched_group_barrier(0x8, 8, 0);
  }
#pragma unroll
  for (int nf = 0; nf < 4; ++nf) {
    int co = coT * 64 + nf * 16 + l15;
    if (co < Cr) {
      float bv = bias[co];
#pragma unroll
      for (int mf = 0; mf < 2; ++mf) {
        int p0 = pixT * 32 + mf * 16 + l4 * 4;
#pragma unroll
        for (int rg = 0; rg < 4; ++rg) {
          float v = activ<ACT>(acc[mf][nf][rg] + bv);
          size_t o = (size_t)(p0 + rg) * Cs_out + co;
          if (RES) v += (float)Out[o];
          Out[o] = (f16)v;
        }
      }
    }
  }
}

// ---------------------------------------------------------------------------
// GroupNorm on NHWC f16, two stage.
// ---------------------------------------------------------------------------
__global__ __launch_bounds__(256) void k_gn_part_h(
    const f16* __restrict__ X, float* __restrict__ part)
{
  int s = blockIdx.x & 7;
  int g = (blockIdx.x >> 3) & 7;
  int b = blockIdx.x >> 6;
  int tid = threadIdx.x;
  const f16* Xp = X + (size_t)b * HWl * 128 + g * 16 + (tid & 1) * 8;
  float sum = 0.f, ss = 0.f;
  for (int p = s * 1920 + (tid >> 1); p < (s + 1) * 1920; p += 128) {
    f16x8 v = *(const f16x8*)&Xp[(size_t)p * 128];
#pragma unroll
    for (int jj = 0; jj < 8; ++jj) { float f = (float)v[jj]; sum += f; ss += f * f; }
  }
  __shared__ float sh1[256], sh2[256];
  sh1[tid] = sum; sh2[tid] = ss;
  __syncthreads();
  for (int st = 128; st > 0; st >>= 1) {
    if (tid < st) { sh1[tid] += sh1[tid + st]; sh2[tid] += sh2[tid + st]; }
    __syncthreads();
  }
  if (tid == 0) {
    part[((b * 8 + g) * 8 + s) * 2] = sh1[0];
    part[((b * 8 + g) * 8 + s) * 2 + 1] = sh2[0];
  }
}

__global__ __launch_bounds__(256) void k_gn_apply_h(
    const f16* __restrict__ X, const float* __restrict__ gw,
    const float* __restrict__ gb, const float* __restrict__ part,
    f16* __restrict__ Q)
{
  int idx = blockIdx.x * blockDim.x + threadIdx.x;
  int total = Bn * HWl * 16;
  if (idx >= total) return;
  int u = idx & 15;
  int pix = (idx >> 4) % HWl;
  int b = idx / (16 * HWl);
  int c0 = u * 8;
  int g = c0 >> 4;
  const float* pp = part + ((b * 8 + g) * 8) * 2;
  float sum = 0.f, ss = 0.f;
#pragma unroll
  for (int s = 0; s < 8; ++s) { sum += pp[s * 2]; ss += pp[s * 2 + 1]; }
  const float n = 16.f * HWl;
  float mean = sum / n;
  float var = ss / n - mean * mean;
  float inv = rsqrtf(var + 1e-5f);
  f16x8 v = *(const f16x8*)&X[((size_t)b * HWl + pix) * 128 + c0];
  f16x8 r;
#pragma unroll
  for (int jj = 0; jj < 8; ++jj) {
    int c = c0 + jj;
    r[jj] = (f16)(((float)v[jj] - mean) * (gw[c] * inv) + gb[c]);
  }
  *(f16x8*)&Q[((size_t)b * HWl + pix) * 128 + c0] = r;
}

// softmax over the 9 points; attn NHWC [b][pix][48]
__global__ __launch_bounds__(256) void k_softmax9_h(f16* __restrict__ a)
{
  int idx = blockIdx.x * blockDim.x + threadIdx.x;
  if (idx >= Bn * NHd * HWl) return;
  int pix = idx % HWl;
  int head = (idx / HWl) & 3;
  int b = idx / (HWl * NHd);
  f16* base = a + ((size_t)b * HWl + pix) * 48 + head * 9;
  float v[9];
  float m = -1e30f;
#pragma unroll
  for (int p0 = 0; p0 < 9; ++p0) { v[p0] = (float)base[p0]; m = fmaxf(m, v[p0]); }
  float s = 0.f;
#pragma unroll
  for (int p0 = 0; p0 < 9; ++p0) { v[p0] = expf(v[p0] - m); s += v[p0]; }
  float inv = 1.f / s;
#pragma unroll
  for (int p0 = 0; p0 < 9; ++p0) base[p0] = (f16)(v[p0] * inv);
}

// ---------------------------------------------------------------------------
// Deformable sampling, NHWC. Thread per (b, head, pix), 32 head-channels.
// ---------------------------------------------------------------------------
__global__ __launch_bounds__(256) void k_deform_h(
    const f16* __restrict__ vals, const f16* __restrict__ off,
    const f16* __restrict__ attn, f16* __restrict__ outa)
{
  int idx = blockIdx.x * blockDim.x + threadIdx.x;
  if (idx >= Bn * NHd * HWl) return;
  int pix = idx % HWl;
  int head = (idx / HWl) & 3;
  int b = idx / (HWl * NHd);
  int j = pix % FW, i = pix / FW;

  const float kx = (float)FW / (float)(FW - 1);
  const float ky = (float)FH / (float)(FH - 1);
  const f16* vb = vals + (size_t)b * HWl * 128 + head * 32;
  const f16* ab = attn + ((size_t)b * HWl + pix) * 48 + head * 9;
  const f16* ob = off + ((size_t)b * HWl + pix) * 80 + head * 18;

  float acc[32];
#pragma unroll
  for (int k = 0; k < 32; ++k) acc[k] = 0.f;

#pragma unroll
  for (int p0 = 0; p0 < 9; ++p0) {
    float ox = (float)ob[p0 * 2];
    float oy = (float)ob[p0 * 2 + 1];
    float aw = (float)ab[p0];
    float xf = ((float)j + ox) * kx - 0.5f;
    float yf = ((float)i + oy) * ky - 0.5f;
    xf = fminf(fmaxf(xf, 0.f), (float)(FW - 1));
    yf = fminf(fmaxf(yf, 0.f), (float)(FH - 1));
    int x0 = (int)floorf(xf), y0 = (int)floorf(yf);
    int x1 = min(x0 + 1, FW - 1), y1 = min(y0 + 1, FH - 1);
    float fx = xf - (float)x0, fy = yf - (float)y0;
    float w00 = aw * (1.f - fx) * (1.f - fy);
    float w01 = aw * fx * (1.f - fy);
    float w10 = aw * (1.f - fx) * fy;
    float w11 = aw * fx * fy;
    const f16x8* c00 = (const f16x8*)&vb[(size_t)(y0 * FW + x0) * 128];
    const f16x8* c01 = (const f16x8*)&vb[(size_t)(y0 * FW + x1) * 128];
    const f16x8* c10 = (const f16x8*)&vb[(size_t)(y1 * FW + x0) * 128];
    const f16x8* c11 = (const f16x8*)&vb[(size_t)(y1 * FW + x1) * 128];
#pragma unroll
    for (int k8 = 0; k8 < 4; ++k8) {
      f16x8 a = c00[k8], bb = c01[k8], cc = c10[k8], dd = c11[k8];
#pragma unroll
      for (int jj = 0; jj < 8; ++jj)
        acc[k8 * 8 + jj] += w00 * (float)a[jj] + w01 * (float)bb[jj]
                          + w10 * (float)cc[jj] + w11 * (float)dd[jj];
    }
  }
  f16* op = outa + ((size_t)b * HWl + pix) * 128 + head * 32;
#pragma unroll
  for (int k = 0; k < 32; ++k) op[k] = (f16)acc[k];
}

// ---------------------------------------------------------------------------
// dec2: 32->3 conv from NHWC f16 window + sigmoid, NCHW f32 out rows [c0,+R).
// ---------------------------------------------------------------------------
__global__ __launch_bounds__(256) void k_dec2_h(
    const f16* __restrict__ Xb, const float* __restrict__ w,
    const float* __restrict__ bias, float* __restrict__ out,
    int c0, int b0, int brows, int R)
{
  int idx = blockIdx.x * blockDim.x + threadIdx.x;
  if (idx >= Bn * R * Wh) return;
  int x = idx % Wh;
  int y = c0 + (idx / Wh) % R;
  int b = idx / (Wh * R);
  float a0 = bias[0], a1 = bias[1], a2 = bias[2];
#pragma unroll
  for (int ky = 0; ky < 3; ++ky) {
    int gy = y + ky - 1;
    if (gy < 0 || gy >= Hh) continue;
#pragma unroll
    for (int kxx = 0; kxx < 3; ++kxx) {
      int gx = x + kxx - 1;
      if (gx < 0 || gx >= Wh) continue;
      int tap = ky * 3 + kxx;
      const f16* px = Xb + ((size_t)(b * brows + (gy - b0)) * Wh + gx) * 32;
#pragma unroll
      for (int k8 = 0; k8 < 4; ++k8) {
        f16x8 v = *(const f16x8*)&px[k8 * 8];
#pragma unroll
        for (int jj = 0; jj < 8; ++jj) {
          int ci = k8 * 8 + jj;
          float f = (float)v[jj];
          a0 += f * w[(0 * 32 + ci) * 9 + tap];
          a1 += f * w[(1 * 32 + ci) * 9 + tap];
          a2 += f * w[(2 * 32 + ci) * 9 + tap];
        }
      }
    }
  }
  size_t o = ((size_t)(b * 3 + 0) * Hh + y) * Wh + x;
  out[o] = 1.f / (1.f + expf(-a0));
  out[o + (size_t)Hh * Wh] = 1.f / (1.f + expf(-a1));
  out[o + (size_t)2 * Hh * Wh] = 1.f / (1.f + expf(-a2));
}

// ---------------------------------------------------------------------------
extern "C" void kernel_launch(void* const* d_in, const int* in_sizes, int n_in,
                              void* d_out, int out_size, void* d_ws, size_t ws_size,
                              hipStream_t stream) {
  (void)in_sizes; (void)n_in; (void)out_size; (void)ws_size;
  const float* feat1  = (const float*)d_in[0];
  const float* feat2  = (const float*)d_in[1];
  const float* flowf  = (const float*)d_in[2];
  const float* flowb  = (const float*)d_in[3];
  const float* edge1  = (const float*)d_in[4];
  const float* edge2  = (const float*)d_in[5];
  const float* fuse_w0 = (const float*)d_in[6];
  const float* fuse_b0 = (const float*)d_in[7];
  const float* fuse_w1 = (const float*)d_in[8];
  const float* fuse_b1 = (const float*)d_in[9];
  const float* gn_g   = (const float*)d_in[10];
  const float* gn_b   = (const float*)d_in[11];
  const float* off_w0 = (const float*)d_in[12];
  const float* off_b0 = (const float*)d_in[13];
  const float* off_w1 = (const float*)d_in[14];
  const float* off_b1 = (const float*)d_in[15];
  const float* aw_w0  = (const float*)d_in[16];
  const float* aw_b0  = (const float*)d_in[17];
  const float* aw_w1  = (const float*)d_in[18];
  const float* aw_b1  = (const float*)d_in[19];
  const float* val_w  = (const float*)d_in[20];
  const float* val_b  = (const float*)d_in[21];
  const float* out_w  = (const float*)d_in[22];
  const float* out_b  = (const float*)d_in[23];
  const float* ffn_w0 = (const float*)d_in[24];
  const float* ffn_b0 = (const float*)d_in[25];
  const float* ffn_w1 = (const float*)d_in[26];
  const float* ffn_b1 = (const float*)d_in[27];
  const float* dec_w0 = (const float*)d_in[28];
  const float* dec_b0 = (const float*)d_in[29];
  const float* dec_w1 = (const float*)d_in[30];
  const float* dec_b1 = (const float*)d_in[31];
  const float* dec_w2 = (const float*)d_in[32];
  const float* dec_b2 = (const float*)d_in[33];
  float* out = (float*)d_out;

  // ---- workspace layout (f16 units). Weights + zero page FIRST (decoder
  // overlay can never clobber them). Total ~83 MB.
  f16* ws16 = (f16*)d_ws;
  size_t o = 0;
  auto alloc = [&](size_t n) { f16* p = ws16 + o; o += (n + 7) & ~(size_t)7; return p; };
  f16* xbuf  = alloc((size_t)2 * HWl * 128);
  f16* zp    = alloc(98304);                    // 192KB zero page
  f16* wfF0 = alloc(9 * 9 * 8 * 512);
  f16* wfF1 = alloc(9 * 4 * 8 * 512);
  f16* wfOA = alloc(9 * 4 * 16 * 512);          // off0 (cf 0..7) + aw0 (cf 8..15)
  f16* wfD0 = alloc(9 * 4 * 4 * 512);
  f16* wfD1 = alloc(9 * 2 * 2 * 512);
  f16* w1O  = alloc(4 * 5 * 512);
  f16* w1A  = alloc(4 * 3 * 512);
  f16* w1V  = alloc(4 * 8 * 512);
  f16* w1U  = alloc(4 * 8 * 512);
  f16* w1G0 = alloc(4 * 16 * 512);
  f16* w1G1 = alloc(8 * 8 * 512);
  float* gnp = (float*)alloc(512);
  f16* pool  = ws16 + o;                        // decoder overlay starts here
  f16* regA  = alloc((size_t)2 * HWl * 288);    // fused / t_oa / ffn_t
  f16* regB  = alloc((size_t)2 * HWl * 128);    // source / out_attn
  f16* regC  = alloc((size_t)2 * HWl * 128);    // fuse0-out / qb
  f16* offb  = alloc((size_t)2 * HWl * 80);
  f16* attnb = alloc((size_t)2 * HWl * 48);
  f16* regF  = alloc((size_t)2 * HWl * 131);    // valsb
  f16* featT1 = alloc((size_t)2 * HWl * 128);
  f16* featT2 = alloc((size_t)2 * HWl * 128);

  f16* fused = regA;
  f16* t_oa  = regA;        // merged off/aw 3x3 out, 256 ch
  f16* ffn_t = regA;
  f16* src_h = regB;
  f16* out_attn = regB;
  f16* tmp_h = regC;
  f16* qb    = regC;
  f16* valsb = regF;
  // Decoder overlay over pool (dead after FFN). 96-row chunks:
  f16* bufU = pool;
  f16* bufA = bufU + (size_t)2 * 103 * 640 * 128;
  f16* bufB = bufA + (size_t)2 * 100 * 640 * 64;

  dim3 blk(256);
  auto pg = [](long n) { return dim3((unsigned)((n + 255) / 256)); };
  auto cg = [](int pixTiles, int coTiles) {
    return dim3((unsigned)((pixTiles * coTiles + 3) / 4), 1, 2);
  };
  const int BIG = 1 << 30;

  // ---- zero page init ----
  k_zero<<<dim3(48), blk, 0, stream>>>(zp, 12288);

  // ---- merged weight prep ----
  PrepArgs pa;
  int pb = 0;
  auto addj = [&](int k, const float* w, f16* wf, int Cout, int cing, int coutg,
                  int KS, int CoF, int taps, int CoFt, int cf0) {
    pa.j[k] = PrepJob{w, wf, Cout, cing, coutg, KS, CoF, taps, CoFt, cf0, pb};
    pb += (taps * KS * CoF * 64 + 255) / 256;
  };
  addj(0, fuse_w0, wfF0, 128, 259, 128, 9, 8, 9, 8, 0);
  addj(1, fuse_w1, wfF1, 128, 128, 128, 4, 8, 9, 8, 0);
  addj(2, off_w0, wfOA, 128, 32, 32, 4, 8, 9, 16, 0);
  addj(3, aw_w0,  wfOA, 128, 32, 32, 4, 8, 9, 16, 8);
  addj(4, dec_w0, wfD0, 64, 128, 64, 4, 4, 9, 4, 0);
  addj(5, dec_w1, wfD1, 32, 64, 32, 2, 2, 9, 2, 0);
  addj(6, off_w1, w1O, 72, 128, 72, 4, 5, 1, 5, 0);
  addj(7, aw_w1,  w1A, 36, 128, 36, 4, 3, 1, 3, 0);
  addj(8, val_w,  w1V, 128, 128, 128, 4, 8, 1, 8, 0);
  addj(9, out_w,  w1U, 128, 128, 128, 4, 8, 1, 8, 0);
  addj(10, ffn_w0, w1G0, 256, 128, 256, 4, 16, 1, 16, 0);
  addj(11, ffn_w1, w1G1, 128, 256, 128, 8, 8, 1, 8, 0);
  k_wprep_all<<<dim3((unsigned)pb), blk, 0, stream>>>(pa);

  // ---- 0. feats -> NHWC f16 ----
  k_tr_h<<<pg(2L * Bn * HWl * 8), blk, 0, stream>>>(feat1, feat2, featT1, featT2);
  // ---- 1. warp + concat + source ----
  k_warp_fuse_h<<<pg((long)Bn * HWl * 8), blk, 0, stream>>>(featT1, featT2, flowf, flowb,
                                                            edge1, edge2, fused, src_h);
  // ---- 2-3. fuse convs (pipelined + SGB) ----
  k_conv3g<1, 2, 4, 160, 9><<<cg(480, 2), blk, 0, stream>>>(fused, wfF0, fuse_b0, fuse_b0, BIG,
      tmp_h, zp, 8, 288, 128, FH, 0, FH, 0, FH, 0, FH, 2);
  k_conv3g<1, 2, 4, 160, 4><<<cg(480, 2), blk, 0, stream>>>(tmp_h, wfF1, fuse_b1, fuse_b1, BIG,
      xbuf, zp, 8, 128, 128, FH, 0, FH, 0, FH, 0, FH, 2);
  // ---- 4. group norm ----
  k_gn_part_h<<<dim3(128), blk, 0, stream>>>(xbuf, gnp);
  k_gn_apply_h<<<pg(2L * HWl * 16), blk, 0, stream>>>(xbuf, gn_g, gn_b, gnp, qb);
  // ---- 5. merged off0+aw0 grouped 3x3 (256 out ch, dual bias) ----
  k_conv3g<1, 2, 4, 160, 4><<<cg(480, 4), blk, 0, stream>>>(qb, wfOA, off_b0, aw_b0, 128,
      t_oa, zp, 16, 128, 256, FH, 0, FH, 0, FH, 0, FH, 4);
  // ---- 6-8. 1x1 heads + softmax ----
  k_gemm1x1<0, 0, 4><<<dim3(480), blk, 0, stream>>>(t_oa, w1O, off_b1, offb,
      5, 256, 80, 72, 2, 960);
  k_gemm1x1<0, 0, 4><<<dim3(240), blk, 0, stream>>>(t_oa + 128, w1A, aw_b1, attnb,
      3, 256, 48, 36, 1, 960);
  k_softmax9_h<<<pg(2L * NHd * HWl), blk, 0, stream>>>(attnb);
  // ---- 9. vals ----
  k_gemm1x1<0, 0, 4><<<dim3(480), blk, 0, stream>>>(src_h, w1V, val_b, valsb,
      8, 128, 128, 128, 2, 960);
  // ---- 10. deform ----
  k_deform_h<<<pg(2L * NHd * HWl), blk, 0, stream>>>(valsb, offb, attnb, out_attn);
  // ---- 11. out-proj (residual into xbuf) ----
  k_gemm1x1<0, 1, 4><<<dim3(480), blk, 0, stream>>>(out_attn, w1U, out_b, xbuf,
      8, 128, 128, 128, 2, 960);
  // ---- 12-13. FFN ----
  k_gemm1x1<2, 0, 4><<<dim3(960), blk, 0, stream>>>(xbuf, w1G0, ffn_b0, ffn_t,
      16, 128, 256, 256, 4, 960);
  k_gemm1x1<0, 1, 8><<<dim3(480), blk, 0, stream>>>(ffn_t, w1G1, ffn_b1, xbuf,
      8, 256, 128, 128, 2, 960);

  // ---- 14. decoder, 4 chunks of 96 rows: up4 -> dec0 -> dec1 -> dec2 ----
  for (int c0 = 0; c0 < Hh; c0 += 96) {
    int c1 = c0 + 96;
    int a0 = c0 - 2 > 0 ? c0 - 2 : 0;
    int a1 = c1 + 2 < Hh ? c1 + 2 : Hh;
    int b0 = c0 - 1 > 0 ? c0 - 1 : 0;
    int b1 = c1 + 1 < Hh ? c1 + 1 : Hh;
    int u0 = a0 - 1 > 0 ? a0 - 1 : 0;
    int u1 = a1 + 1 < Hh ? a1 + 1 : Hh;
    int ar = a1 - a0, br = b1 - b0, ur = u1 - u0;
    // upsample rows [u0,u1) -> bufU
    k_up4_h<<<pg(2L * ur * Wh * 8), blk, 0, stream>>>(xbuf, bufU, u0, ur);
    // dec0: 128->64, rows [a0,a1) -> bufA  (M=2, NF=4, KS=4)
    k_conv3g<1, 2, 4, 640, 4><<<cg(ar * 20, 1), blk, 0, stream>>>(bufU, wfD0, dec_b0, dec_b0, BIG,
        bufA, zp, 4, 128, 64, Hh, u0, ur, a0, ar, a0, ar, 1);
    // dec1: 64->32, rows [b0,b1) -> bufB  (M=2, NF=2, KS=2)
    k_conv3g<1, 2, 2, 640, 2><<<cg(br * 20, 1), blk, 0, stream>>>(bufA, wfD1, dec_b1, dec_b1, BIG,
        bufB, zp, 2, 64, 32, Hh, a0, ar, b0, br, b0, br, 1);
    // dec2: 32->3 + sigmoid -> out rows [c0,c1)
    k_dec2_h<<<pg(2L * 96 * Wh), blk, 0, stream>>>(bufB, dec_w2, dec_b2, out,
                                                   c0, b0, br, 96);
  }
}

// Round 15
// 518.949 us; speedup vs baseline: 1.5140x; 1.3067x over previous
//
#include <hip/hip_runtime.h>

typedef _Float16 f16;
typedef _Float16 f16x8 __attribute__((ext_vector_type(8)));
typedef float f32x4 __attribute__((ext_vector_type(4)));

constexpr int Bn = 2, Cn = 128, FH = 96, FW = 160, Hh = 384, Wh = 640;
constexpr int HWl = FH * FW;   // 15360
constexpr int NHd = 4, NPt = 9;

#define DEVINL __device__ __forceinline__

DEVINL f32x4 zero4() { f32x4 z; z[0] = 0.f; z[1] = 0.f; z[2] = 0.f; z[3] = 0.f; return z; }
DEVINL f16x8 zero8() {
  f16x8 z;
#pragma unroll
  for (int j = 0; j < 8; ++j) z[j] = (f16)0.f;
  return z;
}

template<int ACT> DEVINL float activ(float v) {
  if (ACT == 1) return v >= 0.f ? v : 0.1f * v;                           // leaky relu
  if (ACT == 2) return 0.5f * v * (1.f + erff(v * 0.70710678118654752f)); // exact gelu
  if (ACT == 3) return 1.f / (1.f + expf(-v));                            // sigmoid
  return v;
}

// Zero page (conv3g rows outside the image read here).
__global__ __launch_bounds__(256) void k_zero(f16* __restrict__ p, int n8)
{
  int i = blockIdx.x * 256 + threadIdx.x;
  if (i < n8) *(f16x8*)&p[(size_t)i * 8] = zero8();
}

// ---------------------------------------------------------------------------
// Merged weight prep (12 jobs). 3x3: [tap][ks][CoFt cf0+cf][lane][8];
// 1x1: [ks][cf][lane][8]. k = (lane>>4)*8+j. Grouped convs zero-padded.
// ---------------------------------------------------------------------------
struct PrepJob { const float* w; f16* wf; int Cout, cin_g, cout_g, KS, CoF, taps, CoFt, cf0, blk0; };
struct PrepArgs { PrepJob j[12]; };

__global__ __launch_bounds__(256) void k_wprep_all(PrepArgs a)
{
  int jb = 0;
#pragma unroll
  for (int t = 1; t < 12; ++t) if ((int)blockIdx.x >= a.j[t].blk0) jb = t;
  PrepJob J = a.j[jb];
  int idx = (blockIdx.x - J.blk0) * 256 + threadIdx.x;
  int total = J.taps * J.KS * J.CoF * 64;
  if (idx >= total) return;
  int lane = idx & 63;
  int rest = idx >> 6;
  int cf = rest % J.CoF;
  int rest2 = rest / J.CoF;
  int ks = rest2 % J.KS;
  int tap = rest2 / J.KS;
  int co = cf * 16 + (lane & 15);
  f16x8 v = zero8();
#pragma unroll
  for (int j = 0; j < 8; ++j) {
    int cip = ks * 32 + (lane >> 4) * 8 + j;
    int cil = cip - (co / J.cout_g) * J.cin_g;
    float x = 0.f;
    if (co < J.Cout && cil >= 0 && cil < J.cin_g)
      x = J.w[((size_t)co * J.cin_g + cil) * J.taps + tap];
    v[j] = (f16)x;
  }
  size_t oidx = (((size_t)tap * J.KS + ks) * J.CoFt + J.cf0 + cf) * 64 + lane;
  *(f16x8*)&J.wf[oidx * 8] = v;
}

// ---------------------------------------------------------------------------
// NCHW f32 -> NHWC f16 transpose for feat1+feat2.
// ---------------------------------------------------------------------------
__global__ __launch_bounds__(256) void k_tr_h(
    const float* __restrict__ feat1, const float* __restrict__ feat2,
    f16* __restrict__ t1, f16* __restrict__ t2)
{
  int idx = blockIdx.x * blockDim.x + threadIdx.x;
  if (idx >= 2 * Bn * HWl * 8) return;
  int cq = idx & 7;
  int pix = (idx >> 3) % HWl;
  int z = idx / (8 * HWl);
  int b = z & 1;
  const float* src = (z >> 1) ? feat2 : feat1;
  f16* dst = (z >> 1) ? t2 : t1;
  int c0 = cq * 16;
  f16x8 v0, v1;
#pragma unroll
  for (int j = 0; j < 8; ++j) {
    v0[j] = (f16)src[(size_t)(b * Cn + c0 + j) * HWl + pix];
    v1[j] = (f16)src[(size_t)(b * Cn + c0 + 8 + j) * HWl + pix];
  }
  f16* dp = dst + ((size_t)b * HWl + pix) * 128 + c0;
  *(f16x8*)dp = v0;
  *(f16x8*)(dp + 8) = v1;
}

// ---------------------------------------------------------------------------
// Warp + concat + source, NHWC f16, cq-fastest lanes (coalesced).
// ---------------------------------------------------------------------------
__global__ __launch_bounds__(256) void k_warp_fuse_h(
    const f16* __restrict__ t1, const f16* __restrict__ t2,
    const float* __restrict__ flowf, const float* __restrict__ flowb,
    const float* __restrict__ edge1, const float* __restrict__ edge2,
    f16* __restrict__ fused, f16* __restrict__ src)
{
  int idx = blockIdx.x * blockDim.x + threadIdx.x;
  if (idx >= Bn * HWl * 8) return;
  int cq = idx & 7;
  int pix = (idx >> 3) % HWl;
  int b = idx / (8 * HWl);
  int j = pix % FW;
  int i = pix / FW;

  const int y4 = 4 * i + 1, x4 = 4 * j + 1;
  const float* p;
  p = flowf + (size_t)((b * 2 + 0) * Hh + y4) * Wh + x4;
  float fx1 = 0.03125f * (p[0] + p[1] + p[Wh] + p[Wh + 1]);
  p = flowf + (size_t)((b * 2 + 1) * Hh + y4) * Wh + x4;
  float fy1 = 0.03125f * (p[0] + p[1] + p[Wh] + p[Wh + 1]);
  p = flowb + (size_t)((b * 2 + 0) * Hh + y4) * Wh + x4;
  float fx2 = 0.03125f * (p[0] + p[1] + p[Wh] + p[Wh + 1]);
  p = flowb + (size_t)((b * 2 + 1) * Hh + y4) * Wh + x4;
  float fy2 = 0.03125f * (p[0] + p[1] + p[Wh] + p[Wh + 1]);

  float sx1 = fminf(fmaxf((float)j + fx1, 0.f), (float)(FW - 1));
  float sy1 = fminf(fmaxf((float)i + fy1, 0.f), (float)(FH - 1));
  float sx2 = fminf(fmaxf((float)j + fx2, 0.f), (float)(FW - 1));
  float sy2 = fminf(fmaxf((float)i + fy2, 0.f), (float)(FH - 1));

  int x10 = (int)floorf(sx1), y10 = (int)floorf(sy1);
  int x11 = min(x10 + 1, FW - 1), y11 = min(y10 + 1, FH - 1);
  float wx1 = sx1 - (float)x10, wy1 = sy1 - (float)y10;
  int x20 = (int)floorf(sx2), y20 = (int)floorf(sy2);
  int x21 = min(x20 + 1, FW - 1), y21 = min(y20 + 1, FH - 1);
  float wx2 = sx2 - (float)x20, wy2 = sy2 - (float)y20;

  float a00 = (1.f - wx1) * (1.f - wy1), a01 = wx1 * (1.f - wy1);
  float a10 = (1.f - wx1) * wy1,         a11 = wx1 * wy1;
  float c00 = (1.f - wx2) * (1.f - wy2), c01 = wx2 * (1.f - wy2);
  float c10 = (1.f - wx2) * wy2,         c11 = wx2 * wy2;

  int c0 = cq * 16;
  const f16* b1 = t1 + (size_t)b * HWl * 128 + c0;
  const f16* b2 = t2 + (size_t)b * HWl * 128 + c0;
  const f16x8* p100 = (const f16x8*)&b1[(size_t)(y10 * FW + x10) * 128];
  const f16x8* p101 = (const f16x8*)&b1[(size_t)(y10 * FW + x11) * 128];
  const f16x8* p110 = (const f16x8*)&b1[(size_t)(y11 * FW + x10) * 128];
  const f16x8* p111 = (const f16x8*)&b1[(size_t)(y11 * FW + x11) * 128];
  const f16x8* p200 = (const f16x8*)&b2[(size_t)(y20 * FW + x20) * 128];
  const f16x8* p201 = (const f16x8*)&b2[(size_t)(y20 * FW + x21) * 128];
  const f16x8* p210 = (const f16x8*)&b2[(size_t)(y21 * FW + x20) * 128];
  const f16x8* p211 = (const f16x8*)&b2[(size_t)(y21 * FW + x21) * 128];

  f16* fp = fused + ((size_t)b * HWl + pix) * 288;
  f16* sp = src + ((size_t)b * HWl + pix) * 128;

#pragma unroll
  for (int h = 0; h < 2; ++h) {
    f16x8 u00 = p100[h], u01 = p101[h], u10 = p110[h], u11 = p111[h];
    f16x8 w00 = p200[h], w01 = p201[h], w10 = p210[h], w11 = p211[h];
    f16x8 r1, r2, rs;
#pragma unroll
    for (int k = 0; k < 8; ++k) {
      float v1 = (float)u00[k] * a00 + (float)u01[k] * a01
               + (float)u10[k] * a10 + (float)u11[k] * a11;
      float v2 = (float)w00[k] * c00 + (float)w01[k] * c01
               + (float)w10[k] * c10 + (float)w11[k] * c11;
      r1[k] = (f16)v1; r2[k] = (f16)v2; rs[k] = (f16)(0.5f * (v1 + v2));
    }
    *(f16x8*)(fp + c0 + h * 8) = r1;
    *(f16x8*)(fp + 128 + c0 + h * 8) = r2;
    *(f16x8*)(sp + c0 + h * 8) = rs;
  }

  if (cq == 0) {
    p = edge1 + (size_t)(b * Hh + y4) * Wh + x4;
    float e1v = 0.25f * (p[0] + p[1] + p[Wh] + p[Wh + 1]);
    p = edge2 + (size_t)(b * Hh + y4) * Wh + x4;
    float e2v = 0.25f * (p[0] + p[1] + p[Wh] + p[Wh + 1]);
    fp[256] = (f16)e1v;
    fp[257] = (f16)e2v;
    fp[258] = (f16)0.5f;
#pragma unroll
    for (int c = 259; c < 288; ++c) fp[c] = (f16)0.f;
  }
}

// ---------------------------------------------------------------------------
// Barrier-free MFMA 3x3 conv for L2-resident (low-res) inputs — 2-stage
// pipeline + sched_group_barrier. Used for fuse0/fuse1/off+aw.
// ---------------------------------------------------------------------------
template<int ACT, int M, int NF, int W, int KS>
__global__ __launch_bounds__(256, 2) void k_conv3g(
    const f16* __restrict__ X, const f16* __restrict__ Wf,
    const float* __restrict__ bias, const float* __restrict__ bias2, int bsplit,
    f16* __restrict__ Out, const f16* __restrict__ zpage,
    int CoF, int Cs_in, int Cs_out, int Htot,
    int in_r0, int in_rows, int out_r0, int out_rows,
    int ogr0, int nrows, int coTiles)
{
  int wid = blockIdx.x * 4 + (threadIdx.x >> 6);
  int lane = threadIdx.x & 63;
  int l15 = lane & 15, l4 = lane >> 4;
  int pixTiles = nrows * W / (M * 16);
  if (wid >= pixTiles * coTiles) return;
  int coT = wid % coTiles;
  int pixT = wid / coTiles;
  int b = blockIdx.z;
  int base = pixT * (M * 16);
  int row = ogr0 + base / W;       // wave-uniform (16M | W)
  int colB = base % W;

  f32x4 acc[M][NF];
#pragma unroll
  for (int mf = 0; mf < M; ++mf)
#pragma unroll
    for (int nf = 0; nf < NF; ++nf) acc[mf][nf] = zero4();

  const f16* rp[3];
#pragma unroll
  for (int ky = 0; ky < 3; ++ky) {
    int srow = row + ky - 1;
    bool rv = (srow >= 0 && srow < Htot);
    int crow = min(max(srow, in_r0), in_r0 + in_rows - 1);
    const f16* real = X + ((size_t)(b * in_rows + (crow - in_r0)) * W) * Cs_in + l4 * 8;
    rp[ky] = rv ? real : (zpage + l4 * 8);
  }
  int sc[3][M]; bool okc[3][M];
#pragma unroll
  for (int kx = 0; kx < 3; ++kx)
#pragma unroll
    for (int mf = 0; mf < M; ++mf) {
      int scol = colB + mf * 16 + l15 + kx - 1;
      okc[kx][mf] = (unsigned)scol < (unsigned)W;
      sc[kx][mf] = min(max(scol, 0), W - 1);
    }

  const f16* wb = Wf + (size_t)coT * NF * 512;
  constexpr int G = KS * 3;
  constexpr int NLD = 3 * (M + NF);
  constexpr int NMM = 3 * M * NF;

  f16x8 Afb[2][3][M];
  f16x8 Bfb[2][3][NF];

  auto loadGroup = [&](int g, int buf) {
    int cs = g / 3, ky = g % 3;
#pragma unroll
    for (int kx = 0; kx < 3; ++kx) {
#pragma unroll
      for (int mf = 0; mf < M; ++mf) {
        f16x8 t = *(const f16x8*)&rp[ky][(size_t)sc[kx][mf] * Cs_in + cs * 32];
        if ((kx == 0 && mf == 0) || (kx == 2 && mf == M - 1))
          t = okc[kx][mf] ? t : zero8();
        Afb[buf][kx][mf] = t;
      }
#pragma unroll
      for (int nf = 0; nf < NF; ++nf)
        Bfb[buf][kx][nf] =
            *(const f16x8*)&wb[((((size_t)(ky * 3 + kx) * KS + cs) * CoF + nf) * 64 + lane) * 8];
    }
  };

  loadGroup(0, 0);
  __builtin_amdgcn_sched_group_barrier(0x20, NLD, 0);   // VMEM_READ
#pragma unroll
  for (int g = 0; g < G; ++g) {
    int cb = g & 1;
    if (g + 1 < G) loadGroup(g + 1, cb ^ 1);
#pragma unroll
    for (int kx = 0; kx < 3; ++kx)
#pragma unroll
      for (int mf = 0; mf < M; ++mf)
#pragma unroll
        for (int nf = 0; nf < NF; ++nf)
          acc[mf][nf] = __builtin_amdgcn_mfma_f32_16x16x32_f16(
              Afb[cb][kx][mf], Bfb[cb][kx][nf], acc[mf][nf], 0, 0, 0);
    if (g + 1 < G) __builtin_amdgcn_sched_group_barrier(0x20, NLD, 0);
    __builtin_amdgcn_sched_group_barrier(0x8, NMM, 0);  // MFMA
  }

  size_t rowoff = ((size_t)b * out_rows + (row - out_r0)) * W;
#pragma unroll
  for (int nf = 0; nf < NF; ++nf) {
    int co = coT * (NF * 16) + nf * 16 + l15;
    float bv = (co < bsplit) ? bias[co] : bias2[co - bsplit];
#pragma unroll
    for (int mf = 0; mf < M; ++mf) {
      int xo = colB + mf * 16 + l4 * 4;
#pragma unroll
      for (int rg = 0; rg < 4; ++rg) {
        float v = activ<ACT>(acc[mf][nf][rg] + bv);
        Out[(rowoff + xo + rg) * (size_t)Cs_out + co] = (f16)v;
      }
    }
  }
}

// ---------------------------------------------------------------------------
// LDS-staged MFMA 3x3 conv for HBM-scale (decoder) inputs — register-prefetch
// double buffer, upsample fused into staging (UP=1). R5-verified (610 us).
// Block = 4 waves; wave w = tile row w. Tile: 4 rows x 32 cols x NF*16 co.
// ---------------------------------------------------------------------------
template<int ACT, int UP, int NF>
__global__ __launch_bounds__(256) void k_conv3m(
    const f16* __restrict__ Xin, const f16* __restrict__ Wf,
    const float* __restrict__ bias, f16* __restrict__ Out,
    int KS, int CoF, int Cs_in, int Cs_out, int Wd, int Ht,
    int in_r0, int in_rows, int out_r0, int out_rows, int ogr0, int ogr1)
{
  __shared__ f16 sA[8160];   // 6 rows x 34 cols x 40 f16 (80 B/px)
  int tid = threadIdx.x;
  int wv = tid >> 6, lane = tid & 63;
  int l15 = lane & 15, l4 = lane >> 4;
  int colTiles = Wd >> 5;
  int tileC = blockIdx.x % colTiles, tileR = blockIdx.x / colTiles;
  int b = blockIdx.z;
  int co0 = blockIdx.y * (NF * 16);
  int cfB = blockIdx.y * NF;
  int rowBaseOut = ogr0 + tileR * 4;
  int rowBase = rowBaseOut - 1;
  int colBase = tileC * 32;

  f32x4 acc[2][NF];
#pragma unroll
  for (int mf = 0; mf < 2; ++mf)
#pragma unroll
    for (int nf = 0; nf < NF; ++nf) acc[mf][nf] = zero4();

  f16x8 stv[4];        // UP=0 staged values
  f16x8 stc[4][4];     // UP=1 staged corners

  auto prefetch = [&](int cs) {
#pragma unroll
    for (int k = 0; k < 4; ++k) {
      int u = tid + k * 256;
      if (u < 816) {
        int s = u & 3;
        int pxy = u >> 2;
        int x = pxy % 34, y = pxy / 34;
        int gy = rowBase + y, gx = colBase + x - 1;
        if (UP) {
          stc[k][0] = zero8(); stc[k][1] = zero8();
          stc[k][2] = zero8(); stc[k][3] = zero8();
          if (gy >= 0 && gy < Ht && gx >= 0 && gx < Wd) {
            float uy = ((float)gy + 0.5f) * 0.25f - 0.5f;
            uy = fminf(fmaxf(uy, 0.f), (float)(FH - 1));
            int y0 = (int)floorf(uy);
            int y1 = min(y0 + 1, FH - 1);
            float ux = ((float)gx + 0.5f) * 0.25f - 0.5f;
            ux = fminf(fmaxf(ux, 0.f), (float)(FW - 1));
            int x0 = (int)floorf(ux);
            int x1 = min(x0 + 1, FW - 1);
            const f16* xb = Xin + (size_t)b * HWl * 128 + cs * 32 + s * 8;
            stc[k][0] = *(const f16x8*)&xb[(size_t)(y0 * FW + x0) * 128];
            stc[k][1] = *(const f16x8*)&xb[(size_t)(y0 * FW + x1) * 128];
            stc[k][2] = *(const f16x8*)&xb[(size_t)(y1 * FW + x0) * 128];
            stc[k][3] = *(const f16x8*)&xb[(size_t)(y1 * FW + x1) * 128];
          }
        } else {
          stv[k] = zero8();
          if (gy >= in_r0 && gy < in_r0 + in_rows && gx >= 0 && gx < Wd)
            stv[k] = *(const f16x8*)&Xin[(((size_t)b * in_rows + (gy - in_r0)) * Wd + gx) * Cs_in
                                         + cs * 32 + s * 8];
        }
      }
    }
  };

  auto writeLDS = [&]() {
#pragma unroll
    for (int k = 0; k < 4; ++k) {
      int u = tid + k * 256;
      if (u < 816) {
        int s = u & 3;
        int pxy = u >> 2;
        f16x8 v;
        if (UP) {
          int x = pxy % 34, y = pxy / 34;
          int gy = rowBase + y, gx = colBase + x - 1;
          float uy = ((float)gy + 0.5f) * 0.25f - 0.5f;
          uy = fminf(fmaxf(uy, 0.f), (float)(FH - 1));
          float fy = uy - floorf(uy);
          float ux = ((float)gx + 0.5f) * 0.25f - 0.5f;
          ux = fminf(fmaxf(ux, 0.f), (float)(FW - 1));
          float fx = ux - floorf(ux);
#pragma unroll
          for (int jj = 0; jj < 8; ++jj) {
            float t0 = (float)stc[k][0][jj] * (1.f - fx) + (float)stc[k][1][jj] * fx;
            float t1 = (float)stc[k][2][jj] * (1.f - fx) + (float)stc[k][3][jj] * fx;
            v[jj] = (f16)(t0 * (1.f - fy) + t1 * fy);
          }
        } else {
          v = stv[k];
        }
        *(f16x8*)((char*)sA + pxy * 80 + s * 16) = v;
      }
    }
  };

  prefetch(0);
  for (int cs = 0; cs < KS; ++cs) {
    writeLDS();
    __syncthreads();
    if (cs + 1 < KS) prefetch(cs + 1);   // latency hides under MFMA phase
#pragma unroll
    for (int ky = 0; ky < 3; ++ky) {
#pragma unroll
      for (int kx = 0; kx < 3; ++kx) {
        const char* ab = (const char*)sA;
        f16x8 a0 = *(const f16x8*)(ab + ((wv + ky) * 34 + l15 + kx) * 80 + l4 * 16);
        f16x8 a1 = *(const f16x8*)(ab + ((wv + ky) * 34 + l15 + 16 + kx) * 80 + l4 * 16);
        int tap = ky * 3 + kx;
#pragma unroll
        for (int nf = 0; nf < NF; ++nf) {
          f16x8 bf = *(const f16x8*)&Wf[((((size_t)tap * KS + cs) * CoF + cfB + nf) * 64 + lane) * 8];
          acc[0][nf] = __builtin_amdgcn_mfma_f32_16x16x32_f16(a0, bf, acc[0][nf], 0, 0, 0);
          acc[1][nf] = __builtin_amdgcn_mfma_f32_16x16x32_f16(a1, bf, acc[1][nf], 0, 0, 0);
        }
      }
    }
    __syncthreads();
  }

  int r = rowBaseOut + wv;
  if (r < ogr1) {
    size_t rowoff = ((size_t)b * out_rows + (r - out_r0)) * Wd;
#pragma unroll
    for (int nf = 0; nf < NF; ++nf) {
      int co = co0 + nf * 16 + l15;
      float bv = bias[co];
#pragma unroll
      for (int mf = 0; mf < 2; ++mf) {
        int xo = colBase + mf * 16 + l4 * 4;
#pragma unroll
        for (int rg = 0; rg < 4; ++rg) {
          float v = activ<ACT>(acc[mf][nf][rg] + bv);
          Out[(rowoff + xo + rg) * Cs_out + co] = (f16)v;
        }
      }
    }
  }
}

// ---------------------------------------------------------------------------
// MFMA 1x1 conv (pure GEMM), 2-stage pipeline + SGB.
// ---------------------------------------------------------------------------
template<int ACT, int RES, int KS>
__global__ __launch_bounds__(256, 2) void k_gemm1x1(
    const f16* __restrict__ X, const f16* __restrict__ Wf,
    const float* __restrict__ bias, f16* __restrict__ Out,
    int CoF, int Cs_in, int Cs_out, int Cr, int coTiles, int pixTiles)
{
  int wid = blockIdx.x * 4 + (threadIdx.x >> 6);
  int lane = threadIdx.x & 63;
  int total = pixTiles * coTiles;
  if (wid >= total) return;
  int coT = wid % coTiles;
  int pixT = wid / coTiles;
  int l15 = lane & 15, l4 = lane >> 4;

  f32x4 acc[2][4];
#pragma unroll
  for (int mf = 0; mf < 2; ++mf)
#pragma unroll
    for (int nf = 0; nf < 4; ++nf) acc[mf][nf] = zero4();

  int pA0 = pixT * 32 + l15;
  f16x8 Ab[2][2];
  f16x8 Bb[2][4];
  auto load = [&](int ks, int buf) {
    Ab[buf][0] = *(const f16x8*)&X[(size_t)pA0 * Cs_in + ks * 32 + l4 * 8];
    Ab[buf][1] = *(const f16x8*)&X[(size_t)(pA0 + 16) * Cs_in + ks * 32 + l4 * 8];
#pragma unroll
    for (int nf = 0; nf < 4; ++nf)
      Bb[buf][nf] = *(const f16x8*)&Wf[(((size_t)ks * CoF + coT * 4 + nf) * 64 + lane) * 8];
  };

  load(0, 0);
  __builtin_amdgcn_sched_group_barrier(0x20, 6, 0);
#pragma unroll
  for (int ks = 0; ks < KS; ++ks) {
    int cb = ks & 1;
    if (ks + 1 < KS) load(ks + 1, cb ^ 1);
#pragma unroll
    for (int nf = 0; nf < 4; ++nf) {
      acc[0][nf] = __builtin_amdgcn_mfma_f32_16x16x32_f16(Ab[cb][0], Bb[cb][nf], acc[0][nf], 0, 0, 0);
      acc[1][nf] = __builtin_amdgcn_mfma_f32_16x16x32_f16(Ab[cb][1], Bb[cb][nf], acc[1][nf], 0, 0, 0);
    }
    if (ks + 1 < KS) __builtin_amdgcn_sched_group_barrier(0x20, 6, 0);
    __builtin_amdgcn_sched_group_barrier(0x8, 8, 0);
  }
#pragma unroll
  for (int nf = 0; nf < 4; ++nf) {
    int co = coT * 64 + nf * 16 + l15;
    if (co < Cr) {
      float bv = bias[co];
#pragma unroll
      for (int mf = 0; mf < 2; ++mf) {
        int p0 = pixT * 32 + mf * 16 + l4 * 4;
#pragma unroll
        for (int rg = 0; rg < 4; ++rg) {
          float v = activ<ACT>(acc[mf][nf][rg] + bv);
          size_t o = (size_t)(p0 + rg) * Cs_out + co;
          if (RES) v += (float)Out[o];
          Out[o] = (f16)v;
        }
      }
    }
  }
}

// ---------------------------------------------------------------------------
// GroupNorm on NHWC f16, two stage.
// ---------------------------------------------------------------------------
__global__ __launch_bounds__(256) void k_gn_part_h(
    const f16* __restrict__ X, float* __restrict__ part)
{
  int s = blockIdx.x & 7;
  int g = (blockIdx.x >> 3) & 7;
  int b = blockIdx.x >> 6;
  int tid = threadIdx.x;
  const f16* Xp = X + (size_t)b * HWl * 128 + g * 16 + (tid & 1) * 8;
  float sum = 0.f, ss = 0.f;
  for (int p = s * 1920 + (tid >> 1); p < (s + 1) * 1920; p += 128) {
    f16x8 v = *(const f16x8*)&Xp[(size_t)p * 128];
#pragma unroll
    for (int jj = 0; jj < 8; ++jj) { float f = (float)v[jj]; sum += f; ss += f * f; }
  }
  __shared__ float sh1[256], sh2[256];
  sh1[tid] = sum; sh2[tid] = ss;
  __syncthreads();
  for (int st = 128; st > 0; st >>= 1) {
    if (tid < st) { sh1[tid] += sh1[tid + st]; sh2[tid] += sh2[tid + st]; }
    __syncthreads();
  }
  if (tid == 0) {
    part[((b * 8 + g) * 8 + s) * 2] = sh1[0];
    part[((b * 8 + g) * 8 + s) * 2 + 1] = sh2[0];
  }
}

__global__ __launch_bounds__(256) void k_gn_apply_h(
    const f16* __restrict__ X, const float* __restrict__ gw,
    const float* __restrict__ gb, const float* __restrict__ part,
    f16* __restrict__ Q)
{
  int idx = blockIdx.x * blockDim.x + threadIdx.x;
  int total = Bn * HWl * 16;
  if (idx >= total) return;
  int u = idx & 15;
  int pix = (idx >> 4) % HWl;
  int b = idx / (16 * HWl);
  int c0 = u * 8;
  int g = c0 >> 4;
  const float* pp = part + ((b * 8 + g) * 8) * 2;
  float sum = 0.f, ss = 0.f;
#pragma unroll
  for (int s = 0; s < 8; ++s) { sum += pp[s * 2]; ss += pp[s * 2 + 1]; }
  const float n = 16.f * HWl;
  float mean = sum / n;
  float var = ss / n - mean * mean;
  float inv = rsqrtf(var + 1e-5f);
  f16x8 v = *(const f16x8*)&X[((size_t)b * HWl + pix) * 128 + c0];
  f16x8 r;
#pragma unroll
  for (int jj = 0; jj < 8; ++jj) {
    int c = c0 + jj;
    r[jj] = (f16)(((float)v[jj] - mean) * (gw[c] * inv) + gb[c]);
  }
  *(f16x8*)&Q[((size_t)b * HWl + pix) * 128 + c0] = r;
}

// softmax over the 9 points; attn NHWC [b][pix][48]
__global__ __launch_bounds__(256) void k_softmax9_h(f16* __restrict__ a)
{
  int idx = blockIdx.x * blockDim.x + threadIdx.x;
  if (idx >= Bn * NHd * HWl) return;
  int pix = idx % HWl;
  int head = (idx / HWl) & 3;
  int b = idx / (HWl * NHd);
  f16* base = a + ((size_t)b * HWl + pix) * 48 + head * 9;
  float v[9];
  float m = -1e30f;
#pragma unroll
  for (int p0 = 0; p0 < 9; ++p0) { v[p0] = (float)base[p0]; m = fmaxf(m, v[p0]); }
  float s = 0.f;
#pragma unroll
  for (int p0 = 0; p0 < 9; ++p0) { v[p0] = expf(v[p0] - m); s += v[p0]; }
  float inv = 1.f / s;
#pragma unroll
  for (int p0 = 0; p0 < 9; ++p0) base[p0] = (f16)(v[p0] * inv);
}

// ---------------------------------------------------------------------------
// Deformable sampling, NHWC. Thread per (b, head, pix), 32 head-channels.
// ---------------------------------------------------------------------------
__global__ __launch_bounds__(256) void k_deform_h(
    const f16* __restrict__ vals, const f16* __restrict__ off,
    const f16* __restrict__ attn, f16* __restrict__ outa)
{
  int idx = blockIdx.x * blockDim.x + threadIdx.x;
  if (idx >= Bn * NHd * HWl) return;
  int pix = idx % HWl;
  int head = (idx / HWl) & 3;
  int b = idx / (HWl * NHd);
  int j = pix % FW, i = pix / FW;

  const float kx = (float)FW / (float)(FW - 1);
  const float ky = (float)FH / (float)(FH - 1);
  const f16* vb = vals + (size_t)b * HWl * 128 + head * 32;
  const f16* ab = attn + ((size_t)b * HWl + pix) * 48 + head * 9;
  const f16* ob = off + ((size_t)b * HWl + pix) * 80 + head * 18;

  float acc[32];
#pragma unroll
  for (int k = 0; k < 32; ++k) acc[k] = 0.f;

#pragma unroll
  for (int p0 = 0; p0 < 9; ++p0) {
    float ox = (float)ob[p0 * 2];
    float oy = (float)ob[p0 * 2 + 1];
    float aw = (float)ab[p0];
    float xf = ((float)j + ox) * kx - 0.5f;
    float yf = ((float)i + oy) * ky - 0.5f;
    xf = fminf(fmaxf(xf, 0.f), (float)(FW - 1));
    yf = fminf(fmaxf(yf, 0.f), (float)(FH - 1));
    int x0 = (int)floorf(xf), y0 = (int)floorf(yf);
    int x1 = min(x0 + 1, FW - 1), y1 = min(y0 + 1, FH - 1);
    float fx = xf - (float)x0, fy = yf - (float)y0;
    float w00 = aw * (1.f - fx) * (1.f - fy);
    float w01 = aw * fx * (1.f - fy);
    float w10 = aw * (1.f - fx) * fy;
    float w11 = aw * fx * fy;
    const f16x8* c00 = (const f16x8*)&vb[(size_t)(y0 * FW + x0) * 128];
    const f16x8* c01 = (const f16x8*)&vb[(size_t)(y0 * FW + x1) * 128];
    const f16x8* c10 = (const f16x8*)&vb[(size_t)(y1 * FW + x0) * 128];
    const f16x8* c11 = (const f16x8*)&vb[(size_t)(y1 * FW + x1) * 128];
#pragma unroll
    for (int k8 = 0; k8 < 4; ++k8) {
      f16x8 a = c00[k8], bb = c01[k8], cc = c10[k8], dd = c11[k8];
#pragma unroll
      for (int jj = 0; jj < 8; ++jj)
        acc[k8 * 8 + jj] += w00 * (float)a[jj] + w01 * (float)bb[jj]
                          + w10 * (float)cc[jj] + w11 * (float)dd[jj];
    }
  }
  f16* op = outa + ((size_t)b * HWl + pix) * 128 + head * 32;
#pragma unroll
  for (int k = 0; k < 32; ++k) op[k] = (f16)acc[k];
}

// ---------------------------------------------------------------------------
// dec2: 32->3 conv from NHWC f16 window + sigmoid, NCHW f32 out rows [c0,+R).
// ---------------------------------------------------------------------------
__global__ __launch_bounds__(256) void k_dec2_h(
    const f16* __restrict__ Xb, const float* __restrict__ w,
    const float* __restrict__ bias, float* __restrict__ out,
    int c0, int b0, int brows, int R)
{
  int idx = blockIdx.x * blockDim.x + threadIdx.x;
  if (idx >= Bn * R * Wh) return;
  int x = idx % Wh;
  int y = c0 + (idx / Wh) % R;
  int b = idx / (Wh * R);
  float a0 = bias[0], a1 = bias[1], a2 = bias[2];
#pragma unroll
  for (int ky = 0; ky < 3; ++ky) {
    int gy = y + ky - 1;
    if (gy < 0 || gy >= Hh) continue;
#pragma unroll
    for (int kxx = 0; kxx < 3; ++kxx) {
      int gx = x + kxx - 1;
      if (gx < 0 || gx >= Wh) continue;
      int tap = ky * 3 + kxx;
      const f16* px = Xb + ((size_t)(b * brows + (gy - b0)) * Wh + gx) * 32;
#pragma unroll
      for (int k8 = 0; k8 < 4; ++k8) {
        f16x8 v = *(const f16x8*)&px[k8 * 8];
#pragma unroll
        for (int jj = 0; jj < 8; ++jj) {
          int ci = k8 * 8 + jj;
          float f = (float)v[jj];
          a0 += f * w[(0 * 32 + ci) * 9 + tap];
          a1 += f * w[(1 * 32 + ci) * 9 + tap];
          a2 += f * w[(2 * 32 + ci) * 9 + tap];
        }
      }
    }
  }
  size_t o = ((size_t)(b * 3 + 0) * Hh + y) * Wh + x;
  out[o] = 1.f / (1.f + expf(-a0));
  out[o + (size_t)Hh * Wh] = 1.f / (1.f + expf(-a1));
  out[o + (size_t)2 * Hh * Wh] = 1.f / (1.f + expf(-a2));
}

// ---------------------------------------------------------------------------
extern "C" void kernel_launch(void* const* d_in, const int* in_sizes, int n_in,
                              void* d_out, int out_size, void* d_ws, size_t ws_size,
                              hipStream_t stream) {
  (void)in_sizes; (void)n_in; (void)out_size; (void)ws_size;
  const float* feat1  = (const float*)d_in[0];
  const float* feat2  = (const float*)d_in[1];
  const float* flowf  = (const float*)d_in[2];
  const float* flowb  = (const float*)d_in[3];
  const float* edge1  = (const float*)d_in[4];
  const float* edge2  = (const float*)d_in[5];
  const float* fuse_w0 = (const float*)d_in[6];
  const float* fuse_b0 = (const float*)d_in[7];
  const float* fuse_w1 = (const float*)d_in[8];
  const float* fuse_b1 = (const float*)d_in[9];
  const float* gn_g   = (const float*)d_in[10];
  const float* gn_b   = (const float*)d_in[11];
  const float* off_w0 = (const float*)d_in[12];
  const float* off_b0 = (const float*)d_in[13];
  const float* off_w1 = (const float*)d_in[14];
  const float* off_b1 = (const float*)d_in[15];
  const float* aw_w0  = (const float*)d_in[16];
  const float* aw_b0  = (const float*)d_in[17];
  const float* aw_w1  = (const float*)d_in[18];
  const float* aw_b1  = (const float*)d_in[19];
  const float* val_w  = (const float*)d_in[20];
  const float* val_b  = (const float*)d_in[21];
  const float* out_w  = (const float*)d_in[22];
  const float* out_b  = (const float*)d_in[23];
  const float* ffn_w0 = (const float*)d_in[24];
  const float* ffn_b0 = (const float*)d_in[25];
  const float* ffn_w1 = (const float*)d_in[26];
  const float* ffn_b1 = (const float*)d_in[27];
  const float* dec_w0 = (const float*)d_in[28];
  const float* dec_b0 = (const float*)d_in[29];
  const float* dec_w1 = (const float*)d_in[30];
  const float* dec_b1 = (const float*)d_in[31];
  const float* dec_w2 = (const float*)d_in[32];
  const float* dec_b2 = (const float*)d_in[33];
  float* out = (float*)d_out;

  // ---- workspace layout (f16 units). Weights + zero page FIRST. ~75 MB.
  f16* ws16 = (f16*)d_ws;
  size_t o = 0;
  auto alloc = [&](size_t n) { f16* p = ws16 + o; o += (n + 7) & ~(size_t)7; return p; };
  f16* xbuf  = alloc((size_t)2 * HWl * 128);
  f16* zp    = alloc(98304);                    // 192KB zero page
  f16* wfF0 = alloc(9 * 9 * 8 * 512);
  f16* wfF1 = alloc(9 * 4 * 8 * 512);
  f16* wfOA = alloc(9 * 4 * 16 * 512);          // off0 (cf 0..7) + aw0 (cf 8..15)
  f16* wfD0 = alloc(9 * 4 * 4 * 512);
  f16* wfD1 = alloc(9 * 2 * 2 * 512);
  f16* w1O  = alloc(4 * 5 * 512);
  f16* w1A  = alloc(4 * 3 * 512);
  f16* w1V  = alloc(4 * 8 * 512);
  f16* w1U  = alloc(4 * 8 * 512);
  f16* w1G0 = alloc(4 * 16 * 512);
  f16* w1G1 = alloc(8 * 8 * 512);
  float* gnp = (float*)alloc(512);
  f16* pool  = ws16 + o;                        // decoder overlay starts here
  f16* regA  = alloc((size_t)2 * HWl * 288);    // fused / t_oa / ffn_t
  f16* regB  = alloc((size_t)2 * HWl * 128);    // source / out_attn
  f16* regC  = alloc((size_t)2 * HWl * 128);    // fuse0-out / qb
  f16* offb  = alloc((size_t)2 * HWl * 80);
  f16* attnb = alloc((size_t)2 * HWl * 48);
  f16* regF  = alloc((size_t)2 * HWl * 131);    // valsb
  f16* featT1 = alloc((size_t)2 * HWl * 128);
  f16* featT2 = alloc((size_t)2 * HWl * 128);

  f16* fused = regA;
  f16* t_oa  = regA;        // merged off/aw 3x3 out, 256 ch
  f16* ffn_t = regA;
  f16* src_h = regB;
  f16* out_attn = regB;
  f16* tmp_h = regC;
  f16* qb    = regC;
  f16* valsb = regF;
  // Decoder overlay over pool (dead after FFN). 192-row chunks, NO bufU
  // (upsample fused into dec0 staging): bufA 2*196*640*64 = 16.06M,
  // bufB 2*194*640*32 = 7.95M; total 24.0M <= pool 32.5M f16.
  f16* bufA = pool;
  f16* bufB = bufA + (size_t)2 * 196 * 640 * 64;

  dim3 blk(256);
  auto pg = [](long n) { return dim3((unsigned)((n + 255) / 256)); };
  auto cg = [](int pixTiles, int coTiles) {
    return dim3((unsigned)((pixTiles * coTiles + 3) / 4), 1, 2);
  };
  const int BIG = 1 << 30;

  // ---- zero page init ----
  k_zero<<<dim3(48), blk, 0, stream>>>(zp, 12288);

  // ---- merged weight prep ----
  PrepArgs pa;
  int pb = 0;
  auto addj = [&](int k, const float* w, f16* wf, int Cout, int cing, int coutg,
                  int KS, int CoF, int taps, int CoFt, int cf0) {
    pa.j[k] = PrepJob{w, wf, Cout, cing, coutg, KS, CoF, taps, CoFt, cf0, pb};
    pb += (taps * KS * CoF * 64 + 255) / 256;
  };
  addj(0, fuse_w0, wfF0, 128, 259, 128, 9, 8, 9, 8, 0);
  addj(1, fuse_w1, wfF1, 128, 128, 128, 4, 8, 9, 8, 0);
  addj(2, off_w0, wfOA, 128, 32, 32, 4, 8, 9, 16, 0);
  addj(3, aw_w0,  wfOA, 128, 32, 32, 4, 8, 9, 16, 8);
  addj(4, dec_w0, wfD0, 64, 128, 64, 4, 4, 9, 4, 0);
  addj(5, dec_w1, wfD1, 32, 64, 32, 2, 2, 9, 2, 0);
  addj(6, off_w1, w1O, 72, 128, 72, 4, 5, 1, 5, 0);
  addj(7, aw_w1,  w1A, 36, 128, 36, 4, 3, 1, 3, 0);
  addj(8, val_w,  w1V, 128, 128, 128, 4, 8, 1, 8, 0);
  addj(9, out_w,  w1U, 128, 128, 128, 4, 8, 1, 8, 0);
  addj(10, ffn_w0, w1G0, 256, 128, 256, 4, 16, 1, 16, 0);
  addj(11, ffn_w1, w1G1, 128, 256, 128, 8, 8, 1, 8, 0);
  k_wprep_all<<<dim3((unsigned)pb), blk, 0, stream>>>(pa);

  // ---- 0. feats -> NHWC f16 ----
  k_tr_h<<<pg(2L * Bn * HWl * 8), blk, 0, stream>>>(feat1, feat2, featT1, featT2);
  // ---- 1. warp + concat + source ----
  k_warp_fuse_h<<<pg((long)Bn * HWl * 8), blk, 0, stream>>>(featT1, featT2, flowf, flowb,
                                                            edge1, edge2, fused, src_h);
  // ---- 2-3. fuse convs (conv3g + SGB; L2-resident) ----
  k_conv3g<1, 2, 4, 160, 9><<<cg(480, 2), blk, 0, stream>>>(fused, wfF0, fuse_b0, fuse_b0, BIG,
      tmp_h, zp, 8, 288, 128, FH, 0, FH, 0, FH, 0, FH, 2);
  k_conv3g<1, 2, 4, 160, 4><<<cg(480, 2), blk, 0, stream>>>(tmp_h, wfF1, fuse_b1, fuse_b1, BIG,
      xbuf, zp, 8, 128, 128, FH, 0, FH, 0, FH, 0, FH, 2);
  // ---- 4. group norm ----
  k_gn_part_h<<<dim3(128), blk, 0, stream>>>(xbuf, gnp);
  k_gn_apply_h<<<pg(2L * HWl * 16), blk, 0, stream>>>(xbuf, gn_g, gn_b, gnp, qb);
  // ---- 5. merged off0+aw0 grouped 3x3 (conv3g, 256 out ch, dual bias) ----
  k_conv3g<1, 2, 4, 160, 4><<<cg(480, 4), blk, 0, stream>>>(qb, wfOA, off_b0, aw_b0, 128,
      t_oa, zp, 16, 128, 256, FH, 0, FH, 0, FH, 0, FH, 4);
  // ---- 6-8. 1x1 heads + softmax ----
  k_gemm1x1<0, 0, 4><<<dim3(480), blk, 0, stream>>>(t_oa, w1O, off_b1, offb,
      5, 256, 80, 72, 2, 960);
  k_gemm1x1<0, 0, 4><<<dim3(240), blk, 0, stream>>>(t_oa + 128, w1A, aw_b1, attnb,
      3, 256, 48, 36, 1, 960);
  k_softmax9_h<<<pg(2L * NHd * HWl), blk, 0, stream>>>(attnb);
  // ---- 9. vals ----
  k_gemm1x1<0, 0, 4><<<dim3(480), blk, 0, stream>>>(src_h, w1V, val_b, valsb,
      8, 128, 128, 128, 2, 960);
  // ---- 10. deform ----
  k_deform_h<<<pg(2L * NHd * HWl), blk, 0, stream>>>(valsb, offb, attnb, out_attn);
  // ---- 11. out-proj (residual into xbuf) ----
  k_gemm1x1<0, 1, 4><<<dim3(480), blk, 0, stream>>>(out_attn, w1U, out_b, xbuf,
      8, 128, 128, 128, 2, 960);
  // ---- 12-13. FFN ----
  k_gemm1x1<2, 0, 4><<<dim3(960), blk, 0, stream>>>(xbuf, w1G0, ffn_b0, ffn_t,
      16, 128, 256, 256, 4, 960);
  k_gemm1x1<0, 1, 8><<<dim3(480), blk, 0, stream>>>(ffn_t, w1G1, ffn_b1, xbuf,
      8, 256, 128, 128, 2, 960);

  // ---- 14. decoder, 2 chunks of 192 rows; conv3m (LDS), upsample fused ----
  for (int c0 = 0; c0 < Hh; c0 += 192) {
    int c1 = c0 + 192;
    int a0 = c0 - 2 > 0 ? c0 - 2 : 0;
    int a1 = c1 + 2 < Hh ? c1 + 2 : Hh;
    int b0 = c0 - 1 > 0 ? c0 - 1 : 0;
    int b1 = c1 + 1 < Hh ? c1 + 1 : Hh;
    int ar = a1 - a0, br = b1 - b0;
    // dec0: 128->64 on upsampled grid, rows [a0,a1) -> bufA
    dim3 gD0((unsigned)(((ar + 3) / 4) * 20), 1, 2);
    k_conv3m<1, 1, 4><<<gD0, blk, 0, stream>>>(xbuf, wfD0, dec_b0, bufA,
        4, 4, 128, 64, Wh, Hh, 0, 0, a0, ar, a0, a1);
    // dec1: 64->32, rows [b0,b1) -> bufB
    dim3 gD1((unsigned)(((br + 3) / 4) * 20), 1, 2);
    k_conv3m<1, 0, 2><<<gD1, blk, 0, stream>>>(bufA, wfD1, dec_b1, bufB,
        2, 2, 64, 32, Wh, Hh, a0, ar, b0, br, b0, b1);
    // dec2: 32->3 + sigmoid -> out rows [c0,c1)
    k_dec2_h<<<pg(2L * 192 * Wh), blk, 0, stream>>>(bufB, dec_w2, dec_b2, out,
                                                    c0, b0, br, 192);
  }
}